// Round 16
// baseline (202.541 us; speedup 1.0000x reference)
//
#include <hip/hip_runtime.h>
#include <hip/hip_bf16.h>

// Problem constants (match reference)
#define NB 16
#define NP 784
#define NC 10
#define NM 4096
#define NMG 128
#define DPT 1152
#define DRG 768
#define DTOT (DPT + DRG)   // 1920

typedef __attribute__((ext_vector_type(8))) short bf16x8;    // 8 bf16 (4 VGPR)
typedef __attribute__((ext_vector_type(4))) float f32x4;     // 16x16 MFMA acc
typedef __attribute__((ext_vector_type(4))) int i32x4;
typedef __attribute__((ext_vector_type(8))) int i32x8;

#define SONE 0x7F7F7F7F   // e8m0 scale = 1.0 in every byte
#define SKIP_THR 70.0f    // clamp(50) + fp8-quantization guard band

__device__ __forceinline__ unsigned short f2bf(float f) {
  unsigned u = __float_as_uint(f);
  return (unsigned short)((u + 0x7fffu + ((u >> 16) & 1u)) >> 16); // RNE
}
// order-preserving float->uint encoding (for atomicMin on float values)
__device__ __forceinline__ unsigned enc_f(float f) {
  unsigned u = __float_as_uint(f);
  return (u & 0x80000000u) ? ~u : (u | 0x80000000u);
}
__device__ __forceinline__ float dec_f(unsigned u) {
  return __uint_as_float((u & 0x80000000u) ? (u & 0x7fffffffu) : ~u);
}
// async global->LDS, 16B per lane. LDS dest must be wave-uniform (HW adds lane*16).
__device__ __forceinline__ void gl_lds16(const void* g, void* s) {
  __builtin_amdgcn_global_load_lds(
      (const __attribute__((address_space(1))) unsigned int*)g,
      (__attribute__((address_space(3))) unsigned int*)s, 16, 0, 0);
}

// ---------------------------------------------------------------------------
// init: zero nv/flags, sentinel mc/pmc/gmin, compute present[]. grid 64x256.
// (gs_part needs no init: prep fully overwrites it.)
// ---------------------------------------------------------------------------
__global__ __launch_bounds__(256) void init_kernel(
    const int* __restrict__ cl, float* __restrict__ nvArr,
    unsigned* __restrict__ mc, unsigned* __restrict__ gmin,
    unsigned* __restrict__ flagF, unsigned* __restrict__ classFlag,
    unsigned* __restrict__ present) {
  const int tid = blockIdx.x * 256 + threadIdx.x;
  const int stride = gridDim.x * 256;
  const int total_mc = 4 * NB * NP;           // 50176 words (mc + pmc)
  // 0xF7F7F7F7 decodes (enc_f inverse) to ~+6e33: finite, > any candidate
  for (int i = tid; i < total_mc; i += stride) mc[i] = 0xF7F7F7F7u;
  if (tid < NB) nvArr[tid] = 0.f;
  if (tid < 2 * NB) gmin[tid] = 0xF7F7F7F7u;
  if (tid < 2 * NB) flagF[tid] = 0u;
  if (tid < NC) classFlag[tid] = 0u;
  if (blockIdx.x == 0) {
    if (threadIdx.x < NC) present[threadIdx.x] = 0u;
    __syncthreads();
    if (threadIdx.x < NB) present[cl[threadIdx.x]] = 1u;
  }
}

// ---------------------------------------------------------------------------
// FUSED convert128 + prep: independent passes run concurrently in one grid.
//  blk [0,784): prep — patch norms (full + first-128) + masked global-sum
//               PARTIALS (LDS cross-wave reduce, NO gs atomics) + nv
//               + fp8 convert of first 128 dims.
//  blk [784,2064): bank fp32 -> fp8 first 128 dims + partial norms, 64 rows
//               per block (gated on present).
// ---------------------------------------------------------------------------
__global__ __launch_bounds__(256) void fused_cp_kernel(
    const float* __restrict__ feat_pt, const float* __restrict__ feat_rgb,
    const float* __restrict__ bank_pt, const float* __restrict__ bank_rgb,
    const int* __restrict__ valid_mask,
    float* __restrict__ xx_pt, float* __restrict__ xx_rgb,
    float* __restrict__ xxS_pt, float* __restrict__ xxS_rgb,
    float* __restrict__ gs_part,   // [NB][49][DTOT]
    float* __restrict__ nvArr,
    unsigned char* __restrict__ f8_pt, unsigned char* __restrict__ f8_rgb,
    unsigned char* __restrict__ b8_pt, unsigned char* __restrict__ b8_rgb,
    float* __restrict__ bnS_pt, float* __restrict__ bnS_rgb,
    const unsigned* __restrict__ present) {
  __shared__ float accL[4][DTOT];   // 30 KB (prep blocks only)
  const int blk = blockIdx.x;
  const int w = threadIdx.x >> 6, lane = threadIdx.x & 63;
  if (blk < 784) {
    const int b = blk / 49, xb = blk % 49;
    float2 gp[9], gr[6];
#pragma unroll
    for (int i = 0; i < 9; ++i) gp[i] = make_float2(0.f, 0.f);
#pragma unroll
    for (int i = 0; i < 6; ++i) gr[i] = make_float2(0.f, 0.f);
    const int pbase = xb * 16 + w * 4;
    float mcount = 0.f;
#pragma unroll
    for (int pi = 0; pi < 4; ++pi) {
      const int p = pbase + pi;
      const float msk = (float)valid_mask[b * NP + p];
      mcount += msk;
      const float2* xr = (const float2*)(feat_pt + ((size_t)b * NP + p) * DPT);
      unsigned short* xw = (unsigned short*)(f8_pt + ((size_t)b * NP + p) * DPT);
      float s = 0.f, sp = 0.f;
#pragma unroll
      for (int i = 0; i < 9; ++i) {
        float2 v = xr[lane + 64 * i];
        float c2 = v.x * v.x + v.y * v.y;
        s += c2;
        if (i == 0) {
          sp = c2;   // dims 0..127
          int pk = __builtin_amdgcn_cvt_pk_fp8_f32(v.x, v.y, 0, false);
          xw[lane] = (unsigned short)(pk & 0xFFFF);
        }
        gp[i].x += msk * v.x; gp[i].y += msk * v.y;
      }
      const float2* rr = (const float2*)(feat_rgb + ((size_t)b * NP + p) * DRG);
      unsigned short* rw = (unsigned short*)(f8_rgb + ((size_t)b * NP + p) * DRG);
      float s2 = 0.f, sp2 = 0.f;
#pragma unroll
      for (int i = 0; i < 6; ++i) {
        float2 v = rr[lane + 64 * i];
        float c2 = v.x * v.x + v.y * v.y;
        s2 += c2;
        if (i == 0) {
          sp2 = c2;  // dims 0..127
          int pk = __builtin_amdgcn_cvt_pk_fp8_f32(v.x, v.y, 0, false);
          rw[lane] = (unsigned short)(pk & 0xFFFF);
        }
        gr[i].x += msk * v.x; gr[i].y += msk * v.y;
      }
      for (int sft = 1; sft < 64; sft <<= 1) {
        s += __shfl_xor(s, sft, 64);
        s2 += __shfl_xor(s2, sft, 64);
        sp += __shfl_xor(sp, sft, 64);
        sp2 += __shfl_xor(sp2, sft, 64);
      }
      if (lane == 0) {
        xx_pt[b * NP + p] = s;
        xx_rgb[b * NP + p] = s2;
        xxS_pt[b * NP + p] = sp;
        xxS_rgb[b * NP + p] = sp2;
      }
    }
    if (lane == 0) atomicAdd(&nvArr[b], mcount);
    // per-wave rows into LDS (conflict-free float2 stores), then 4->1 reduce
#pragma unroll
    for (int i = 0; i < 9; ++i)
      *(float2*)&accL[w][2 * (lane + 64 * i)] = gp[i];
#pragma unroll
    for (int i = 0; i < 6; ++i)
      *(float2*)&accL[w][DPT + 2 * (lane + 64 * i)] = gr[i];
    __syncthreads();
    float* dst = gs_part + ((size_t)b * 49 + xb) * DTOT;
    for (int e = threadIdx.x; e < DTOT; e += 256)
      dst[e] = accL[0][e] + accL[1][e] + accL[2][e] + accL[3][e];
  } else {
    const int cb = blk - 784;          // 0..1279
    const int branch = cb & 1;
    const int grp = cb >> 1;           // 0..639
    const int c = grp >> 6;
    if (present[c] == 0u) return;
    const int rch = grp & 63;
    const float* bank = branch ? bank_rgb : bank_pt;
    unsigned char* b8 = branch ? b8_rgb : b8_pt;
    float* bnS = branch ? bnS_rgb : bnS_pt;
    const int D = branch ? DRG : DPT;
#pragma unroll 1
    for (int rl = 0; rl < 16; ++rl) {
      const int row = (c << 12) + rch * 64 + w * 16 + rl;
      const float2* rp = (const float2*)(bank + (size_t)row * D);
      unsigned short* dp = (unsigned short*)(b8 + (size_t)row * D);
      float2 v = rp[lane];
      float s = v.x * v.x + v.y * v.y;
      int pk = __builtin_amdgcn_cvt_pk_fp8_f32(v.x, v.y, 0, false);
      dp[lane] = (unsigned short)(pk & 0xFFFF);
      for (int sft = 1; sft < 64; sft <<= 1) s += __shfl_xor(s, sft, 64);
      if (lane == 0) bnS[row] = s;
    }
  }
}

// ---------------------------------------------------------------------------
// FUSED gemm1 + gdistA: independent, run concurrently.
//  blk [0,1024): certificate GEMM (partial min over first 128 dims), B in
//               VGPRs, A 2-deep prefetch with counted vmcnt(4).
//  blk [1024,1280): global-bank min (gdistA); builds gsh by summing the 49
//               gs partials (L2-hot; hidden under concurrent gemm1 blocks).
// ---------------------------------------------------------------------------
__global__ __launch_bounds__(256) void fused_g1_kernel(
    const unsigned char* __restrict__ f8_pt, const unsigned char* __restrict__ f8_rgb,
    const unsigned char* __restrict__ b8_pt, const unsigned char* __restrict__ b8_rgb,
    const float* __restrict__ bnS_pt, const float* __restrict__ bnS_rgb,
    const int* __restrict__ classlabels,
    unsigned* __restrict__ pmc_pt, unsigned* __restrict__ pmc_rgb,
    const float* __restrict__ bgp, const float* __restrict__ bgr,
    const float* __restrict__ gs_part, const float* __restrict__ nvArr,
    unsigned* __restrict__ gmin) {
  __shared__ __align__(16) unsigned char As[2][16384];
  __shared__ __align__(16) unsigned char Bs[16384];
  const int blk = blockIdx.x;
  const int t = threadIdx.x;
  const int w = t >> 6, lane = t & 63;

  if (blk >= 1024) {
    // ---- gdistA ----
    const int g = blk - 1024;          // 0..255
    const int slice = g & 7;
    const int b = (g >> 3) & 15;
    const int branch = g >> 7;
    const int D = branch ? DRG : DPT;
    const int base = branch ? DPT : 0;
    const float* bank = branch ? bgr : bgp;
    const int cls = classlabels[b];
    float* gsh = (float*)&As[0][0];    // reuse LDS
    const float inv = 1.f / nvArr[b];
    const float* gp0 = gs_part + (size_t)b * 49 * DTOT + base;
    for (int d = t; d < D; d += 256) {
      float s = 0.f;
#pragma unroll 1
      for (int k = 0; k < 49; ++k) s += gp0[(size_t)k * DTOT + d];
      gsh[d] = s * inv;
    }
    __syncthreads();
    const int cnt = D >> 7;
    float mn = 1e30f;
#pragma unroll 1
    for (int rl = 0; rl < 4; ++rl) {
      const int row = slice * 16 + w * 4 + rl;
      const float2* yr = (const float2*)(bank + ((size_t)cls * NMG + row) * D);
      float s = 0.f;
      for (int i = 0; i < cnt; ++i) {
        float2 y = yr[lane + 64 * i];
        int d = 2 * (lane + 64 * i);
        float dx = gsh[d] - y.x, dy = gsh[d + 1] - y.y;
        s += dx * dx + dy * dy;
      }
      for (int sft = 1; sft < 64; sft <<= 1) s += __shfl_xor(s, sft, 64);
      mn = fminf(mn, s);
    }
    if (lane == 0) atomicMin(&gmin[branch * NB + b], enc_f(mn));
    return;
  }

  // ---- gemm1 ----
  const int branch = blk & 1;
  const int mch = (blk >> 1) & 31;
  const int b = blk >> 6;
  const int D = branch ? DRG : DPT;
  const unsigned char* f8 = branch ? f8_rgb : f8_pt;
  const unsigned char* b8 = branch ? b8_rgb : b8_pt;
  const float* bnS = branch ? bnS_rgb : bnS_pt;
  unsigned* pmc = branch ? pmc_rgb : pmc_pt;
  const int cls = classlabels[b];

  const unsigned char* fB = f8 + (size_t)b * NP * D;
  const unsigned char* bB = b8 + (size_t)cls * NM * D;
  const int mbase = mch * 128;

  int rr[4], cx[4];
#pragma unroll
  for (int i = 0; i < 4; ++i) {
    int pos = w * 256 + i * 64 + lane;
    rr[i] = pos >> 3;
    cx[i] = ((pos & 7) ^ (rr[i] & 7)) << 4;
  }
  const int wr = w >> 1, wcq = w & 1;
  const int lrow = lane & 15, lk = lane >> 4;
  int aoff0[4], aoff1[4], boff0[4], boff1[4];
#pragma unroll
  for (int i = 0; i < 4; ++i) {
    int ra = wr * 64 + i * 16 + lrow;
    aoff0[i] = ra * 128 + ((lk * 32) ^ ((ra & 7) << 4));
    aoff1[i] = ra * 128 + ((lk * 32 + 16) ^ ((ra & 7) << 4));
    int rb = wcq * 64 + i * 16 + lrow;
    boff0[i] = rb * 128 + ((lk * 32) ^ ((rb & 7) << 4));
    boff1[i] = rb * 128 + ((lk * 32 + 16) ^ ((rb & 7) << 4));
  }
  float bnv[4];
#pragma unroll
  for (int j = 0; j < 4; ++j)
    bnv[j] = bnS[cls * NM + mbase + wcq * 64 + j * 16 + lrow];

  auto STAGE_A = [&](int pt, int buf) {
#pragma unroll
    for (int i = 0; i < 4; ++i) {
      int pr = pt * 128 + rr[i];
      if (pr > NP - 1) pr = NP - 1;
      gl_lds16(fB + (size_t)pr * D + cx[i], &As[buf][0] + (w * 4 + i) * 1024);
    }
  };

  // prologue: stage B, A(0), A(1)   -> ledger: B(4), A0(4), A1(4)
#pragma unroll
  for (int i = 0; i < 4; ++i)
    gl_lds16(bB + (size_t)(mbase + rr[i]) * D + cx[i], &Bs[0] + (w * 4 + i) * 1024);
  STAGE_A(0, 0);
  STAGE_A(1, 1);
  asm volatile("s_waitcnt vmcnt(8)" ::: "memory");   // B landed
  __builtin_amdgcn_s_barrier();
  __builtin_amdgcn_sched_barrier(0);
  i32x8 bfv[4];
#pragma unroll
  for (int i = 0; i < 4; ++i) {
    i32x4 lo = *(const i32x4*)(&Bs[0] + boff0[i]);
    i32x4 hi = *(const i32x4*)(&Bs[0] + boff1[i]);
    bfv[i] = __builtin_shufflevector(lo, hi, 0, 1, 2, 3, 4, 5, 6, 7);
  }
  asm volatile("s_waitcnt lgkmcnt(0)" ::: "memory");
  __builtin_amdgcn_s_barrier();                      // B reads done
  __builtin_amdgcn_sched_barrier(0);

#pragma unroll 1
  for (int pt = 0; pt < 7; ++pt) {
    const int cur = pt & 1;
    // entry: A(pt) done (A(pt+1) stays in flight)
    asm volatile("s_waitcnt vmcnt(4)" ::: "memory");
    __builtin_amdgcn_s_barrier();
    __builtin_amdgcn_sched_barrier(0);
    i32x8 af[4];
#pragma unroll
    for (int i = 0; i < 4; ++i) {
      i32x4 lo = *(const i32x4*)(&As[cur][0] + aoff0[i]);
      i32x4 hi = *(const i32x4*)(&As[cur][0] + aoff1[i]);
      af[i] = __builtin_shufflevector(lo, hi, 0, 1, 2, 3, 4, 5, 6, 7);
    }
    float rm[4][4];
#pragma unroll
    for (int i = 0; i < 4; ++i) {
      f32x4 a0 = (f32x4){0.f, 0.f, 0.f, 0.f};
      f32x4 a1 = a0, a2 = a0, a3 = a0;
      a0 = __builtin_amdgcn_mfma_scale_f32_16x16x128_f8f6f4(af[i], bfv[0], a0, 0, 0, 0, SONE, 0, SONE);
      a1 = __builtin_amdgcn_mfma_scale_f32_16x16x128_f8f6f4(af[i], bfv[1], a1, 0, 0, 0, SONE, 0, SONE);
      a2 = __builtin_amdgcn_mfma_scale_f32_16x16x128_f8f6f4(af[i], bfv[2], a2, 0, 0, 0, SONE, 0, SONE);
      a3 = __builtin_amdgcn_mfma_scale_f32_16x16x128_f8f6f4(af[i], bfv[3], a3, 0, 0, 0, SONE, 0, SONE);
#pragma unroll
      for (int e = 0; e < 4; ++e) {
        float v = bnv[0] - 2.0f * a0[e];
        v = fminf(v, bnv[1] - 2.0f * a1[e]);
        v = fminf(v, bnv[2] - 2.0f * a2[e]);
        v = fminf(v, bnv[3] - 2.0f * a3[e]);
        rm[i][e] = v;
      }
    }
#pragma unroll
    for (int s2 = 1; s2 < 16; s2 <<= 1)
#pragma unroll
      for (int i = 0; i < 4; ++i)
#pragma unroll
        for (int e = 0; e < 4; ++e)
          rm[i][e] = fminf(rm[i][e], __shfl_xor(rm[i][e], s2, 64));
    if (lrow == 0) {
#pragma unroll
      for (int i = 0; i < 4; ++i)
#pragma unroll
        for (int e = 0; e < 4; ++e) {
          int p = pt * 128 + wr * 64 + i * 16 + lk * 4 + e;
          if (p < NP) atomicMin(&pmc[b * NP + p], enc_f(rm[i][e]));
        }
    }
    // exit: all waves finished reading buf[cur] -> safe to overwrite
    asm volatile("s_waitcnt lgkmcnt(0)" ::: "memory");
    __builtin_amdgcn_sched_barrier(0);
    __builtin_amdgcn_s_barrier();
    if (pt + 2 < 7) STAGE_A(pt + 2, cur);
  }
}

// ---------------------------------------------------------------------------
// Flag kernel. grid: 32 x 256. flags pre-zeroed by init.
// ---------------------------------------------------------------------------
__global__ __launch_bounds__(256) void flag_kernel(
    const float* __restrict__ xxS_pt, const float* __restrict__ xxS_rgb,
    const unsigned* __restrict__ pmc_pt, const unsigned* __restrict__ pmc_rgb,
    const int* __restrict__ classlabels,
    unsigned* __restrict__ flagF, unsigned* __restrict__ classFlag) {
  const int tid = blockIdx.x * 256 + threadIdx.x;
  const int stride = gridDim.x * 256;
  for (int idx = tid; idx < 2 * NB * NP; idx += stride) {
    const int branch = idx / (NB * NP);
    const int rem = idx - branch * NB * NP;
    const int b = rem / NP;
    const float* xxS = branch ? xxS_rgb : xxS_pt;
    const unsigned* pmc = branch ? pmc_rgb : pmc_pt;
    float bound = xxS[rem] + dec_f(pmc[rem]);   // lower bound on full min d^2
    if (bound < SKIP_THR) {
      atomicOr(&flagF[branch * NB + b], 1u);
      atomicOr(&classFlag[classlabels[b]], 1u);
    }
  }
}

// ---------------------------------------------------------------------------
// Full fp8 conversion (fallback only; gated). Flat grid:
//  blocks [0,1280): bank rows, gated classFlag; [1280,2064): features, flagF
// ---------------------------------------------------------------------------
__global__ __launch_bounds__(256) void fullconv_kernel(
    const float* __restrict__ bank_pt, const float* __restrict__ bank_rgb,
    const float* __restrict__ feat_pt, const float* __restrict__ feat_rgb,
    unsigned char* __restrict__ b8_pt, unsigned char* __restrict__ b8_rgb,
    unsigned char* __restrict__ f8_pt, unsigned char* __restrict__ f8_rgb,
    float* __restrict__ bn_pt, float* __restrict__ bn_rgb,
    const unsigned* __restrict__ classFlag, const unsigned* __restrict__ flagF) {
  const int id = blockIdx.x;
  const int w = threadIdx.x >> 6, lane = threadIdx.x & 63;
  if (id < 1280) {
    const int branch = id & 1;
    const int cb = id >> 1;
    const int c = cb >> 6;
    if (classFlag[c] == 0u) return;
    const int rch = cb & 63;
    const float* bank = branch ? bank_rgb : bank_pt;
    unsigned char* b8 = branch ? b8_rgb : b8_pt;
    float* bn = branch ? bn_rgb : bn_pt;
    const int D = branch ? DRG : DPT;
    const int D4 = D >> 2;
#pragma unroll 1
    for (int rl = 0; rl < 16; ++rl) {
      const int row = (c << 12) + rch * 64 + w * 16 + rl;
      const float4* rp = (const float4*)(bank + (size_t)row * D);
      unsigned* dp = (unsigned*)(b8 + (size_t)row * D);
      float s = 0.f;
      for (int i = lane; i < D4; i += 64) {
        float4 v = rp[i];
        s += v.x * v.x + v.y * v.y + v.z * v.z + v.w * v.w;
        int pk = __builtin_amdgcn_cvt_pk_fp8_f32(v.x, v.y, 0, false);
        pk = __builtin_amdgcn_cvt_pk_fp8_f32(v.z, v.w, pk, true);
        dp[i] = (unsigned)pk;
      }
      for (int sft = 1; sft < 64; sft <<= 1) s += __shfl_xor(s, sft, 64);
      if (lane == 0) bn[row] = s;
    }
  } else {
    const int fb = id - 1280;
    const int b = fb / 49, xb = fb % 49;
    if (flagF[b] == 0u && flagF[NB + b] == 0u) return;
    const int pbase = xb * 16 + w * 4;
#pragma unroll 1
    for (int pi = 0; pi < 4; ++pi) {
      const int p = pbase + pi;
      const float2* xr = (const float2*)(feat_pt + ((size_t)b * NP + p) * DPT);
      unsigned short* xw = (unsigned short*)(f8_pt + ((size_t)b * NP + p) * DPT);
#pragma unroll
      for (int i = 0; i < 9; ++i) {
        float2 v = xr[lane + 64 * i];
        int pk = __builtin_amdgcn_cvt_pk_fp8_f32(v.x, v.y, 0, false);
        xw[lane + 64 * i] = (unsigned short)(pk & 0xFFFF);
      }
      const float2* rr = (const float2*)(feat_rgb + ((size_t)b * NP + p) * DRG);
      unsigned short* rw = (unsigned short*)(f8_rgb + ((size_t)b * NP + p) * DRG);
#pragma unroll
      for (int i = 0; i < 6; ++i) {
        float2 v = rr[lane + 64 * i];
        int pk = __builtin_amdgcn_cvt_pk_fp8_f32(v.x, v.y, 0, false);
        rw[lane + 64 * i] = (unsigned short)(pk & 0xFFFF);
      }
    }
  }
}

// ---------------------------------------------------------------------------
// Stage-2 GEMM (fallback, R7 schedule): full-K MX-fp8, gated on flagF.
// grid: (64, NB), block 256.
// ---------------------------------------------------------------------------
__global__ __launch_bounds__(256) void gemm2_kernel(
    const unsigned char* __restrict__ f8_pt, const unsigned char* __restrict__ f8_rgb,
    const unsigned char* __restrict__ b8_pt, const unsigned char* __restrict__ b8_rgb,
    const float* __restrict__ bn_pt, const float* __restrict__ bn_rgb,
    const int* __restrict__ classlabels, const unsigned* __restrict__ flagF,
    unsigned* __restrict__ mc_pt, unsigned* __restrict__ mc_rgb) {
  const int branch = blockIdx.x & 1;
  const int mch = blockIdx.x >> 1;
  const int b = blockIdx.y;
  if (flagF[branch * NB + b] == 0u) return;   // certificate passed: all clamp
  const int D = branch ? DRG : DPT;
  const int NK = D >> 7;
  const unsigned char* f8 = branch ? f8_rgb : f8_pt;
  const unsigned char* b8 = branch ? b8_rgb : b8_pt;
  const float* bn = branch ? bn_rgb : bn_pt;
  unsigned* mc = branch ? mc_rgb : mc_pt;
  const int cls = classlabels[b];

  __shared__ __align__(16) unsigned char As[2][16384];
  __shared__ __align__(16) unsigned char Bs[2][16384];

  const int t = threadIdx.x;
  const int w = t >> 6, lane = t & 63;
  const unsigned char* fB = f8 + (size_t)b * NP * D;
  const unsigned char* bB = b8 + (size_t)cls * NM * D;
  const float* bnC = bn + cls * NM;
  const int mbase = mch * 128;

  int rr[4], cx[4];
  const unsigned char* pA[4];
  const unsigned char* pB[4];
#pragma unroll
  for (int i = 0; i < 4; ++i) {
    int pos = w * 256 + i * 64 + lane;
    rr[i] = pos >> 3;
    cx[i] = ((pos & 7) ^ (rr[i] & 7)) << 4;
    pB[i] = bB + (size_t)(mbase + rr[i]) * D + cx[i];
  }
  const int wr = w >> 1, wcq = w & 1;
  const int lrow = lane & 15, lk = lane >> 4;
  int aoff0[4], aoff1[4], boff0[4], boff1[4];
#pragma unroll
  for (int i = 0; i < 4; ++i) {
    int ra = wr * 64 + i * 16 + lrow;
    aoff0[i] = ra * 128 + ((lk * 32) ^ ((ra & 7) << 4));
    aoff1[i] = ra * 128 + ((lk * 32 + 16) ^ ((ra & 7) << 4));
    int rb = wcq * 64 + i * 16 + lrow;
    boff0[i] = rb * 128 + ((lk * 32) ^ ((rb & 7) << 4));
    boff1[i] = rb * 128 + ((lk * 32 + 16) ^ ((rb & 7) << 4));
  }
  auto mkA = [&](int pt) {
    const int p0 = pt * 128;
#pragma unroll
    for (int i = 0; i < 4; ++i) {
      int pr = p0 + rr[i];
      if (pr > NP - 1) pr = NP - 1;
      pA[i] = fB + (size_t)pr * D + cx[i];
    }
  };
  auto STAGE = [&](int k, int buf) {
    unsigned char* ab = &As[buf][0];
    unsigned char* bb2 = &Bs[buf][0];
#pragma unroll
    for (int i = 0; i < 4; ++i) gl_lds16(pA[i] + k, ab + (w * 4 + i) * 1024);
#pragma unroll
    for (int i = 0; i < 4; ++i) gl_lds16(pB[i] + k, bb2 + (w * 4 + i) * 1024);
  };

  mkA(0);
  STAGE(0, 0);
  int cur = 0;
  int npt = 0, nk = 128;

#pragma unroll 1
  for (int pt = 0; pt < 7; ++pt) {
    float rm[4][4];
    f32x4 acc[4][4];
#pragma unroll
    for (int i = 0; i < 4; ++i)
#pragma unroll
      for (int j = 0; j < 4; ++j) {
        acc[i][j] = (f32x4){0.f, 0.f, 0.f, 0.f};
        rm[i][j] = 1e30f;
      }
#pragma unroll 1
    for (int s = 0; s < NK; ++s) {
      STAGE(nk, cur ^ 1);
      if (npt < 7) {
        nk += 128;
        if (nk == D) { nk = 0; ++npt; if (npt < 7) mkA(npt); else nk = 0; }
      }
      asm volatile("s_waitcnt vmcnt(8)" ::: "memory");
      __builtin_amdgcn_s_barrier();
      __builtin_amdgcn_sched_barrier(0);
      const unsigned char* ab = &As[cur][0];
      const unsigned char* bb2 = &Bs[cur][0];
      i32x8 af[4], bfv[4];
#pragma unroll
      for (int i = 0; i < 4; ++i) {
        i32x4 lo = *(const i32x4*)(ab + aoff0[i]);
        i32x4 hi = *(const i32x4*)(ab + aoff1[i]);
        af[i] = __builtin_shufflevector(lo, hi, 0, 1, 2, 3, 4, 5, 6, 7);
        i32x4 lo2 = *(const i32x4*)(bb2 + boff0[i]);
        i32x4 hi2 = *(const i32x4*)(bb2 + boff1[i]);
        bfv[i] = __builtin_shufflevector(lo2, hi2, 0, 1, 2, 3, 4, 5, 6, 7);
      }
#pragma unroll
      for (int i = 0; i < 4; ++i)
#pragma unroll
        for (int j = 0; j < 4; ++j)
          acc[i][j] = __builtin_amdgcn_mfma_scale_f32_16x16x128_f8f6f4(
              af[i], bfv[j], acc[i][j], 0, 0, 0, SONE, 0, SONE);
      asm volatile("s_waitcnt lgkmcnt(0)" ::: "memory");
      __builtin_amdgcn_sched_barrier(0);
      __builtin_amdgcn_s_barrier();
      cur ^= 1;
    }
#pragma unroll
    for (int j = 0; j < 4; ++j) {
      float bnv = bnC[mbase + wcq * 64 + j * 16 + lrow];
#pragma unroll
      for (int i = 0; i < 4; ++i)
#pragma unroll
        for (int e = 0; e < 4; ++e)
          rm[i][e] = fminf(rm[i][e], bnv - 2.0f * acc[i][j][e]);
    }
#pragma unroll
    for (int s2 = 1; s2 < 16; s2 <<= 1)
#pragma unroll
      for (int i = 0; i < 4; ++i)
#pragma unroll
        for (int e = 0; e < 4; ++e)
          rm[i][e] = fminf(rm[i][e], __shfl_xor(rm[i][e], s2, 64));
    if (lrow == 0) {
#pragma unroll
      for (int i = 0; i < 4; ++i)
#pragma unroll
        for (int e = 0; e < 4; ++e) {
          int p = pt * 128 + wr * 64 + i * 16 + lk * 4 + e;
          if (p < NP) atomicMin(&mc[b * NP + p], enc_f(rm[i][e]));
        }
    }
  }
}

// ---------------------------------------------------------------------------
// gdistB: per-b patch reduction + combine. grid NB, block 256.
// ---------------------------------------------------------------------------
__global__ __launch_bounds__(256) void gdistB_kernel(
    const int* __restrict__ valid_mask,
    const float* __restrict__ xx_pt, const float* __restrict__ xx_rgb,
    const unsigned* __restrict__ mc_pt, const unsigned* __restrict__ mc_rgb,
    const float* __restrict__ nvArr, const unsigned* __restrict__ gmin,
    float* __restrict__ partial) {
  const int b = blockIdx.x;
  const int tid = threadIdx.x;
  __shared__ float s1[256], s2[256];
  float spt = 0.f, srgb = 0.f;
  for (int p = tid; p < NP; p += 256) {
    float m = (float)valid_mask[b * NP + p];
    float dpt = xx_pt[b * NP + p] + dec_f(mc_pt[b * NP + p]);
    dpt = sqrtf(fminf(fmaxf(dpt, 1e-12f), 50.f));
    float drg = xx_rgb[b * NP + p] + dec_f(mc_rgb[b * NP + p]);
    drg = sqrtf(fminf(fmaxf(drg, 1e-12f), 50.f));
    spt += m * dpt;
    srgb += drg;
  }
  s1[tid] = spt; s2[tid] = srgb;
  __syncthreads();
  for (int s = 128; s > 0; s >>= 1) {
    if (tid < s) { s1[tid] += s1[tid + s]; s2[tid] += s2[tid + s]; }
    __syncthreads();
  }
  if (tid == 0) {
    const float nv = nvArr[b];
    float ming_pt = sqrtf(fminf(fmaxf(dec_f(gmin[b]), 1e-12f), 50.f));
    float ming_rgb = sqrtf(fminf(fmaxf(dec_f(gmin[NB + b]), 1e-12f), 50.f));
    partial[b] = s2[0] / (float)NP + s1[0] / nv + 0.4f * (ming_pt + ming_rgb);
  }
}

// ---------------------------------------------------------------------------
// final tiny reduction. 1 block of 64.
// ---------------------------------------------------------------------------
__global__ void final_kernel(const float* __restrict__ partial, float* __restrict__ out) {
  const int lane = threadIdx.x & 63;
  float v = (lane < NB) ? partial[lane] : 0.f;
  for (int sft = 1; sft < 64; sft <<= 1) v += __shfl_xor(v, sft, 64);
  if (lane == 0) out[0] = 0.9f * v / (float)NB;
}

// ---------------------------------------------------------------------------
// FALLBACK path kernels (ws too small): fp32->bf16 pipeline
// ---------------------------------------------------------------------------
__global__ __launch_bounds__(256) void bank_norms_kernel(
    const float* __restrict__ bank_pt, const float* __restrict__ bank_rgb,
    float* __restrict__ bn_pt, float* __restrict__ bn_rgb) {
  const int branch = blockIdx.y;
  const float* bank = branch ? bank_rgb : bank_pt;
  float* bn = branch ? bn_rgb : bn_pt;
  const int D = branch ? DRG : DPT;
  const int w = threadIdx.x >> 6, lane = threadIdx.x & 63;
  const int row = blockIdx.x * 4 + w;
  const float2* rp = (const float2*)(bank + (size_t)row * D);
  const int cnt = D >> 7;
  float s = 0.f;
  for (int i = 0; i < cnt; ++i) {
    float2 v = rp[lane + 64 * i];
    s += v.x * v.x + v.y * v.y;
  }
  for (int sft = 1; sft < 64; sft <<= 1) s += __shfl_xor(s, sft, 64);
  if (lane == 0) bn[row] = s;
}

__global__ __launch_bounds__(256) void prep_fb_kernel(
    const float* __restrict__ feat_pt, const float* __restrict__ feat_rgb,
    const int* __restrict__ valid_mask,
    float* __restrict__ xx_pt, float* __restrict__ xx_rgb,
    float* __restrict__ gs_pt, float* __restrict__ gs_rgb) {
  const int b = blockIdx.y;
  const int w = threadIdx.x >> 6, lane = threadIdx.x & 63;
  float2 gp[9], gr[6];
#pragma unroll
  for (int i = 0; i < 9; ++i) gp[i] = make_float2(0.f, 0.f);
#pragma unroll
  for (int i = 0; i < 6; ++i) gr[i] = make_float2(0.f, 0.f);
  const int pbase = blockIdx.x * 16 + w * 4;
#pragma unroll
  for (int pi = 0; pi < 4; ++pi) {
    const int p = pbase + pi;
    const float msk = (float)valid_mask[b * NP + p];
    const float2* xr = (const float2*)(feat_pt + ((size_t)b * NP + p) * DPT);
    float s = 0.f;
#pragma unroll
    for (int i = 0; i < 9; ++i) {
      float2 v = xr[lane + 64 * i];
      s += v.x * v.x + v.y * v.y;
      gp[i].x += msk * v.x; gp[i].y += msk * v.y;
    }
    const float2* rr = (const float2*)(feat_rgb + ((size_t)b * NP + p) * DRG);
    float s2 = 0.f;
#pragma unroll
    for (int i = 0; i < 6; ++i) {
      float2 v = rr[lane + 64 * i];
      s2 += v.x * v.x + v.y * v.y;
      gr[i].x += msk * v.x; gr[i].y += msk * v.y;
    }
    for (int sft = 1; sft < 64; sft <<= 1) {
      s += __shfl_xor(s, sft, 64);
      s2 += __shfl_xor(s2, sft, 64);
    }
    if (lane == 0) {
      xx_pt[b * NP + p] = s;
      xx_rgb[b * NP + p] = s2;
    }
  }
#pragma unroll
  for (int i = 0; i < 9; ++i) {
    int d = 2 * (lane + 64 * i);
    atomicAdd(&gs_pt[b * DPT + d], gp[i].x);
    atomicAdd(&gs_pt[b * DPT + d + 1], gp[i].y);
  }
#pragma unroll
  for (int i = 0; i < 6; ++i) {
    int d = 2 * (lane + 64 * i);
    atomicAdd(&gs_rgb[b * DRG + d], gr[i].x);
    atomicAdd(&gs_rgb[b * DRG + d + 1], gr[i].y);
  }
}

__global__ __launch_bounds__(256) void gemm_min_kernel(
    const float* __restrict__ feat_pt, const float* __restrict__ feat_rgb,
    const float* __restrict__ bank_pt, const float* __restrict__ bank_rgb,
    const float* __restrict__ bn_pt, const float* __restrict__ bn_rgb,
    const int* __restrict__ classlabels,
    unsigned* __restrict__ mc_pt, unsigned* __restrict__ mc_rgb) {
  const int branch = blockIdx.z;
  const int b = blockIdx.y;
  const int ptile = blockIdx.x % 7;
  const int mchunk = blockIdx.x / 7;
  const int D = branch ? DRG : DPT;
  const float* feat = branch ? feat_rgb : feat_pt;
  const float* bank = branch ? bank_rgb : bank_pt;
  const float* bn = branch ? bn_rgb : bn_pt;
  unsigned* mc = branch ? mc_rgb : mc_pt;
  const int cls = classlabels[b];

  __shared__ __align__(16) unsigned short As[128 * 32];
  __shared__ __align__(16) unsigned short Bs2[128 * 32];

  const int tid = threadIdx.x;
  const int r = tid >> 1;
  const int h = tid & 1;
  const int p0 = ptile * 128;
  const int prow = (p0 + r < NP) ? (p0 + r) : (NP - 1);
  const float* Arow = feat + ((size_t)b * NP + prow) * D + h * 16;
  const float* BankC = bank + (size_t)cls * NM * D;
  const float* bnC = bn + cls * NM;
  const int swz = (r >> 1) & 3;
  const int wo0 = r * 32 + ((2 * h) ^ swz) * 8;
  const int wo1 = r * 32 + ((2 * h + 1) ^ swz) * 8;

  const int lane = tid & 63;
  const int w = tid >> 6;
  const int wr = w >> 1, wcq = w & 1;
  const int lrow = lane & 15, lk = lane >> 4;
  int aoff[4], boff[4];
#pragma unroll
  for (int i = 0; i < 4; ++i) {
    int row = wr * 64 + i * 16 + lrow;
    aoff[i] = row * 32 + (lk ^ ((row >> 1) & 3)) * 8;
    row = wcq * 64 + i * 16 + lrow;
    boff[i] = row * 32 + (lk ^ ((row >> 1) & 3)) * 8;
  }

  float rm[4][4];
#pragma unroll
  for (int i = 0; i < 4; ++i)
#pragma unroll
    for (int e = 0; e < 4; ++e) rm[i][e] = 1e30f;

  union V16 { unsigned short s[8]; float4 v; };

#pragma unroll 1
  for (int mt = 0; mt < 8; ++mt) {
    const int mbase = mchunk * 1024 + mt * 128;
    const float* Brow = BankC + (size_t)(mbase + r) * D + h * 16;
    f32x4 acc[4][4];
#pragma unroll
    for (int i = 0; i < 4; ++i)
#pragma unroll
      for (int j = 0; j < 4; ++j) acc[i][j] = (f32x4){0.f, 0.f, 0.f, 0.f};

#pragma unroll 1
    for (int k0 = 0; k0 < D; k0 += 32) {
      __syncthreads();
      {
        const float4* ga = (const float4*)(Arow + k0);
        float4 f0 = ga[0], f1 = ga[1], f2 = ga[2], f3 = ga[3];
        V16 u0, u1;
        u0.s[0] = f2bf(f0.x); u0.s[1] = f2bf(f0.y); u0.s[2] = f2bf(f0.z); u0.s[3] = f2bf(f0.w);
        u0.s[4] = f2bf(f1.x); u0.s[5] = f2bf(f1.y); u0.s[6] = f2bf(f1.z); u0.s[7] = f2bf(f1.w);
        u1.s[0] = f2bf(f2.x); u1.s[1] = f2bf(f2.y); u1.s[2] = f2bf(f2.z); u1.s[3] = f2bf(f2.w);
        u1.s[4] = f2bf(f3.x); u1.s[5] = f2bf(f3.y); u1.s[6] = f2bf(f3.z); u1.s[7] = f2bf(f3.w);
        *(float4*)&As[wo0] = u0.v;
        *(float4*)&As[wo1] = u1.v;
      }
      {
        const float4* gb = (const float4*)(Brow + k0);
        float4 f0 = gb[0], f1 = gb[1], f2 = gb[2], f3 = gb[3];
        V16 u0, u1;
        u0.s[0] = f2bf(f0.x); u0.s[1] = f2bf(f0.y); u0.s[2] = f2bf(f0.z); u0.s[3] = f2bf(f0.w);
        u0.s[4] = f2bf(f1.x); u0.s[5] = f2bf(f1.y); u0.s[6] = f2bf(f1.z); u0.s[7] = f2bf(f1.w);
        u1.s[0] = f2bf(f2.x); u1.s[1] = f2bf(f2.y); u1.s[2] = f2bf(f2.z); u1.s[3] = f2bf(f2.w);
        u1.s[4] = f2bf(f3.x); u1.s[5] = f2bf(f3.y); u1.s[6] = f2bf(f3.z); u1.s[7] = f2bf(f3.w);
        *(float4*)&Bs2[wo0] = u0.v;
        *(float4*)&Bs2[wo1] = u1.v;
      }
      __syncthreads();
      bf16x8 af[4], bfv[4];
#pragma unroll
      for (int i = 0; i < 4; ++i) {
        af[i] = *(const bf16x8*)&As[aoff[i]];
        bfv[i] = *(const bf16x8*)&Bs2[boff[i]];
      }
#pragma unroll
      for (int i = 0; i < 4; ++i)
#pragma unroll
        for (int j = 0; j < 4; ++j)
          acc[i][j] = __builtin_amdgcn_mfma_f32_16x16x32_bf16(af[i], bfv[j], acc[i][j], 0, 0, 0);
    }
#pragma unroll
    for (int j = 0; j < 4; ++j) {
      float bnv = bnC[mbase + wcq * 64 + j * 16 + lrow];
#pragma unroll
      for (int i = 0; i < 4; ++i)
#pragma unroll
        for (int e = 0; e < 4; ++e)
          rm[i][e] = fminf(rm[i][e], bnv - 2.0f * acc[i][j][e]);
    }
  }
#pragma unroll
  for (int s = 1; s < 16; s <<= 1)
#pragma unroll
    for (int i = 0; i < 4; ++i)
#pragma unroll
      for (int e = 0; e < 4; ++e)
        rm[i][e] = fminf(rm[i][e], __shfl_xor(rm[i][e], s, 64));
  if (lrow == 0) {
#pragma unroll
    for (int i = 0; i < 4; ++i)
#pragma unroll
      for (int e = 0; e < 4; ++e) {
        int p = p0 + wr * 64 + i * 16 + lk * 4 + e;
        if (p < NP) atomicMin(&mc[b * NP + p], enc_f(rm[i][e]));
      }
  }
}

__global__ __launch_bounds__(256) void gdist_fb_kernel(
    const float* __restrict__ bgp, const float* __restrict__ bgr,
    const float* __restrict__ gs_pt, const float* __restrict__ gs_rgb,
    const int* __restrict__ classlabels, const int* __restrict__ valid_mask,
    const float* __restrict__ xx_pt, const float* __restrict__ xx_rgb,
    const unsigned* __restrict__ mc_pt, const unsigned* __restrict__ mc_rgb,
    float* __restrict__ partial) {
  const int b = blockIdx.x;
  const int tid = threadIdx.x;
  const int w = tid >> 6, lane = tid & 63;
  __shared__ float sred[256], sred2[256], sred3[256];
  __shared__ float gsh[DPT];
  __shared__ float wmin[4];
  float nvi = 0.f, spt = 0.f, srgb = 0.f;
  for (int p = tid; p < NP; p += 256) {
    float m = (float)valid_mask[b * NP + p];
    nvi += m;
    float dpt = xx_pt[b * NP + p] + dec_f(mc_pt[b * NP + p]);
    dpt = sqrtf(fminf(fmaxf(dpt, 1e-12f), 50.f));
    float drg = xx_rgb[b * NP + p] + dec_f(mc_rgb[b * NP + p]);
    drg = sqrtf(fminf(fmaxf(drg, 1e-12f), 50.f));
    spt += m * dpt;
    srgb += drg;
  }
  sred[tid] = nvi; sred2[tid] = spt; sred3[tid] = srgb;
  __syncthreads();
  for (int s = 128; s > 0; s >>= 1) {
    if (tid < s) {
      sred[tid] += sred[tid + s];
      sred2[tid] += sred2[tid + s];
      sred3[tid] += sred3[tid + s];
    }
    __syncthreads();
  }
  const float nv = sred[0];
  const float mean_pt = sred2[0] / nv;
  const float mean_rgb = sred3[0] / (float)NP;
  const int cls = classlabels[b];
  float ming_pt, ming_rgb;
  for (int d = tid; d < DPT; d += 256) gsh[d] = gs_pt[b * DPT + d] / nv;
  __syncthreads();
  {
    float mn = 1e30f;
    for (int row = w; row < NMG; row += 4) {
      const float2* yr = (const float2*)(bgp + ((size_t)cls * NMG + row) * DPT);
      float s = 0.f;
#pragma unroll
      for (int i = 0; i < 9; ++i) {
        float2 y = yr[lane + 64 * i];
        int d = 2 * (lane + 64 * i);
        float dx = gsh[d] - y.x, dy = gsh[d + 1] - y.y;
        s += dx * dx + dy * dy;
      }
      for (int sft = 1; sft < 64; sft <<= 1) s += __shfl_xor(s, sft, 64);
      mn = fminf(mn, s);
    }
    if (lane == 0) wmin[w] = mn;
    __syncthreads();
    float m2 = fminf(fminf(wmin[0], wmin[1]), fminf(wmin[2], wmin[3]));
    ming_pt = sqrtf(fminf(fmaxf(m2, 1e-12f), 50.f));
    __syncthreads();
  }
  for (int d = tid; d < DRG; d += 256) gsh[d] = gs_rgb[b * DRG + d] / nv;
  __syncthreads();
  {
    float mn = 1e30f;
    for (int row = w; row < NMG; row += 4) {
      const float2* yr = (const float2*)(bgr + ((size_t)cls * NMG + row) * DRG);
      float s = 0.f;
#pragma unroll
      for (int i = 0; i < 6; ++i) {
        float2 y = yr[lane + 64 * i];
        int d = 2 * (lane + 64 * i);
        float dx = gsh[d] - y.x, dy = gsh[d + 1] - y.y;
        s += dx * dx + dy * dy;
      }
      for (int sft = 1; sft < 64; sft <<= 1) s += __shfl_xor(s, sft, 64);
      mn = fminf(mn, s);
    }
    if (lane == 0) wmin[w] = mn;
    __syncthreads();
    float m2 = fminf(fminf(wmin[0], wmin[1]), fminf(wmin[2], wmin[3]));
    ming_rgb = sqrtf(fminf(fmaxf(m2, 1e-12f), 50.f));
  }
  if (tid == 0)
    partial[b] = mean_rgb + mean_pt + 0.4f * (ming_pt + ming_rgb);
}

// ---------------------------------------------------------------------------
extern "C" void kernel_launch(void* const* d_in, const int* in_sizes, int n_in,
                              void* d_out, int out_size, void* d_ws, size_t ws_size,
                              hipStream_t stream) {
  const float* feat_pt = (const float*)d_in[0];
  const float* feat_rgb = (const float*)d_in[1];
  const float* bank_pt = (const float*)d_in[2];
  const float* bank_rgb = (const float*)d_in[3];
  const float* bgp = (const float*)d_in[4];
  const float* bgr = (const float*)d_in[5];
  const int* classlabels = (const int*)d_in[6];
  const int* valid_mask = (const int*)d_in[7];
  float* out = (float*)d_out;

  const size_t BBP = (size_t)NC * NM * DPT;   // bank fp8 bytes
  const size_t BBR = (size_t)NC * NM * DRG;
  const size_t FBP = (size_t)NB * NP * DPT;   // feature fp8 bytes
  const size_t FBR = (size_t)NB * NP * DRG;
  const size_t GSPART = (size_t)NB * 49 * DTOT;  // 1.5M floats
  const size_t SMALL_WORDS = 4 * (size_t)NC * NM + 8 * (size_t)NB * NP +
                             GSPART + 8 * NB + 2 * NC + 256;
  const size_t NEED = (BBP + BBR + FBP + FBR) + 4 * SMALL_WORDS;
  const bool fast = (ws_size >= NEED);

  if (fast) {
    unsigned char* b8_pt = (unsigned char*)d_ws;
    unsigned char* b8_rgb = b8_pt + BBP;
    unsigned char* f8_pt = b8_rgb + BBR;
    unsigned char* f8_rgb = f8_pt + FBP;
    float* fl = (float*)(f8_rgb + FBR);
    float* bn_pt = fl;                          // NC*NM
    float* bn_rgb = bn_pt + NC * NM;
    float* bnS_pt = bn_rgb + NC * NM;           // NC*NM
    float* bnS_rgb = bnS_pt + NC * NM;
    float* xx_pt = bnS_rgb + NC * NM;           // NB*NP
    float* xx_rgb = xx_pt + NB * NP;
    float* xxS_pt = xx_rgb + NB * NP;
    float* xxS_rgb = xxS_pt + NB * NP;
    float* gs_part = xxS_rgb + NB * NP;         // NB*49*DTOT
    unsigned* mc_pt = (unsigned*)(gs_part + GSPART);
    unsigned* mc_rgb = mc_pt + NB * NP;
    unsigned* pmc_pt = mc_rgb + NB * NP;
    unsigned* pmc_rgb = pmc_pt + NB * NP;
    float* partial = (float*)(pmc_rgb + NB * NP);   // NB
    float* nvArr = partial + NB;                    // NB
    unsigned* gmin = (unsigned*)(nvArr + NB);       // 2*NB
    unsigned* flagF = gmin + 2 * NB;                // 2*NB
    unsigned* classFlag = flagF + 2 * NB;           // NC
    unsigned* present = classFlag + NC;             // NC

    init_kernel<<<64, 256, 0, stream>>>(classlabels, nvArr, mc_pt, gmin,
                                        flagF, classFlag, present);
    fused_cp_kernel<<<2064, 256, 0, stream>>>(
        feat_pt, feat_rgb, bank_pt, bank_rgb, valid_mask,
        xx_pt, xx_rgb, xxS_pt, xxS_rgb, gs_part, nvArr,
        f8_pt, f8_rgb, b8_pt, b8_rgb, bnS_pt, bnS_rgb, present);
    fused_g1_kernel<<<1280, 256, 0, stream>>>(
        f8_pt, f8_rgb, b8_pt, b8_rgb, bnS_pt, bnS_rgb, classlabels,
        pmc_pt, pmc_rgb, bgp, bgr, gs_part, nvArr, gmin);
    flag_kernel<<<32, 256, 0, stream>>>(
        xxS_pt, xxS_rgb, pmc_pt, pmc_rgb, classlabels, flagF, classFlag);
    fullconv_kernel<<<2064, 256, 0, stream>>>(
        bank_pt, bank_rgb, feat_pt, feat_rgb, b8_pt, b8_rgb, f8_pt, f8_rgb,
        bn_pt, bn_rgb, classFlag, flagF);
    gemm2_kernel<<<dim3(64, NB), 256, 0, stream>>>(
        f8_pt, f8_rgb, b8_pt, b8_rgb, bn_pt, bn_rgb, classlabels, flagF, mc_pt, mc_rgb);
    gdistB_kernel<<<NB, 256, 0, stream>>>(
        valid_mask, xx_pt, xx_rgb, mc_pt, mc_rgb, nvArr, gmin, partial);
    final_kernel<<<1, 64, 0, stream>>>(partial, out);
  } else {
    float* ws = (float*)d_ws;
    float* bn_pt = ws;
    float* bn_rgb = bn_pt + NC * NM;
    float* xx_pt = bn_rgb + NC * NM;
    float* xx_rgb = xx_pt + NB * NP;
    float* gs_pt = xx_rgb + NB * NP;
    float* gs_rgb = gs_pt + NB * DPT;
    unsigned* mc_pt = (unsigned*)(gs_rgb + NB * DRG);
    unsigned* mc_rgb = mc_pt + NB * NP;
    float* partial = (float*)(mc_rgb + NB * NP);

    hipMemsetAsync(gs_pt, 0, (size_t)(NB * DPT + NB * DRG) * 4, stream);
    hipMemsetAsync(mc_pt, 0xF7, (size_t)(2 * NB * NP) * 4, stream);

    bank_norms_kernel<<<dim3(NC * NM / 4, 2), 256, 0, stream>>>(bank_pt, bank_rgb, bn_pt, bn_rgb);
    prep_fb_kernel<<<dim3(49, NB), 256, 0, stream>>>(
        feat_pt, feat_rgb, valid_mask, xx_pt, xx_rgb, gs_pt, gs_rgb);
    gemm_min_kernel<<<dim3(28, NB, 2), 256, 0, stream>>>(
        feat_pt, feat_rgb, bank_pt, bank_rgb, bn_pt, bn_rgb, classlabels, mc_pt, mc_rgb);
    gdist_fb_kernel<<<NB, 256, 0, stream>>>(bgp, bgr, gs_pt, gs_rgb, classlabels, valid_mask,
                                            xx_pt, xx_rgb, mc_pt, mc_rgb, partial);
    final_kernel<<<1, 64, 0, stream>>>(partial, out);
  }
}

// Round 17
// 161.178 us; speedup vs baseline: 1.2566x; 1.2566x over previous
//
#include <hip/hip_runtime.h>
#include <hip/hip_bf16.h>

// Problem constants (match reference)
#define NB 16
#define NP 784
#define NC 10
#define NM 4096
#define NMG 128
#define DPT 1152
#define DRG 768
#define DTOT (DPT + DRG)   // 1920

typedef __attribute__((ext_vector_type(8))) short bf16x8;    // 8 bf16 (4 VGPR)
typedef __attribute__((ext_vector_type(4))) float f32x4;     // 16x16 MFMA acc
typedef __attribute__((ext_vector_type(4))) int i32x4;
typedef __attribute__((ext_vector_type(8))) int i32x8;

#define SONE 0x7F7F7F7F   // e8m0 scale = 1.0 in every byte
#define SKIP_THR 70.0f    // clamp(50) + fp8-quantization guard band

__device__ __forceinline__ unsigned short f2bf(float f) {
  unsigned u = __float_as_uint(f);
  return (unsigned short)((u + 0x7fffu + ((u >> 16) & 1u)) >> 16); // RNE
}
// order-preserving float->uint encoding (for atomicMin on float values)
__device__ __forceinline__ unsigned enc_f(float f) {
  unsigned u = __float_as_uint(f);
  return (u & 0x80000000u) ? ~u : (u | 0x80000000u);
}
__device__ __forceinline__ float dec_f(unsigned u) {
  return __uint_as_float((u & 0x80000000u) ? (u & 0x7fffffffu) : ~u);
}
// async global->LDS, 16B per lane. LDS dest must be wave-uniform (HW adds lane*16).
__device__ __forceinline__ void gl_lds16(const void* g, void* s) {
  __builtin_amdgcn_global_load_lds(
      (const __attribute__((address_space(1))) unsigned int*)g,
      (__attribute__((address_space(3))) unsigned int*)s, 16, 0, 0);
}

// ---------------------------------------------------------------------------
// init: zero nv/flags, sentinel mc/pmc/gmin, compute present[]. grid 64x256.
// (gs_part needs no init: prep fully overwrites it.)
// ---------------------------------------------------------------------------
__global__ __launch_bounds__(256) void init_kernel(
    const int* __restrict__ cl, float* __restrict__ nvArr,
    unsigned* __restrict__ mc, unsigned* __restrict__ gmin,
    unsigned* __restrict__ flagF, unsigned* __restrict__ classFlag,
    unsigned* __restrict__ present) {
  const int tid = blockIdx.x * 256 + threadIdx.x;
  const int stride = gridDim.x * 256;
  const int total_mc = 4 * NB * NP;           // 50176 words (mc + pmc)
  // 0xF7F7F7F7 decodes (enc_f inverse) to ~+6e33: finite, > any candidate
  for (int i = tid; i < total_mc; i += stride) mc[i] = 0xF7F7F7F7u;
  if (tid < NB) nvArr[tid] = 0.f;
  if (tid < 2 * NB) gmin[tid] = 0xF7F7F7F7u;
  if (tid < 2 * NB) flagF[tid] = 0u;
  if (tid < NC) classFlag[tid] = 0u;
  if (blockIdx.x == 0) {
    if (threadIdx.x < NC) present[threadIdx.x] = 0u;
    __syncthreads();
    if (threadIdx.x < NB) present[cl[threadIdx.x]] = 1u;
  }
}

// ---------------------------------------------------------------------------
// FUSED convert128 + prep: independent passes run concurrently in one grid.
//  blk [0,784): prep — patch norms (full + first-128) + masked global-sum
//               PARTIALS (LDS cross-wave reduce, NO gs atomics) + nv
//               + fp8 convert of first 128 dims.
//  blk [784,2064): bank fp32 -> fp8 first 128 dims + partial norms, 64 rows
//               per block (gated on present).
// ---------------------------------------------------------------------------
__global__ __launch_bounds__(256) void fused_cp_kernel(
    const float* __restrict__ feat_pt, const float* __restrict__ feat_rgb,
    const float* __restrict__ bank_pt, const float* __restrict__ bank_rgb,
    const int* __restrict__ valid_mask,
    float* __restrict__ xx_pt, float* __restrict__ xx_rgb,
    float* __restrict__ xxS_pt, float* __restrict__ xxS_rgb,
    float* __restrict__ gs_part,   // [NB][49][DTOT]
    float* __restrict__ nvArr,
    unsigned char* __restrict__ f8_pt, unsigned char* __restrict__ f8_rgb,
    unsigned char* __restrict__ b8_pt, unsigned char* __restrict__ b8_rgb,
    float* __restrict__ bnS_pt, float* __restrict__ bnS_rgb,
    const unsigned* __restrict__ present) {
  __shared__ float accL[4][DTOT];   // 30 KB (prep blocks only)
  const int blk = blockIdx.x;
  const int w = threadIdx.x >> 6, lane = threadIdx.x & 63;
  if (blk < 784) {
    const int b = blk / 49, xb = blk % 49;
    float2 gp[9], gr[6];
#pragma unroll
    for (int i = 0; i < 9; ++i) gp[i] = make_float2(0.f, 0.f);
#pragma unroll
    for (int i = 0; i < 6; ++i) gr[i] = make_float2(0.f, 0.f);
    const int pbase = xb * 16 + w * 4;
    float mcount = 0.f;
#pragma unroll
    for (int pi = 0; pi < 4; ++pi) {
      const int p = pbase + pi;
      const float msk = (float)valid_mask[b * NP + p];
      mcount += msk;
      const float2* xr = (const float2*)(feat_pt + ((size_t)b * NP + p) * DPT);
      unsigned short* xw = (unsigned short*)(f8_pt + ((size_t)b * NP + p) * DPT);
      float s = 0.f, sp = 0.f;
#pragma unroll
      for (int i = 0; i < 9; ++i) {
        float2 v = xr[lane + 64 * i];
        float c2 = v.x * v.x + v.y * v.y;
        s += c2;
        if (i == 0) {
          sp = c2;   // dims 0..127
          int pk = __builtin_amdgcn_cvt_pk_fp8_f32(v.x, v.y, 0, false);
          xw[lane] = (unsigned short)(pk & 0xFFFF);
        }
        gp[i].x += msk * v.x; gp[i].y += msk * v.y;
      }
      const float2* rr = (const float2*)(feat_rgb + ((size_t)b * NP + p) * DRG);
      unsigned short* rw = (unsigned short*)(f8_rgb + ((size_t)b * NP + p) * DRG);
      float s2 = 0.f, sp2 = 0.f;
#pragma unroll
      for (int i = 0; i < 6; ++i) {
        float2 v = rr[lane + 64 * i];
        float c2 = v.x * v.x + v.y * v.y;
        s2 += c2;
        if (i == 0) {
          sp2 = c2;  // dims 0..127
          int pk = __builtin_amdgcn_cvt_pk_fp8_f32(v.x, v.y, 0, false);
          rw[lane] = (unsigned short)(pk & 0xFFFF);
        }
        gr[i].x += msk * v.x; gr[i].y += msk * v.y;
      }
      for (int sft = 1; sft < 64; sft <<= 1) {
        s += __shfl_xor(s, sft, 64);
        s2 += __shfl_xor(s2, sft, 64);
        sp += __shfl_xor(sp, sft, 64);
        sp2 += __shfl_xor(sp2, sft, 64);
      }
      if (lane == 0) {
        xx_pt[b * NP + p] = s;
        xx_rgb[b * NP + p] = s2;
        xxS_pt[b * NP + p] = sp;
        xxS_rgb[b * NP + p] = sp2;
      }
    }
    if (lane == 0) atomicAdd(&nvArr[b], mcount);
    // per-wave rows into LDS (conflict-free float2 stores), then 4->1 reduce
#pragma unroll
    for (int i = 0; i < 9; ++i)
      *(float2*)&accL[w][2 * (lane + 64 * i)] = gp[i];
#pragma unroll
    for (int i = 0; i < 6; ++i)
      *(float2*)&accL[w][DPT + 2 * (lane + 64 * i)] = gr[i];
    __syncthreads();
    float* dst = gs_part + ((size_t)b * 49 + xb) * DTOT;
    for (int e = threadIdx.x; e < DTOT; e += 256)
      dst[e] = accL[0][e] + accL[1][e] + accL[2][e] + accL[3][e];
  } else {
    const int cb = blk - 784;          // 0..1279
    const int branch = cb & 1;
    const int grp = cb >> 1;           // 0..639
    const int c = grp >> 6;
    if (present[c] == 0u) return;
    const int rch = grp & 63;
    const float* bank = branch ? bank_rgb : bank_pt;
    unsigned char* b8 = branch ? b8_rgb : b8_pt;
    float* bnS = branch ? bnS_rgb : bnS_pt;
    const int D = branch ? DRG : DPT;
#pragma unroll 1
    for (int rl = 0; rl < 16; ++rl) {
      const int row = (c << 12) + rch * 64 + w * 16 + rl;
      const float2* rp = (const float2*)(bank + (size_t)row * D);
      unsigned short* dp = (unsigned short*)(b8 + (size_t)row * D);
      float2 v = rp[lane];
      float s = v.x * v.x + v.y * v.y;
      int pk = __builtin_amdgcn_cvt_pk_fp8_f32(v.x, v.y, 0, false);
      dp[lane] = (unsigned short)(pk & 0xFFFF);
      for (int sft = 1; sft < 64; sft <<= 1) s += __shfl_xor(s, sft, 64);
      if (lane == 0) bnS[row] = s;
    }
  }
}

// ---------------------------------------------------------------------------
// FUSED gemm1 + gdistA: independent, run concurrently.
//  blk [0,1024): certificate GEMM (partial min over first 128 dims), B in
//               VGPRs, A 2-deep prefetch with counted vmcnt(4).
//  blk [1024,1280): global-bank min (gdistA); builds gsh by summing the 49
//               gs partials with ILP-parallel accumulators (49 loads in
//               flight — the R16 serial chain was the 124us tail).
// ---------------------------------------------------------------------------
__global__ __launch_bounds__(256) void fused_g1_kernel(
    const unsigned char* __restrict__ f8_pt, const unsigned char* __restrict__ f8_rgb,
    const unsigned char* __restrict__ b8_pt, const unsigned char* __restrict__ b8_rgb,
    const float* __restrict__ bnS_pt, const float* __restrict__ bnS_rgb,
    const int* __restrict__ classlabels,
    unsigned* __restrict__ pmc_pt, unsigned* __restrict__ pmc_rgb,
    const float* __restrict__ bgp, const float* __restrict__ bgr,
    const float* __restrict__ gs_part, const float* __restrict__ nvArr,
    unsigned* __restrict__ gmin) {
  __shared__ __align__(16) unsigned char As[2][16384];
  __shared__ __align__(16) unsigned char Bs[16384];
  const int blk = blockIdx.x;
  const int t = threadIdx.x;
  const int w = t >> 6, lane = t & 63;

  if (blk >= 1024) {
    // ---- gdistA ----
    const int g = blk - 1024;          // 0..255
    const int slice = g & 7;
    const int b = (g >> 3) & 15;
    const int branch = g >> 7;
    const int D = branch ? DRG : DPT;
    const int base = branch ? DPT : 0;
    const float* bank = branch ? bgr : bgp;
    const int cls = classlabels[b];
    float* gsh = (float*)&As[0][0];    // reuse LDS
    const float inv = 1.f / nvArr[b];
    const float* gp0 = gs_part + (size_t)b * 49 * DTOT + base;
    // ILP-parallel 49-partial reduce: 4 accumulators, fully unrolled ->
    // all 49 loads in flight per element (R16's unroll-1 serial chain
    // exposed ~600cyc x49 latency per element = the 124us tail).
    for (int d = t; d < D; d += 256) {
      const float* p = gp0 + d;
      float s0 = 0.f, s1 = 0.f, s2 = 0.f, s3 = 0.f;
#pragma unroll
      for (int k = 0; k < 48; k += 4) {
        s0 += p[(size_t)k * DTOT];
        s1 += p[(size_t)(k + 1) * DTOT];
        s2 += p[(size_t)(k + 2) * DTOT];
        s3 += p[(size_t)(k + 3) * DTOT];
      }
      s0 += p[(size_t)48 * DTOT];
      gsh[d] = (s0 + s1 + s2 + s3) * inv;
    }
    __syncthreads();
    const int cnt = D >> 7;
    float mn = 1e30f;
#pragma unroll 1
    for (int rl = 0; rl < 4; ++rl) {
      const int row = slice * 16 + w * 4 + rl;
      const float2* yr = (const float2*)(bank + ((size_t)cls * NMG + row) * D);
      float s = 0.f;
      for (int i = 0; i < cnt; ++i) {
        float2 y = yr[lane + 64 * i];
        int d = 2 * (lane + 64 * i);
        float dx = gsh[d] - y.x, dy = gsh[d + 1] - y.y;
        s += dx * dx + dy * dy;
      }
      for (int sft = 1; sft < 64; sft <<= 1) s += __shfl_xor(s, sft, 64);
      mn = fminf(mn, s);
    }
    if (lane == 0) atomicMin(&gmin[branch * NB + b], enc_f(mn));
    return;
  }

  // ---- gemm1 ----
  const int branch = blk & 1;
  const int mch = (blk >> 1) & 31;
  const int b = blk >> 6;
  const int D = branch ? DRG : DPT;
  const unsigned char* f8 = branch ? f8_rgb : f8_pt;
  const unsigned char* b8 = branch ? b8_rgb : b8_pt;
  const float* bnS = branch ? bnS_rgb : bnS_pt;
  unsigned* pmc = branch ? pmc_rgb : pmc_pt;
  const int cls = classlabels[b];

  const unsigned char* fB = f8 + (size_t)b * NP * D;
  const unsigned char* bB = b8 + (size_t)cls * NM * D;
  const int mbase = mch * 128;

  int rr[4], cx[4];
#pragma unroll
  for (int i = 0; i < 4; ++i) {
    int pos = w * 256 + i * 64 + lane;
    rr[i] = pos >> 3;
    cx[i] = ((pos & 7) ^ (rr[i] & 7)) << 4;
  }
  const int wr = w >> 1, wcq = w & 1;
  const int lrow = lane & 15, lk = lane >> 4;
  int aoff0[4], aoff1[4], boff0[4], boff1[4];
#pragma unroll
  for (int i = 0; i < 4; ++i) {
    int ra = wr * 64 + i * 16 + lrow;
    aoff0[i] = ra * 128 + ((lk * 32) ^ ((ra & 7) << 4));
    aoff1[i] = ra * 128 + ((lk * 32 + 16) ^ ((ra & 7) << 4));
    int rb = wcq * 64 + i * 16 + lrow;
    boff0[i] = rb * 128 + ((lk * 32) ^ ((rb & 7) << 4));
    boff1[i] = rb * 128 + ((lk * 32 + 16) ^ ((rb & 7) << 4));
  }
  float bnv[4];
#pragma unroll
  for (int j = 0; j < 4; ++j)
    bnv[j] = bnS[cls * NM + mbase + wcq * 64 + j * 16 + lrow];

  auto STAGE_A = [&](int pt, int buf) {
#pragma unroll
    for (int i = 0; i < 4; ++i) {
      int pr = pt * 128 + rr[i];
      if (pr > NP - 1) pr = NP - 1;
      gl_lds16(fB + (size_t)pr * D + cx[i], &As[buf][0] + (w * 4 + i) * 1024);
    }
  };

  // prologue: stage B, A(0), A(1)   -> ledger: B(4), A0(4), A1(4)
#pragma unroll
  for (int i = 0; i < 4; ++i)
    gl_lds16(bB + (size_t)(mbase + rr[i]) * D + cx[i], &Bs[0] + (w * 4 + i) * 1024);
  STAGE_A(0, 0);
  STAGE_A(1, 1);
  asm volatile("s_waitcnt vmcnt(8)" ::: "memory");   // B landed
  __builtin_amdgcn_s_barrier();
  __builtin_amdgcn_sched_barrier(0);
  i32x8 bfv[4];
#pragma unroll
  for (int i = 0; i < 4; ++i) {
    i32x4 lo = *(const i32x4*)(&Bs[0] + boff0[i]);
    i32x4 hi = *(const i32x4*)(&Bs[0] + boff1[i]);
    bfv[i] = __builtin_shufflevector(lo, hi, 0, 1, 2, 3, 4, 5, 6, 7);
  }
  asm volatile("s_waitcnt lgkmcnt(0)" ::: "memory");
  __builtin_amdgcn_s_barrier();                      // B reads done
  __builtin_amdgcn_sched_barrier(0);

#pragma unroll 1
  for (int pt = 0; pt < 7; ++pt) {
    const int cur = pt & 1;
    // entry: A(pt) done (A(pt+1) stays in flight)
    asm volatile("s_waitcnt vmcnt(4)" ::: "memory");
    __builtin_amdgcn_s_barrier();
    __builtin_amdgcn_sched_barrier(0);
    i32x8 af[4];
#pragma unroll
    for (int i = 0; i < 4; ++i) {
      i32x4 lo = *(const i32x4*)(&As[cur][0] + aoff0[i]);
      i32x4 hi = *(const i32x4*)(&As[cur][0] + aoff1[i]);
      af[i] = __builtin_shufflevector(lo, hi, 0, 1, 2, 3, 4, 5, 6, 7);
    }
    float rm[4][4];
#pragma unroll
    for (int i = 0; i < 4; ++i) {
      f32x4 a0 = (f32x4){0.f, 0.f, 0.f, 0.f};
      f32x4 a1 = a0, a2 = a0, a3 = a0;
      a0 = __builtin_amdgcn_mfma_scale_f32_16x16x128_f8f6f4(af[i], bfv[0], a0, 0, 0, 0, SONE, 0, SONE);
      a1 = __builtin_amdgcn_mfma_scale_f32_16x16x128_f8f6f4(af[i], bfv[1], a1, 0, 0, 0, SONE, 0, SONE);
      a2 = __builtin_amdgcn_mfma_scale_f32_16x16x128_f8f6f4(af[i], bfv[2], a2, 0, 0, 0, SONE, 0, SONE);
      a3 = __builtin_amdgcn_mfma_scale_f32_16x16x128_f8f6f4(af[i], bfv[3], a3, 0, 0, 0, SONE, 0, SONE);
#pragma unroll
      for (int e = 0; e < 4; ++e) {
        float v = bnv[0] - 2.0f * a0[e];
        v = fminf(v, bnv[1] - 2.0f * a1[e]);
        v = fminf(v, bnv[2] - 2.0f * a2[e]);
        v = fminf(v, bnv[3] - 2.0f * a3[e]);
        rm[i][e] = v;
      }
    }
#pragma unroll
    for (int s2 = 1; s2 < 16; s2 <<= 1)
#pragma unroll
      for (int i = 0; i < 4; ++i)
#pragma unroll
        for (int e = 0; e < 4; ++e)
          rm[i][e] = fminf(rm[i][e], __shfl_xor(rm[i][e], s2, 64));
    if (lrow == 0) {
#pragma unroll
      for (int i = 0; i < 4; ++i)
#pragma unroll
        for (int e = 0; e < 4; ++e) {
          int p = pt * 128 + wr * 64 + i * 16 + lk * 4 + e;
          if (p < NP) atomicMin(&pmc[b * NP + p], enc_f(rm[i][e]));
        }
    }
    // exit: all waves finished reading buf[cur] -> safe to overwrite
    asm volatile("s_waitcnt lgkmcnt(0)" ::: "memory");
    __builtin_amdgcn_sched_barrier(0);
    __builtin_amdgcn_s_barrier();
    if (pt + 2 < 7) STAGE_A(pt + 2, cur);
  }
}

// ---------------------------------------------------------------------------
// Flag kernel. grid: 32 x 256. flags pre-zeroed by init.
// ---------------------------------------------------------------------------
__global__ __launch_bounds__(256) void flag_kernel(
    const float* __restrict__ xxS_pt, const float* __restrict__ xxS_rgb,
    const unsigned* __restrict__ pmc_pt, const unsigned* __restrict__ pmc_rgb,
    const int* __restrict__ classlabels,
    unsigned* __restrict__ flagF, unsigned* __restrict__ classFlag) {
  const int tid = blockIdx.x * 256 + threadIdx.x;
  const int stride = gridDim.x * 256;
  for (int idx = tid; idx < 2 * NB * NP; idx += stride) {
    const int branch = idx / (NB * NP);
    const int rem = idx - branch * NB * NP;
    const int b = rem / NP;
    const float* xxS = branch ? xxS_rgb : xxS_pt;
    const unsigned* pmc = branch ? pmc_rgb : pmc_pt;
    float bound = xxS[rem] + dec_f(pmc[rem]);   // lower bound on full min d^2
    if (bound < SKIP_THR) {
      atomicOr(&flagF[branch * NB + b], 1u);
      atomicOr(&classFlag[classlabels[b]], 1u);
    }
  }
}

// ---------------------------------------------------------------------------
// Full fp8 conversion (fallback only; gated). Flat grid:
//  blocks [0,1280): bank rows, gated classFlag; [1280,2064): features, flagF
// ---------------------------------------------------------------------------
__global__ __launch_bounds__(256) void fullconv_kernel(
    const float* __restrict__ bank_pt, const float* __restrict__ bank_rgb,
    const float* __restrict__ feat_pt, const float* __restrict__ feat_rgb,
    unsigned char* __restrict__ b8_pt, unsigned char* __restrict__ b8_rgb,
    unsigned char* __restrict__ f8_pt, unsigned char* __restrict__ f8_rgb,
    float* __restrict__ bn_pt, float* __restrict__ bn_rgb,
    const unsigned* __restrict__ classFlag, const unsigned* __restrict__ flagF) {
  const int id = blockIdx.x;
  const int w = threadIdx.x >> 6, lane = threadIdx.x & 63;
  if (id < 1280) {
    const int branch = id & 1;
    const int cb = id >> 1;
    const int c = cb >> 6;
    if (classFlag[c] == 0u) return;
    const int rch = cb & 63;
    const float* bank = branch ? bank_rgb : bank_pt;
    unsigned char* b8 = branch ? b8_rgb : b8_pt;
    float* bn = branch ? bn_rgb : bn_pt;
    const int D = branch ? DRG : DPT;
    const int D4 = D >> 2;
#pragma unroll 1
    for (int rl = 0; rl < 16; ++rl) {
      const int row = (c << 12) + rch * 64 + w * 16 + rl;
      const float4* rp = (const float4*)(bank + (size_t)row * D);
      unsigned* dp = (unsigned*)(b8 + (size_t)row * D);
      float s = 0.f;
      for (int i = lane; i < D4; i += 64) {
        float4 v = rp[i];
        s += v.x * v.x + v.y * v.y + v.z * v.z + v.w * v.w;
        int pk = __builtin_amdgcn_cvt_pk_fp8_f32(v.x, v.y, 0, false);
        pk = __builtin_amdgcn_cvt_pk_fp8_f32(v.z, v.w, pk, true);
        dp[i] = (unsigned)pk;
      }
      for (int sft = 1; sft < 64; sft <<= 1) s += __shfl_xor(s, sft, 64);
      if (lane == 0) bn[row] = s;
    }
  } else {
    const int fb = id - 1280;
    const int b = fb / 49, xb = fb % 49;
    if (flagF[b] == 0u && flagF[NB + b] == 0u) return;
    const int pbase = xb * 16 + w * 4;
#pragma unroll 1
    for (int pi = 0; pi < 4; ++pi) {
      const int p = pbase + pi;
      const float2* xr = (const float2*)(feat_pt + ((size_t)b * NP + p) * DPT);
      unsigned short* xw = (unsigned short*)(f8_pt + ((size_t)b * NP + p) * DPT);
#pragma unroll
      for (int i = 0; i < 9; ++i) {
        float2 v = xr[lane + 64 * i];
        int pk = __builtin_amdgcn_cvt_pk_fp8_f32(v.x, v.y, 0, false);
        xw[lane + 64 * i] = (unsigned short)(pk & 0xFFFF);
      }
      const float2* rr = (const float2*)(feat_rgb + ((size_t)b * NP + p) * DRG);
      unsigned short* rw = (unsigned short*)(f8_rgb + ((size_t)b * NP + p) * DRG);
#pragma unroll
      for (int i = 0; i < 6; ++i) {
        float2 v = rr[lane + 64 * i];
        int pk = __builtin_amdgcn_cvt_pk_fp8_f32(v.x, v.y, 0, false);
        rw[lane + 64 * i] = (unsigned short)(pk & 0xFFFF);
      }
    }
  }
}

// ---------------------------------------------------------------------------
// Stage-2 GEMM (fallback, R7 schedule): full-K MX-fp8, gated on flagF.
// grid: (64, NB), block 256.
// ---------------------------------------------------------------------------
__global__ __launch_bounds__(256) void gemm2_kernel(
    const unsigned char* __restrict__ f8_pt, const unsigned char* __restrict__ f8_rgb,
    const unsigned char* __restrict__ b8_pt, const unsigned char* __restrict__ b8_rgb,
    const float* __restrict__ bn_pt, const float* __restrict__ bn_rgb,
    const int* __restrict__ classlabels, const unsigned* __restrict__ flagF,
    unsigned* __restrict__ mc_pt, unsigned* __restrict__ mc_rgb) {
  const int branch = blockIdx.x & 1;
  const int mch = blockIdx.x >> 1;
  const int b = blockIdx.y;
  if (flagF[branch * NB + b] == 0u) return;   // certificate passed: all clamp
  const int D = branch ? DRG : DPT;
  const int NK = D >> 7;
  const unsigned char* f8 = branch ? f8_rgb : f8_pt;
  const unsigned char* b8 = branch ? b8_rgb : b8_pt;
  const float* bn = branch ? bn_rgb : bn_pt;
  unsigned* mc = branch ? mc_rgb : mc_pt;
  const int cls = classlabels[b];

  __shared__ __align__(16) unsigned char As[2][16384];
  __shared__ __align__(16) unsigned char Bs[2][16384];

  const int t = threadIdx.x;
  const int w = t >> 6, lane = t & 63;
  const unsigned char* fB = f8 + (size_t)b * NP * D;
  const unsigned char* bB = b8 + (size_t)cls * NM * D;
  const float* bnC = bn + cls * NM;
  const int mbase = mch * 128;

  int rr[4], cx[4];
  const unsigned char* pA[4];
  const unsigned char* pB[4];
#pragma unroll
  for (int i = 0; i < 4; ++i) {
    int pos = w * 256 + i * 64 + lane;
    rr[i] = pos >> 3;
    cx[i] = ((pos & 7) ^ (rr[i] & 7)) << 4;
    pB[i] = bB + (size_t)(mbase + rr[i]) * D + cx[i];
  }
  const int wr = w >> 1, wcq = w & 1;
  const int lrow = lane & 15, lk = lane >> 4;
  int aoff0[4], aoff1[4], boff0[4], boff1[4];
#pragma unroll
  for (int i = 0; i < 4; ++i) {
    int ra = wr * 64 + i * 16 + lrow;
    aoff0[i] = ra * 128 + ((lk * 32) ^ ((ra & 7) << 4));
    aoff1[i] = ra * 128 + ((lk * 32 + 16) ^ ((ra & 7) << 4));
    int rb = wcq * 64 + i * 16 + lrow;
    boff0[i] = rb * 128 + ((lk * 32) ^ ((rb & 7) << 4));
    boff1[i] = rb * 128 + ((lk * 32 + 16) ^ ((rb & 7) << 4));
  }
  auto mkA = [&](int pt) {
    const int p0 = pt * 128;
#pragma unroll
    for (int i = 0; i < 4; ++i) {
      int pr = p0 + rr[i];
      if (pr > NP - 1) pr = NP - 1;
      pA[i] = fB + (size_t)pr * D + cx[i];
    }
  };
  auto STAGE = [&](int k, int buf) {
    unsigned char* ab = &As[buf][0];
    unsigned char* bb2 = &Bs[buf][0];
#pragma unroll
    for (int i = 0; i < 4; ++i) gl_lds16(pA[i] + k, ab + (w * 4 + i) * 1024);
#pragma unroll
    for (int i = 0; i < 4; ++i) gl_lds16(pB[i] + k, bb2 + (w * 4 + i) * 1024);
  };

  mkA(0);
  STAGE(0, 0);
  int cur = 0;
  int npt = 0, nk = 128;

#pragma unroll 1
  for (int pt = 0; pt < 7; ++pt) {
    float rm[4][4];
    f32x4 acc[4][4];
#pragma unroll
    for (int i = 0; i < 4; ++i)
#pragma unroll
      for (int j = 0; j < 4; ++j) {
        acc[i][j] = (f32x4){0.f, 0.f, 0.f, 0.f};
        rm[i][j] = 1e30f;
      }
#pragma unroll 1
    for (int s = 0; s < NK; ++s) {
      STAGE(nk, cur ^ 1);
      if (npt < 7) {
        nk += 128;
        if (nk == D) { nk = 0; ++npt; if (npt < 7) mkA(npt); else nk = 0; }
      }
      asm volatile("s_waitcnt vmcnt(8)" ::: "memory");
      __builtin_amdgcn_s_barrier();
      __builtin_amdgcn_sched_barrier(0);
      const unsigned char* ab = &As[cur][0];
      const unsigned char* bb2 = &Bs[cur][0];
      i32x8 af[4], bfv[4];
#pragma unroll
      for (int i = 0; i < 4; ++i) {
        i32x4 lo = *(const i32x4*)(ab + aoff0[i]);
        i32x4 hi = *(const i32x4*)(ab + aoff1[i]);
        af[i] = __builtin_shufflevector(lo, hi, 0, 1, 2, 3, 4, 5, 6, 7);
        i32x4 lo2 = *(const i32x4*)(bb2 + boff0[i]);
        i32x4 hi2 = *(const i32x4*)(bb2 + boff1[i]);
        bfv[i] = __builtin_shufflevector(lo2, hi2, 0, 1, 2, 3, 4, 5, 6, 7);
      }
#pragma unroll
      for (int i = 0; i < 4; ++i)
#pragma unroll
        for (int j = 0; j < 4; ++j)
          acc[i][j] = __builtin_amdgcn_mfma_scale_f32_16x16x128_f8f6f4(
              af[i], bfv[j], acc[i][j], 0, 0, 0, SONE, 0, SONE);
      asm volatile("s_waitcnt lgkmcnt(0)" ::: "memory");
      __builtin_amdgcn_sched_barrier(0);
      __builtin_amdgcn_s_barrier();
      cur ^= 1;
    }
#pragma unroll
    for (int j = 0; j < 4; ++j) {
      float bnv = bnC[mbase + wcq * 64 + j * 16 + lrow];
#pragma unroll
      for (int i = 0; i < 4; ++i)
#pragma unroll
        for (int e = 0; e < 4; ++e)
          rm[i][e] = fminf(rm[i][e], bnv - 2.0f * acc[i][j][e]);
    }
#pragma unroll
    for (int s2 = 1; s2 < 16; s2 <<= 1)
#pragma unroll
      for (int i = 0; i < 4; ++i)
#pragma unroll
        for (int e = 0; e < 4; ++e)
          rm[i][e] = fminf(rm[i][e], __shfl_xor(rm[i][e], s2, 64));
    if (lrow == 0) {
#pragma unroll
      for (int i = 0; i < 4; ++i)
#pragma unroll
        for (int e = 0; e < 4; ++e) {
          int p = pt * 128 + wr * 64 + i * 16 + lk * 4 + e;
          if (p < NP) atomicMin(&mc[b * NP + p], enc_f(rm[i][e]));
        }
    }
  }
}

// ---------------------------------------------------------------------------
// gdistB: per-b patch reduction + combine. grid NB, block 256.
// ---------------------------------------------------------------------------
__global__ __launch_bounds__(256) void gdistB_kernel(
    const int* __restrict__ valid_mask,
    const float* __restrict__ xx_pt, const float* __restrict__ xx_rgb,
    const unsigned* __restrict__ mc_pt, const unsigned* __restrict__ mc_rgb,
    const float* __restrict__ nvArr, const unsigned* __restrict__ gmin,
    float* __restrict__ partial) {
  const int b = blockIdx.x;
  const int tid = threadIdx.x;
  __shared__ float s1[256], s2[256];
  float spt = 0.f, srgb = 0.f;
  for (int p = tid; p < NP; p += 256) {
    float m = (float)valid_mask[b * NP + p];
    float dpt = xx_pt[b * NP + p] + dec_f(mc_pt[b * NP + p]);
    dpt = sqrtf(fminf(fmaxf(dpt, 1e-12f), 50.f));
    float drg = xx_rgb[b * NP + p] + dec_f(mc_rgb[b * NP + p]);
    drg = sqrtf(fminf(fmaxf(drg, 1e-12f), 50.f));
    spt += m * dpt;
    srgb += drg;
  }
  s1[tid] = spt; s2[tid] = srgb;
  __syncthreads();
  for (int s = 128; s > 0; s >>= 1) {
    if (tid < s) { s1[tid] += s1[tid + s]; s2[tid] += s2[tid + s]; }
    __syncthreads();
  }
  if (tid == 0) {
    const float nv = nvArr[b];
    float ming_pt = sqrtf(fminf(fmaxf(dec_f(gmin[b]), 1e-12f), 50.f));
    float ming_rgb = sqrtf(fminf(fmaxf(dec_f(gmin[NB + b]), 1e-12f), 50.f));
    partial[b] = s2[0] / (float)NP + s1[0] / nv + 0.4f * (ming_pt + ming_rgb);
  }
}

// ---------------------------------------------------------------------------
// final tiny reduction. 1 block of 64.
// ---------------------------------------------------------------------------
__global__ void final_kernel(const float* __restrict__ partial, float* __restrict__ out) {
  const int lane = threadIdx.x & 63;
  float v = (lane < NB) ? partial[lane] : 0.f;
  for (int sft = 1; sft < 64; sft <<= 1) v += __shfl_xor(v, sft, 64);
  if (lane == 0) out[0] = 0.9f * v / (float)NB;
}

// ---------------------------------------------------------------------------
// FALLBACK path kernels (ws too small): fp32->bf16 pipeline
// ---------------------------------------------------------------------------
__global__ __launch_bounds__(256) void bank_norms_kernel(
    const float* __restrict__ bank_pt, const float* __restrict__ bank_rgb,
    float* __restrict__ bn_pt, float* __restrict__ bn_rgb) {
  const int branch = blockIdx.y;
  const float* bank = branch ? bank_rgb : bank_pt;
  float* bn = branch ? bn_rgb : bn_pt;
  const int D = branch ? DRG : DPT;
  const int w = threadIdx.x >> 6, lane = threadIdx.x & 63;
  const int row = blockIdx.x * 4 + w;
  const float2* rp = (const float2*)(bank + (size_t)row * D);
  const int cnt = D >> 7;
  float s = 0.f;
  for (int i = 0; i < cnt; ++i) {
    float2 v = rp[lane + 64 * i];
    s += v.x * v.x + v.y * v.y;
  }
  for (int sft = 1; sft < 64; sft <<= 1) s += __shfl_xor(s, sft, 64);
  if (lane == 0) bn[row] = s;
}

__global__ __launch_bounds__(256) void prep_fb_kernel(
    const float* __restrict__ feat_pt, const float* __restrict__ feat_rgb,
    const int* __restrict__ valid_mask,
    float* __restrict__ xx_pt, float* __restrict__ xx_rgb,
    float* __restrict__ gs_pt, float* __restrict__ gs_rgb) {
  const int b = blockIdx.y;
  const int w = threadIdx.x >> 6, lane = threadIdx.x & 63;
  float2 gp[9], gr[6];
#pragma unroll
  for (int i = 0; i < 9; ++i) gp[i] = make_float2(0.f, 0.f);
#pragma unroll
  for (int i = 0; i < 6; ++i) gr[i] = make_float2(0.f, 0.f);
  const int pbase = blockIdx.x * 16 + w * 4;
#pragma unroll
  for (int pi = 0; pi < 4; ++pi) {
    const int p = pbase + pi;
    const float msk = (float)valid_mask[b * NP + p];
    const float2* xr = (const float2*)(feat_pt + ((size_t)b * NP + p) * DPT);
    float s = 0.f;
#pragma unroll
    for (int i = 0; i < 9; ++i) {
      float2 v = xr[lane + 64 * i];
      s += v.x * v.x + v.y * v.y;
      gp[i].x += msk * v.x; gp[i].y += msk * v.y;
    }
    const float2* rr = (const float2*)(feat_rgb + ((size_t)b * NP + p) * DRG);
    float s2 = 0.f;
#pragma unroll
    for (int i = 0; i < 6; ++i) {
      float2 v = rr[lane + 64 * i];
      s2 += v.x * v.x + v.y * v.y;
      gr[i].x += msk * v.x; gr[i].y += msk * v.y;
    }
    for (int sft = 1; sft < 64; sft <<= 1) {
      s += __shfl_xor(s, sft, 64);
      s2 += __shfl_xor(s2, sft, 64);
    }
    if (lane == 0) {
      xx_pt[b * NP + p] = s;
      xx_rgb[b * NP + p] = s2;
    }
  }
#pragma unroll
  for (int i = 0; i < 9; ++i) {
    int d = 2 * (lane + 64 * i);
    atomicAdd(&gs_pt[b * DPT + d], gp[i].x);
    atomicAdd(&gs_pt[b * DPT + d + 1], gp[i].y);
  }
#pragma unroll
  for (int i = 0; i < 6; ++i) {
    int d = 2 * (lane + 64 * i);
    atomicAdd(&gs_rgb[b * DRG + d], gr[i].x);
    atomicAdd(&gs_rgb[b * DRG + d + 1], gr[i].y);
  }
}

__global__ __launch_bounds__(256) void gemm_min_kernel(
    const float* __restrict__ feat_pt, const float* __restrict__ feat_rgb,
    const float* __restrict__ bank_pt, const float* __restrict__ bank_rgb,
    const float* __restrict__ bn_pt, const float* __restrict__ bn_rgb,
    const int* __restrict__ classlabels,
    unsigned* __restrict__ mc_pt, unsigned* __restrict__ mc_rgb) {
  const int branch = blockIdx.z;
  const int b = blockIdx.y;
  const int ptile = blockIdx.x % 7;
  const int mchunk = blockIdx.x / 7;
  const int D = branch ? DRG : DPT;
  const float* feat = branch ? feat_rgb : feat_pt;
  const float* bank = branch ? bank_rgb : bank_pt;
  const float* bn = branch ? bn_rgb : bn_pt;
  unsigned* mc = branch ? mc_rgb : mc_pt;
  const int cls = classlabels[b];

  __shared__ __align__(16) unsigned short As[128 * 32];
  __shared__ __align__(16) unsigned short Bs2[128 * 32];

  const int tid = threadIdx.x;
  const int r = tid >> 1;
  const int h = tid & 1;
  const int p0 = ptile * 128;
  const int prow = (p0 + r < NP) ? (p0 + r) : (NP - 1);
  const float* Arow = feat + ((size_t)b * NP + prow) * D + h * 16;
  const float* BankC = bank + (size_t)cls * NM * D;
  const float* bnC = bn + cls * NM;
  const int swz = (r >> 1) & 3;
  const int wo0 = r * 32 + ((2 * h) ^ swz) * 8;
  const int wo1 = r * 32 + ((2 * h + 1) ^ swz) * 8;

  const int lane = tid & 63;
  const int w = tid >> 6;
  const int wr = w >> 1, wcq = w & 1;
  const int lrow = lane & 15, lk = lane >> 4;
  int aoff[4], boff[4];
#pragma unroll
  for (int i = 0; i < 4; ++i) {
    int row = wr * 64 + i * 16 + lrow;
    aoff[i] = row * 32 + (lk ^ ((row >> 1) & 3)) * 8;
    row = wcq * 64 + i * 16 + lrow;
    boff[i] = row * 32 + (lk ^ ((row >> 1) & 3)) * 8;
  }

  float rm[4][4];
#pragma unroll
  for (int i = 0; i < 4; ++i)
#pragma unroll
    for (int e = 0; e < 4; ++e) rm[i][e] = 1e30f;

  union V16 { unsigned short s[8]; float4 v; };

#pragma unroll 1
  for (int mt = 0; mt < 8; ++mt) {
    const int mbase = mchunk * 1024 + mt * 128;
    const float* Brow = BankC + (size_t)(mbase + r) * D + h * 16;
    f32x4 acc[4][4];
#pragma unroll
    for (int i = 0; i < 4; ++i)
#pragma unroll
      for (int j = 0; j < 4; ++j) acc[i][j] = (f32x4){0.f, 0.f, 0.f, 0.f};

#pragma unroll 1
    for (int k0 = 0; k0 < D; k0 += 32) {
      __syncthreads();
      {
        const float4* ga = (const float4*)(Arow + k0);
        float4 f0 = ga[0], f1 = ga[1], f2 = ga[2], f3 = ga[3];
        V16 u0, u1;
        u0.s[0] = f2bf(f0.x); u0.s[1] = f2bf(f0.y); u0.s[2] = f2bf(f0.z); u0.s[3] = f2bf(f0.w);
        u0.s[4] = f2bf(f1.x); u0.s[5] = f2bf(f1.y); u0.s[6] = f2bf(f1.z); u0.s[7] = f2bf(f1.w);
        u1.s[0] = f2bf(f2.x); u1.s[1] = f2bf(f2.y); u1.s[2] = f2bf(f2.z); u1.s[3] = f2bf(f2.w);
        u1.s[4] = f2bf(f3.x); u1.s[5] = f2bf(f3.y); u1.s[6] = f2bf(f3.z); u1.s[7] = f2bf(f3.w);
        *(float4*)&As[wo0] = u0.v;
        *(float4*)&As[wo1] = u1.v;
      }
      {
        const float4* gb = (const float4*)(Brow + k0);
        float4 f0 = gb[0], f1 = gb[1], f2 = gb[2], f3 = gb[3];
        V16 u0, u1;
        u0.s[0] = f2bf(f0.x); u0.s[1] = f2bf(f0.y); u0.s[2] = f2bf(f0.z); u0.s[3] = f2bf(f0.w);
        u0.s[4] = f2bf(f1.x); u0.s[5] = f2bf(f1.y); u0.s[6] = f2bf(f1.z); u0.s[7] = f2bf(f1.w);
        u1.s[0] = f2bf(f2.x); u1.s[1] = f2bf(f2.y); u1.s[2] = f2bf(f2.z); u1.s[3] = f2bf(f2.w);
        u1.s[4] = f2bf(f3.x); u1.s[5] = f2bf(f3.y); u1.s[6] = f2bf(f3.z); u1.s[7] = f2bf(f3.w);
        *(float4*)&Bs2[wo0] = u0.v;
        *(float4*)&Bs2[wo1] = u1.v;
      }
      __syncthreads();
      bf16x8 af[4], bfv[4];
#pragma unroll
      for (int i = 0; i < 4; ++i) {
        af[i] = *(const bf16x8*)&As[aoff[i]];
        bfv[i] = *(const bf16x8*)&Bs2[boff[i]];
      }
#pragma unroll
      for (int i = 0; i < 4; ++i)
#pragma unroll
        for (int j = 0; j < 4; ++j)
          acc[i][j] = __builtin_amdgcn_mfma_f32_16x16x32_bf16(af[i], bfv[j], acc[i][j], 0, 0, 0);
    }
#pragma unroll
    for (int j = 0; j < 4; ++j) {
      float bnv = bnC[mbase + wcq * 64 + j * 16 + lrow];
#pragma unroll
      for (int i = 0; i < 4; ++i)
#pragma unroll
        for (int e = 0; e < 4; ++e)
          rm[i][e] = fminf(rm[i][e], bnv - 2.0f * acc[i][j][e]);
    }
  }
#pragma unroll
  for (int s = 1; s < 16; s <<= 1)
#pragma unroll
    for (int i = 0; i < 4; ++i)
#pragma unroll
      for (int e = 0; e < 4; ++e)
        rm[i][e] = fminf(rm[i][e], __shfl_xor(rm[i][e], s, 64));
  if (lrow == 0) {
#pragma unroll
    for (int i = 0; i < 4; ++i)
#pragma unroll
      for (int e = 0; e < 4; ++e) {
        int p = p0 + wr * 64 + i * 16 + lk * 4 + e;
        if (p < NP) atomicMin(&mc[b * NP + p], enc_f(rm[i][e]));
      }
  }
}

__global__ __launch_bounds__(256) void gdist_fb_kernel(
    const float* __restrict__ bgp, const float* __restrict__ bgr,
    const float* __restrict__ gs_pt, const float* __restrict__ gs_rgb,
    const int* __restrict__ classlabels, const int* __restrict__ valid_mask,
    const float* __restrict__ xx_pt, const float* __restrict__ xx_rgb,
    const unsigned* __restrict__ mc_pt, const unsigned* __restrict__ mc_rgb,
    float* __restrict__ partial) {
  const int b = blockIdx.x;
  const int tid = threadIdx.x;
  const int w = tid >> 6, lane = tid & 63;
  __shared__ float sred[256], sred2[256], sred3[256];
  __shared__ float gsh[DPT];
  __shared__ float wmin[4];
  float nvi = 0.f, spt = 0.f, srgb = 0.f;
  for (int p = tid; p < NP; p += 256) {
    float m = (float)valid_mask[b * NP + p];
    nvi += m;
    float dpt = xx_pt[b * NP + p] + dec_f(mc_pt[b * NP + p]);
    dpt = sqrtf(fminf(fmaxf(dpt, 1e-12f), 50.f));
    float drg = xx_rgb[b * NP + p] + dec_f(mc_rgb[b * NP + p]);
    drg = sqrtf(fminf(fmaxf(drg, 1e-12f), 50.f));
    spt += m * dpt;
    srgb += drg;
  }
  sred[tid] = nvi; sred2[tid] = spt; sred3[tid] = srgb;
  __syncthreads();
  for (int s = 128; s > 0; s >>= 1) {
    if (tid < s) {
      sred[tid] += sred[tid + s];
      sred2[tid] += sred2[tid + s];
      sred3[tid] += sred3[tid + s];
    }
    __syncthreads();
  }
  const float nv = sred[0];
  const float mean_pt = sred2[0] / nv;
  const float mean_rgb = sred3[0] / (float)NP;
  const int cls = classlabels[b];
  float ming_pt, ming_rgb;
  for (int d = tid; d < DPT; d += 256) gsh[d] = gs_pt[b * DPT + d] / nv;
  __syncthreads();
  {
    float mn = 1e30f;
    for (int row = w; row < NMG; row += 4) {
      const float2* yr = (const float2*)(bgp + ((size_t)cls * NMG + row) * DPT);
      float s = 0.f;
#pragma unroll
      for (int i = 0; i < 9; ++i) {
        float2 y = yr[lane + 64 * i];
        int d = 2 * (lane + 64 * i);
        float dx = gsh[d] - y.x, dy = gsh[d + 1] - y.y;
        s += dx * dx + dy * dy;
      }
      for (int sft = 1; sft < 64; sft <<= 1) s += __shfl_xor(s, sft, 64);
      mn = fminf(mn, s);
    }
    if (lane == 0) wmin[w] = mn;
    __syncthreads();
    float m2 = fminf(fminf(wmin[0], wmin[1]), fminf(wmin[2], wmin[3]));
    ming_pt = sqrtf(fminf(fmaxf(m2, 1e-12f), 50.f));
    __syncthreads();
  }
  for (int d = tid; d < DRG; d += 256) gsh[d] = gs_rgb[b * DRG + d] / nv;
  __syncthreads();
  {
    float mn = 1e30f;
    for (int row = w; row < NMG; row += 4) {
      const float2* yr = (const float2*)(bgr + ((size_t)cls * NMG + row) * DRG);
      float s = 0.f;
#pragma unroll
      for (int i = 0; i < 6; ++i) {
        float2 y = yr[lane + 64 * i];
        int d = 2 * (lane + 64 * i);
        float dx = gsh[d] - y.x, dy = gsh[d + 1] - y.y;
        s += dx * dx + dy * dy;
      }
      for (int sft = 1; sft < 64; sft <<= 1) s += __shfl_xor(s, sft, 64);
      mn = fminf(mn, s);
    }
    if (lane == 0) wmin[w] = mn;
    __syncthreads();
    float m2 = fminf(fminf(wmin[0], wmin[1]), fminf(wmin[2], wmin[3]));
    ming_rgb = sqrtf(fminf(fmaxf(m2, 1e-12f), 50.f));
  }
  if (tid == 0)
    partial[b] = mean_rgb + mean_pt + 0.4f * (ming_pt + ming_rgb);
}

// ---------------------------------------------------------------------------
extern "C" void kernel_launch(void* const* d_in, const int* in_sizes, int n_in,
                              void* d_out, int out_size, void* d_ws, size_t ws_size,
                              hipStream_t stream) {
  const float* feat_pt = (const float*)d_in[0];
  const float* feat_rgb = (const float*)d_in[1];
  const float* bank_pt = (const float*)d_in[2];
  const float* bank_rgb = (const float*)d_in[3];
  const float* bgp = (const float*)d_in[4];
  const float* bgr = (const float*)d_in[5];
  const int* classlabels = (const int*)d_in[6];
  const int* valid_mask = (const int*)d_in[7];
  float* out = (float*)d_out;

  const size_t BBP = (size_t)NC * NM * DPT;   // bank fp8 bytes
  const size_t BBR = (size_t)NC * NM * DRG;
  const size_t FBP = (size_t)NB * NP * DPT;   // feature fp8 bytes
  const size_t FBR = (size_t)NB * NP * DRG;
  const size_t GSPART = (size_t)NB * 49 * DTOT;  // 1.5M floats
  const size_t SMALL_WORDS = 4 * (size_t)NC * NM + 8 * (size_t)NB * NP +
                             GSPART + 8 * NB + 2 * NC + 256;
  const size_t NEED = (BBP + BBR + FBP + FBR) + 4 * SMALL_WORDS;
  const bool fast = (ws_size >= NEED);

  if (fast) {
    unsigned char* b8_pt = (unsigned char*)d_ws;
    unsigned char* b8_rgb = b8_pt + BBP;
    unsigned char* f8_pt = b8_rgb + BBR;
    unsigned char* f8_rgb = f8_pt + FBP;
    float* fl = (float*)(f8_rgb + FBR);
    float* bn_pt = fl;                          // NC*NM
    float* bn_rgb = bn_pt + NC * NM;
    float* bnS_pt = bn_rgb + NC * NM;           // NC*NM
    float* bnS_rgb = bnS_pt + NC * NM;
    float* xx_pt = bnS_rgb + NC * NM;           // NB*NP
    float* xx_rgb = xx_pt + NB * NP;
    float* xxS_pt = xx_rgb + NB * NP;
    float* xxS_rgb = xxS_pt + NB * NP;
    float* gs_part = xxS_rgb + NB * NP;         // NB*49*DTOT
    unsigned* mc_pt = (unsigned*)(gs_part + GSPART);
    unsigned* mc_rgb = mc_pt + NB * NP;
    unsigned* pmc_pt = mc_rgb + NB * NP;
    unsigned* pmc_rgb = pmc_pt + NB * NP;
    float* partial = (float*)(pmc_rgb + NB * NP);   // NB
    float* nvArr = partial + NB;                    // NB
    unsigned* gmin = (unsigned*)(nvArr + NB);       // 2*NB
    unsigned* flagF = gmin + 2 * NB;                // 2*NB
    unsigned* classFlag = flagF + 2 * NB;           // NC
    unsigned* present = classFlag + NC;             // NC

    init_kernel<<<64, 256, 0, stream>>>(classlabels, nvArr, mc_pt, gmin,
                                        flagF, classFlag, present);
    fused_cp_kernel<<<2064, 256, 0, stream>>>(
        feat_pt, feat_rgb, bank_pt, bank_rgb, valid_mask,
        xx_pt, xx_rgb, xxS_pt, xxS_rgb, gs_part, nvArr,
        f8_pt, f8_rgb, b8_pt, b8_rgb, bnS_pt, bnS_rgb, present);
    fused_g1_kernel<<<1280, 256, 0, stream>>>(
        f8_pt, f8_rgb, b8_pt, b8_rgb, bnS_pt, bnS_rgb, classlabels,
        pmc_pt, pmc_rgb, bgp, bgr, gs_part, nvArr, gmin);
    flag_kernel<<<32, 256, 0, stream>>>(
        xxS_pt, xxS_rgb, pmc_pt, pmc_rgb, classlabels, flagF, classFlag);
    fullconv_kernel<<<2064, 256, 0, stream>>>(
        bank_pt, bank_rgb, feat_pt, feat_rgb, b8_pt, b8_rgb, f8_pt, f8_rgb,
        bn_pt, bn_rgb, classFlag, flagF);
    gemm2_kernel<<<dim3(64, NB), 256, 0, stream>>>(
        f8_pt, f8_rgb, b8_pt, b8_rgb, bn_pt, bn_rgb, classlabels, flagF, mc_pt, mc_rgb);
    gdistB_kernel<<<NB, 256, 0, stream>>>(
        valid_mask, xx_pt, xx_rgb, mc_pt, mc_rgb, nvArr, gmin, partial);
    final_kernel<<<1, 64, 0, stream>>>(partial, out);
  } else {
    float* ws = (float*)d_ws;
    float* bn_pt = ws;
    float* bn_rgb = bn_pt + NC * NM;
    float* xx_pt = bn_rgb + NC * NM;
    float* xx_rgb = xx_pt + NB * NP;
    float* gs_pt = xx_rgb + NB * NP;
    float* gs_rgb = gs_pt + NB * DPT;
    unsigned* mc_pt = (unsigned*)(gs_rgb + NB * DRG);
    unsigned* mc_rgb = mc_pt + NB * NP;
    float* partial = (float*)(mc_rgb + NB * NP);

    hipMemsetAsync(gs_pt, 0, (size_t)(NB * DPT + NB * DRG) * 4, stream);
    hipMemsetAsync(mc_pt, 0xF7, (size_t)(2 * NB * NP) * 4, stream);

    bank_norms_kernel<<<dim3(NC * NM / 4, 2), 256, 0, stream>>>(bank_pt, bank_rgb, bn_pt, bn_rgb);
    prep_fb_kernel<<<dim3(49, NB), 256, 0, stream>>>(
        feat_pt, feat_rgb, valid_mask, xx_pt, xx_rgb, gs_pt, gs_rgb);
    gemm_min_kernel<<<dim3(28, NB, 2), 256, 0, stream>>>(
        feat_pt, feat_rgb, bank_pt, bank_rgb, bn_pt, bn_rgb, classlabels, mc_pt, mc_rgb);
    gdist_fb_kernel<<<NB, 256, 0, stream>>>(bgp, bgr, gs_pt, gs_rgb, classlabels, valid_mask,
                                            xx_pt, xx_rgb, mc_pt, mc_rgb, partial);
    final_kernel<<<1, 64, 0, stream>>>(partial, out);
  }
}

// Round 18
// 103.833 us; speedup vs baseline: 1.9507x; 1.5523x over previous
//
#include <hip/hip_runtime.h>
#include <hip/hip_bf16.h>

// Problem constants (match reference)
#define NB 16
#define NP 784
#define NC 10
#define NM 4096
#define NMG 128
#define DPT 1152
#define DRG 768
#define DTOT (DPT + DRG)   // 1920

typedef __attribute__((ext_vector_type(8))) short bf16x8;    // 8 bf16 (4 VGPR)
typedef __attribute__((ext_vector_type(4))) float f32x4;     // 16x16 MFMA acc
typedef __attribute__((ext_vector_type(4))) int i32x4;
typedef __attribute__((ext_vector_type(8))) int i32x8;

#define SONE 0x7F7F7F7F   // e8m0 scale = 1.0 in every byte
#define SKIP_THR 70.0f    // clamp(50) + fp8-quantization guard band

__device__ __forceinline__ unsigned short f2bf(float f) {
  unsigned u = __float_as_uint(f);
  return (unsigned short)((u + 0x7fffu + ((u >> 16) & 1u)) >> 16); // RNE
}
// order-preserving float->uint encoding (for atomicMin on float values)
__device__ __forceinline__ unsigned enc_f(float f) {
  unsigned u = __float_as_uint(f);
  return (u & 0x80000000u) ? ~u : (u | 0x80000000u);
}
__device__ __forceinline__ float dec_f(unsigned u) {
  return __uint_as_float((u & 0x80000000u) ? (u & 0x7fffffffu) : ~u);
}
// async global->LDS, 16B per lane. LDS dest must be wave-uniform (HW adds lane*16).
__device__ __forceinline__ void gl_lds16(const void* g, void* s) {
  __builtin_amdgcn_global_load_lds(
      (const __attribute__((address_space(1))) unsigned int*)g,
      (__attribute__((address_space(3))) unsigned int*)s, 16, 0, 0);
}

// ---------------------------------------------------------------------------
// FUSED init + convert128 + prep (one launch, independent block roles):
//  blk [0,784):     prep — patch norms (full + first-128), gs PARTIALS,
//                   nv partial (plain store), fp8 convert of first 128 dims.
//  blk [784,2064):  bank fp32 -> fp8 first 128 dims + partial norms, 64 rows
//                   per block (present gate computed inline from classlabels).
//  blk [2064,2080): init — mc/pmc/gmin sentinels, flag zeros.
// ---------------------------------------------------------------------------
__global__ __launch_bounds__(256) void fused_cp_kernel(
    const float* __restrict__ feat_pt, const float* __restrict__ feat_rgb,
    const float* __restrict__ bank_pt, const float* __restrict__ bank_rgb,
    const int* __restrict__ classlabels, const int* __restrict__ valid_mask,
    float* __restrict__ xx_pt, float* __restrict__ xx_rgb,
    float* __restrict__ xxS_pt, float* __restrict__ xxS_rgb,
    float* __restrict__ gs_part,   // [NB][49][DTOT]
    float* __restrict__ nv_part,   // [NB][49]
    unsigned char* __restrict__ f8_pt, unsigned char* __restrict__ f8_rgb,
    unsigned char* __restrict__ b8_pt, unsigned char* __restrict__ b8_rgb,
    float* __restrict__ bnS_pt, float* __restrict__ bnS_rgb,
    unsigned* __restrict__ mc, unsigned* __restrict__ gmin,
    unsigned* __restrict__ flagF, unsigned* __restrict__ classFlag) {
  __shared__ float accL[4][DTOT];   // 30 KB (prep blocks only)
  __shared__ float wnv[4];
  const int blk = blockIdx.x;
  const int w = threadIdx.x >> 6, lane = threadIdx.x & 63;
  if (blk < 784) {
    const int b = blk / 49, xb = blk % 49;
    float2 gp[9], gr[6];
#pragma unroll
    for (int i = 0; i < 9; ++i) gp[i] = make_float2(0.f, 0.f);
#pragma unroll
    for (int i = 0; i < 6; ++i) gr[i] = make_float2(0.f, 0.f);
    const int pbase = xb * 16 + w * 4;
    float mcount = 0.f;
#pragma unroll
    for (int pi = 0; pi < 4; ++pi) {
      const int p = pbase + pi;
      const float msk = (float)valid_mask[b * NP + p];
      mcount += msk;
      const float2* xr = (const float2*)(feat_pt + ((size_t)b * NP + p) * DPT);
      unsigned short* xw = (unsigned short*)(f8_pt + ((size_t)b * NP + p) * DPT);
      float s = 0.f, sp = 0.f;
#pragma unroll
      for (int i = 0; i < 9; ++i) {
        float2 v = xr[lane + 64 * i];
        float c2 = v.x * v.x + v.y * v.y;
        s += c2;
        if (i == 0) {
          sp = c2;   // dims 0..127
          int pk = __builtin_amdgcn_cvt_pk_fp8_f32(v.x, v.y, 0, false);
          xw[lane] = (unsigned short)(pk & 0xFFFF);
        }
        gp[i].x += msk * v.x; gp[i].y += msk * v.y;
      }
      const float2* rr = (const float2*)(feat_rgb + ((size_t)b * NP + p) * DRG);
      unsigned short* rw = (unsigned short*)(f8_rgb + ((size_t)b * NP + p) * DRG);
      float s2 = 0.f, sp2 = 0.f;
#pragma unroll
      for (int i = 0; i < 6; ++i) {
        float2 v = rr[lane + 64 * i];
        float c2 = v.x * v.x + v.y * v.y;
        s2 += c2;
        if (i == 0) {
          sp2 = c2;  // dims 0..127
          int pk = __builtin_amdgcn_cvt_pk_fp8_f32(v.x, v.y, 0, false);
          rw[lane] = (unsigned short)(pk & 0xFFFF);
        }
        gr[i].x += msk * v.x; gr[i].y += msk * v.y;
      }
      for (int sft = 1; sft < 64; sft <<= 1) {
        s += __shfl_xor(s, sft, 64);
        s2 += __shfl_xor(s2, sft, 64);
        sp += __shfl_xor(sp, sft, 64);
        sp2 += __shfl_xor(sp2, sft, 64);
      }
      if (lane == 0) {
        xx_pt[b * NP + p] = s;
        xx_rgb[b * NP + p] = s2;
        xxS_pt[b * NP + p] = sp;
        xxS_rgb[b * NP + p] = sp2;
      }
    }
    // per-wave rows into LDS (conflict-free float2 stores), then 4->1 reduce
#pragma unroll
    for (int i = 0; i < 9; ++i)
      *(float2*)&accL[w][2 * (lane + 64 * i)] = gp[i];
#pragma unroll
    for (int i = 0; i < 6; ++i)
      *(float2*)&accL[w][DPT + 2 * (lane + 64 * i)] = gr[i];
    if (lane == 0) wnv[w] = mcount;
    __syncthreads();
    float* dst = gs_part + ((size_t)b * 49 + xb) * DTOT;
    for (int e = threadIdx.x; e < DTOT; e += 256)
      dst[e] = accL[0][e] + accL[1][e] + accL[2][e] + accL[3][e];
    if (threadIdx.x == 0)
      nv_part[b * 49 + xb] = wnv[0] + wnv[1] + wnv[2] + wnv[3];
  } else if (blk < 2064) {
    const int cb = blk - 784;          // 0..1279
    const int branch = cb & 1;
    const int grp = cb >> 1;           // 0..639
    const int c = grp >> 6;
    bool pres = false;
#pragma unroll
    for (int i = 0; i < NB; ++i) pres |= (classlabels[i] == c);
    if (!pres) return;
    const int rch = grp & 63;
    const float* bank = branch ? bank_rgb : bank_pt;
    unsigned char* b8 = branch ? b8_rgb : b8_pt;
    float* bnS = branch ? bnS_rgb : bnS_pt;
    const int D = branch ? DRG : DPT;
#pragma unroll 1
    for (int rl = 0; rl < 16; ++rl) {
      const int row = (c << 12) + rch * 64 + w * 16 + rl;
      const float2* rp = (const float2*)(bank + (size_t)row * D);
      unsigned short* dp = (unsigned short*)(b8 + (size_t)row * D);
      float2 v = rp[lane];
      float s = v.x * v.x + v.y * v.y;
      int pk = __builtin_amdgcn_cvt_pk_fp8_f32(v.x, v.y, 0, false);
      dp[lane] = (unsigned short)(pk & 0xFFFF);
      for (int sft = 1; sft < 64; sft <<= 1) s += __shfl_xor(s, sft, 64);
      if (lane == 0) bnS[row] = s;
    }
  } else {
    // init blocks: sentinels + flag zeros (consumed by LATER kernels only)
    const int tid = (blk - 2064) * 256 + threadIdx.x;
    const int stride = 16 * 256;
    const int total_mc = 4 * NB * NP;  // mc + pmc
    for (int i = tid; i < total_mc; i += stride) mc[i] = 0xF7F7F7F7u;
    if (tid < 2 * NB) gmin[tid] = 0xF7F7F7F7u;
    if (tid < 2 * NB) flagF[tid] = 0u;
    if (tid < NC) classFlag[tid] = 0u;
  }
}

// ---------------------------------------------------------------------------
// FUSED gemm1 + gdistA:
//  blk [0,512):   certificate GEMM, 2 m-chunks (256 bank rows) per block.
//                 B held as 8 reg fragments (staged twice through one LDS
//                 buffer); A 2-deep prefetch with counted vmcnt(4); per
//                 p-tile: 8 ds_read + 32 MFMA, ONE reduce+atomic for 256 rows.
//  blk [512,768): gdistA — global-bank min; gsh from 49 gs partials with
//                 ILP-parallel accumulators; nv summed inline.
// ---------------------------------------------------------------------------
__global__ __launch_bounds__(256) void fused_g1_kernel(
    const unsigned char* __restrict__ f8_pt, const unsigned char* __restrict__ f8_rgb,
    const unsigned char* __restrict__ b8_pt, const unsigned char* __restrict__ b8_rgb,
    const float* __restrict__ bnS_pt, const float* __restrict__ bnS_rgb,
    const int* __restrict__ classlabels,
    unsigned* __restrict__ pmc_pt, unsigned* __restrict__ pmc_rgb,
    const float* __restrict__ bgp, const float* __restrict__ bgr,
    const float* __restrict__ gs_part, const float* __restrict__ nv_part,
    unsigned* __restrict__ gmin) {
  __shared__ __align__(16) unsigned char As[2][16384];
  __shared__ __align__(16) unsigned char Bs[16384];
  const int blk = blockIdx.x;
  const int t = threadIdx.x;
  const int w = t >> 6, lane = t & 63;

  if (blk >= 512) {
    // ---- gdistA ----
    const int g = blk - 512;           // 0..255
    const int slice = g & 7;
    const int b = (g >> 3) & 15;
    const int branch = g >> 7;
    const int D = branch ? DRG : DPT;
    const int base = branch ? DPT : 0;
    const float* bank = branch ? bgr : bgp;
    const int cls = classlabels[b];
    float* gsh = (float*)&As[0][0];    // reuse LDS
    float nv = 0.f;
    {
      const float* np_ = nv_part + b * 49;
      float n0 = 0.f, n1 = 0.f, n2 = 0.f, n3 = 0.f;
#pragma unroll
      for (int k = 0; k < 48; k += 4) {
        n0 += np_[k]; n1 += np_[k + 1]; n2 += np_[k + 2]; n3 += np_[k + 3];
      }
      nv = n0 + n1 + n2 + n3 + np_[48];
    }
    const float inv = 1.f / nv;
    const float* gp0 = gs_part + (size_t)b * 49 * DTOT + base;
    for (int d = t; d < D; d += 256) {
      const float* p = gp0 + d;
      float s0 = 0.f, s1 = 0.f, s2 = 0.f, s3 = 0.f;
#pragma unroll
      for (int k = 0; k < 48; k += 4) {
        s0 += p[(size_t)k * DTOT];
        s1 += p[(size_t)(k + 1) * DTOT];
        s2 += p[(size_t)(k + 2) * DTOT];
        s3 += p[(size_t)(k + 3) * DTOT];
      }
      s0 += p[(size_t)48 * DTOT];
      gsh[d] = (s0 + s1 + s2 + s3) * inv;
    }
    __syncthreads();
    const int cnt = D >> 7;
    float mn = 1e30f;
#pragma unroll 1
    for (int rl = 0; rl < 4; ++rl) {
      const int row = slice * 16 + w * 4 + rl;
      const float2* yr = (const float2*)(bank + ((size_t)cls * NMG + row) * D);
      float s = 0.f;
      for (int i = 0; i < cnt; ++i) {
        float2 y = yr[lane + 64 * i];
        int d = 2 * (lane + 64 * i);
        float dx = gsh[d] - y.x, dy = gsh[d + 1] - y.y;
        s += dx * dx + dy * dy;
      }
      for (int sft = 1; sft < 64; sft <<= 1) s += __shfl_xor(s, sft, 64);
      mn = fminf(mn, s);
    }
    if (lane == 0) atomicMin(&gmin[branch * NB + b], enc_f(mn));
    return;
  }

  // ---- gemm1: 2 m-chunks (256 rows) per block ----
  const int branch = blk & 1;
  const int mch = (blk >> 1) & 15;    // 16 chunks x 256 rows
  const int b = blk >> 5;
  const int D = branch ? DRG : DPT;
  const unsigned char* f8 = branch ? f8_rgb : f8_pt;
  const unsigned char* b8 = branch ? b8_rgb : b8_pt;
  const float* bnS = branch ? bnS_rgb : bnS_pt;
  unsigned* pmc = branch ? pmc_rgb : pmc_pt;
  const int cls = classlabels[b];

  const unsigned char* fB = f8 + (size_t)b * NP * D;
  const unsigned char* bB = b8 + (size_t)cls * NM * D;
  const int mbase = mch * 256;

  int rr[4], cx[4];
#pragma unroll
  for (int i = 0; i < 4; ++i) {
    int pos = w * 256 + i * 64 + lane;
    rr[i] = pos >> 3;
    cx[i] = ((pos & 7) ^ (rr[i] & 7)) << 4;
  }
  const int wr = w >> 1, wcq = w & 1;
  const int lrow = lane & 15, lk = lane >> 4;
  int aoff0[4], aoff1[4], boff0[4], boff1[4];
#pragma unroll
  for (int i = 0; i < 4; ++i) {
    int ra = wr * 64 + i * 16 + lrow;
    aoff0[i] = ra * 128 + ((lk * 32) ^ ((ra & 7) << 4));
    aoff1[i] = ra * 128 + ((lk * 32 + 16) ^ ((ra & 7) << 4));
    int rb = wcq * 64 + i * 16 + lrow;
    boff0[i] = rb * 128 + ((lk * 32) ^ ((rb & 7) << 4));
    boff1[i] = rb * 128 + ((lk * 32 + 16) ^ ((rb & 7) << 4));
  }
  float bnv[8];
#pragma unroll
  for (int j = 0; j < 4; ++j) {
    bnv[j] = bnS[cls * NM + mbase + wcq * 64 + j * 16 + lrow];
    bnv[4 + j] = bnS[cls * NM + mbase + 128 + wcq * 64 + j * 16 + lrow];
  }

  auto STAGE_A = [&](int pt, int buf) {
#pragma unroll
    for (int i = 0; i < 4; ++i) {
      int pr = pt * 128 + rr[i];
      if (pr > NP - 1) pr = NP - 1;
      gl_lds16(fB + (size_t)pr * D + cx[i], &As[buf][0] + (w * 4 + i) * 1024);
    }
  };
  auto STAGE_B = [&](int half) {
#pragma unroll
    for (int i = 0; i < 4; ++i)
      gl_lds16(bB + (size_t)(mbase + half * 128 + rr[i]) * D + cx[i],
               &Bs[0] + (w * 4 + i) * 1024);
  };

  // prologue: B half 0 -> regs, B half 1 -> regs (one LDS buffer), then A0,A1
  i32x8 bfv[8];
  STAGE_B(0);
  asm volatile("s_waitcnt vmcnt(0)" ::: "memory");
  __builtin_amdgcn_s_barrier();
  __builtin_amdgcn_sched_barrier(0);
#pragma unroll
  for (int i = 0; i < 4; ++i) {
    i32x4 lo = *(const i32x4*)(&Bs[0] + boff0[i]);
    i32x4 hi = *(const i32x4*)(&Bs[0] + boff1[i]);
    bfv[i] = __builtin_shufflevector(lo, hi, 0, 1, 2, 3, 4, 5, 6, 7);
  }
  asm volatile("s_waitcnt lgkmcnt(0)" ::: "memory");
  __builtin_amdgcn_sched_barrier(0);
  __builtin_amdgcn_s_barrier();
  STAGE_B(1);
  asm volatile("s_waitcnt vmcnt(0)" ::: "memory");
  __builtin_amdgcn_s_barrier();
  __builtin_amdgcn_sched_barrier(0);
#pragma unroll
  for (int i = 0; i < 4; ++i) {
    i32x4 lo = *(const i32x4*)(&Bs[0] + boff0[i]);
    i32x4 hi = *(const i32x4*)(&Bs[0] + boff1[i]);
    bfv[4 + i] = __builtin_shufflevector(lo, hi, 0, 1, 2, 3, 4, 5, 6, 7);
  }
  asm volatile("s_waitcnt lgkmcnt(0)" ::: "memory");
  __builtin_amdgcn_sched_barrier(0);
  __builtin_amdgcn_s_barrier();
  STAGE_A(0, 0);
  STAGE_A(1, 1);

#pragma unroll 1
  for (int pt = 0; pt < 7; ++pt) {
    const int cur = pt & 1;
    // entry: A(pt) done (A(pt+1) stays in flight)
    asm volatile("s_waitcnt vmcnt(4)" ::: "memory");
    __builtin_amdgcn_s_barrier();
    __builtin_amdgcn_sched_barrier(0);
    i32x8 af[4];
#pragma unroll
    for (int i = 0; i < 4; ++i) {
      i32x4 lo = *(const i32x4*)(&As[cur][0] + aoff0[i]);
      i32x4 hi = *(const i32x4*)(&As[cur][0] + aoff1[i]);
      af[i] = __builtin_shufflevector(lo, hi, 0, 1, 2, 3, 4, 5, 6, 7);
    }
    float rm[4][4];
#pragma unroll
    for (int i = 0; i < 4; ++i) {
      f32x4 q0 = (f32x4){0.f, 0.f, 0.f, 0.f};
      f32x4 q1 = q0, q2 = q0, q3 = q0, q4 = q0, q5 = q0, q6 = q0, q7 = q0;
      q0 = __builtin_amdgcn_mfma_scale_f32_16x16x128_f8f6f4(af[i], bfv[0], q0, 0, 0, 0, SONE, 0, SONE);
      q1 = __builtin_amdgcn_mfma_scale_f32_16x16x128_f8f6f4(af[i], bfv[1], q1, 0, 0, 0, SONE, 0, SONE);
      q2 = __builtin_amdgcn_mfma_scale_f32_16x16x128_f8f6f4(af[i], bfv[2], q2, 0, 0, 0, SONE, 0, SONE);
      q3 = __builtin_amdgcn_mfma_scale_f32_16x16x128_f8f6f4(af[i], bfv[3], q3, 0, 0, 0, SONE, 0, SONE);
      q4 = __builtin_amdgcn_mfma_scale_f32_16x16x128_f8f6f4(af[i], bfv[4], q4, 0, 0, 0, SONE, 0, SONE);
      q5 = __builtin_amdgcn_mfma_scale_f32_16x16x128_f8f6f4(af[i], bfv[5], q5, 0, 0, 0, SONE, 0, SONE);
      q6 = __builtin_amdgcn_mfma_scale_f32_16x16x128_f8f6f4(af[i], bfv[6], q6, 0, 0, 0, SONE, 0, SONE);
      q7 = __builtin_amdgcn_mfma_scale_f32_16x16x128_f8f6f4(af[i], bfv[7], q7, 0, 0, 0, SONE, 0, SONE);
#pragma unroll
      for (int e = 0; e < 4; ++e) {
        float v = bnv[0] - 2.0f * q0[e];
        v = fminf(v, bnv[1] - 2.0f * q1[e]);
        v = fminf(v, bnv[2] - 2.0f * q2[e]);
        v = fminf(v, bnv[3] - 2.0f * q3[e]);
        v = fminf(v, bnv[4] - 2.0f * q4[e]);
        v = fminf(v, bnv[5] - 2.0f * q5[e]);
        v = fminf(v, bnv[6] - 2.0f * q6[e]);
        v = fminf(v, bnv[7] - 2.0f * q7[e]);
        rm[i][e] = v;
      }
    }
#pragma unroll
    for (int s2 = 1; s2 < 16; s2 <<= 1)
#pragma unroll
      for (int i = 0; i < 4; ++i)
#pragma unroll
        for (int e = 0; e < 4; ++e)
          rm[i][e] = fminf(rm[i][e], __shfl_xor(rm[i][e], s2, 64));
    if (lrow == 0) {
#pragma unroll
      for (int i = 0; i < 4; ++i)
#pragma unroll
        for (int e = 0; e < 4; ++e) {
          int p = pt * 128 + wr * 64 + i * 16 + lk * 4 + e;
          if (p < NP) atomicMin(&pmc[b * NP + p], enc_f(rm[i][e]));
        }
    }
    // exit: all waves finished reading buf[cur] -> safe to overwrite
    asm volatile("s_waitcnt lgkmcnt(0)" ::: "memory");
    __builtin_amdgcn_sched_barrier(0);
    __builtin_amdgcn_s_barrier();
    if (pt + 2 < 7) STAGE_A(pt + 2, cur);
  }
}

// ---------------------------------------------------------------------------
// Flag kernel. grid: 32 x 256. flags pre-zeroed in fused_cp init blocks.
// ---------------------------------------------------------------------------
__global__ __launch_bounds__(256) void flag_kernel(
    const float* __restrict__ xxS_pt, const float* __restrict__ xxS_rgb,
    const unsigned* __restrict__ pmc_pt, const unsigned* __restrict__ pmc_rgb,
    const int* __restrict__ classlabels,
    unsigned* __restrict__ flagF, unsigned* __restrict__ classFlag) {
  const int tid = blockIdx.x * 256 + threadIdx.x;
  const int stride = gridDim.x * 256;
  for (int idx = tid; idx < 2 * NB * NP; idx += stride) {
    const int branch = idx / (NB * NP);
    const int rem = idx - branch * NB * NP;
    const int b = rem / NP;
    const float* xxS = branch ? xxS_rgb : xxS_pt;
    const unsigned* pmc = branch ? pmc_rgb : pmc_pt;
    float bound = xxS[rem] + dec_f(pmc[rem]);   // lower bound on full min d^2
    if (bound < SKIP_THR) {
      atomicOr(&flagF[branch * NB + b], 1u);
      atomicOr(&classFlag[classlabels[b]], 1u);
    }
  }
}

// ---------------------------------------------------------------------------
// Full fp8 conversion (fallback only; gated). Flat grid:
//  blocks [0,1280): bank rows, gated classFlag; [1280,2064): features, flagF
// ---------------------------------------------------------------------------
__global__ __launch_bounds__(256) void fullconv_kernel(
    const float* __restrict__ bank_pt, const float* __restrict__ bank_rgb,
    const float* __restrict__ feat_pt, const float* __restrict__ feat_rgb,
    unsigned char* __restrict__ b8_pt, unsigned char* __restrict__ b8_rgb,
    unsigned char* __restrict__ f8_pt, unsigned char* __restrict__ f8_rgb,
    float* __restrict__ bn_pt, float* __restrict__ bn_rgb,
    const unsigned* __restrict__ classFlag, const unsigned* __restrict__ flagF) {
  const int id = blockIdx.x;
  const int w = threadIdx.x >> 6, lane = threadIdx.x & 63;
  if (id < 1280) {
    const int branch = id & 1;
    const int cb = id >> 1;
    const int c = cb >> 6;
    if (classFlag[c] == 0u) return;
    const int rch = cb & 63;
    const float* bank = branch ? bank_rgb : bank_pt;
    unsigned char* b8 = branch ? b8_rgb : b8_pt;
    float* bn = branch ? bn_rgb : bn_pt;
    const int D = branch ? DRG : DPT;
    const int D4 = D >> 2;
#pragma unroll 1
    for (int rl = 0; rl < 16; ++rl) {
      const int row = (c << 12) + rch * 64 + w * 16 + rl;
      const float4* rp = (const float4*)(bank + (size_t)row * D);
      unsigned* dp = (unsigned*)(b8 + (size_t)row * D);
      float s = 0.f;
      for (int i = lane; i < D4; i += 64) {
        float4 v = rp[i];
        s += v.x * v.x + v.y * v.y + v.z * v.z + v.w * v.w;
        int pk = __builtin_amdgcn_cvt_pk_fp8_f32(v.x, v.y, 0, false);
        pk = __builtin_amdgcn_cvt_pk_fp8_f32(v.z, v.w, pk, true);
        dp[i] = (unsigned)pk;
      }
      for (int sft = 1; sft < 64; sft <<= 1) s += __shfl_xor(s, sft, 64);
      if (lane == 0) bn[row] = s;
    }
  } else {
    const int fb = id - 1280;
    const int b = fb / 49, xb = fb % 49;
    if (flagF[b] == 0u && flagF[NB + b] == 0u) return;
    const int pbase = xb * 16 + w * 4;
#pragma unroll 1
    for (int pi = 0; pi < 4; ++pi) {
      const int p = pbase + pi;
      const float2* xr = (const float2*)(feat_pt + ((size_t)b * NP + p) * DPT);
      unsigned short* xw = (unsigned short*)(f8_pt + ((size_t)b * NP + p) * DPT);
#pragma unroll
      for (int i = 0; i < 9; ++i) {
        float2 v = xr[lane + 64 * i];
        int pk = __builtin_amdgcn_cvt_pk_fp8_f32(v.x, v.y, 0, false);
        xw[lane + 64 * i] = (unsigned short)(pk & 0xFFFF);
      }
      const float2* rr = (const float2*)(feat_rgb + ((size_t)b * NP + p) * DRG);
      unsigned short* rw = (unsigned short*)(f8_rgb + ((size_t)b * NP + p) * DRG);
#pragma unroll
      for (int i = 0; i < 6; ++i) {
        float2 v = rr[lane + 64 * i];
        int pk = __builtin_amdgcn_cvt_pk_fp8_f32(v.x, v.y, 0, false);
        rw[lane + 64 * i] = (unsigned short)(pk & 0xFFFF);
      }
    }
  }
}

// ---------------------------------------------------------------------------
// Stage-2 GEMM (fallback, R7 schedule): full-K MX-fp8, gated on flagF.
// grid: (64, NB), block 256.
// ---------------------------------------------------------------------------
__global__ __launch_bounds__(256) void gemm2_kernel(
    const unsigned char* __restrict__ f8_pt, const unsigned char* __restrict__ f8_rgb,
    const unsigned char* __restrict__ b8_pt, const unsigned char* __restrict__ b8_rgb,
    const float* __restrict__ bn_pt, const float* __restrict__ bn_rgb,
    const int* __restrict__ classlabels, const unsigned* __restrict__ flagF,
    unsigned* __restrict__ mc_pt, unsigned* __restrict__ mc_rgb) {
  const int branch = blockIdx.x & 1;
  const int mch = blockIdx.x >> 1;
  const int b = blockIdx.y;
  if (flagF[branch * NB + b] == 0u) return;   // certificate passed: all clamp
  const int D = branch ? DRG : DPT;
  const int NK = D >> 7;
  const unsigned char* f8 = branch ? f8_rgb : f8_pt;
  const unsigned char* b8 = branch ? b8_rgb : b8_pt;
  const float* bn = branch ? bn_rgb : bn_pt;
  unsigned* mc = branch ? mc_rgb : mc_pt;
  const int cls = classlabels[b];

  __shared__ __align__(16) unsigned char As[2][16384];
  __shared__ __align__(16) unsigned char Bs[2][16384];

  const int t = threadIdx.x;
  const int w = t >> 6, lane = t & 63;
  const unsigned char* fB = f8 + (size_t)b * NP * D;
  const unsigned char* bB = b8 + (size_t)cls * NM * D;
  const float* bnC = bn + cls * NM;
  const int mbase = mch * 128;

  int rr[4], cx[4];
  const unsigned char* pA[4];
  const unsigned char* pB[4];
#pragma unroll
  for (int i = 0; i < 4; ++i) {
    int pos = w * 256 + i * 64 + lane;
    rr[i] = pos >> 3;
    cx[i] = ((pos & 7) ^ (rr[i] & 7)) << 4;
    pB[i] = bB + (size_t)(mbase + rr[i]) * D + cx[i];
  }
  const int wr = w >> 1, wcq = w & 1;
  const int lrow = lane & 15, lk = lane >> 4;
  int aoff0[4], aoff1[4], boff0[4], boff1[4];
#pragma unroll
  for (int i = 0; i < 4; ++i) {
    int ra = wr * 64 + i * 16 + lrow;
    aoff0[i] = ra * 128 + ((lk * 32) ^ ((ra & 7) << 4));
    aoff1[i] = ra * 128 + ((lk * 32 + 16) ^ ((ra & 7) << 4));
    int rb = wcq * 64 + i * 16 + lrow;
    boff0[i] = rb * 128 + ((lk * 32) ^ ((rb & 7) << 4));
    boff1[i] = rb * 128 + ((lk * 32 + 16) ^ ((rb & 7) << 4));
  }
  auto mkA = [&](int pt) {
    const int p0 = pt * 128;
#pragma unroll
    for (int i = 0; i < 4; ++i) {
      int pr = p0 + rr[i];
      if (pr > NP - 1) pr = NP - 1;
      pA[i] = fB + (size_t)pr * D + cx[i];
    }
  };
  auto STAGE = [&](int k, int buf) {
    unsigned char* ab = &As[buf][0];
    unsigned char* bb2 = &Bs[buf][0];
#pragma unroll
    for (int i = 0; i < 4; ++i) gl_lds16(pA[i] + k, ab + (w * 4 + i) * 1024);
#pragma unroll
    for (int i = 0; i < 4; ++i) gl_lds16(pB[i] + k, bb2 + (w * 4 + i) * 1024);
  };

  mkA(0);
  STAGE(0, 0);
  int cur = 0;
  int npt = 0, nk = 128;

#pragma unroll 1
  for (int pt = 0; pt < 7; ++pt) {
    float rm[4][4];
    f32x4 acc[4][4];
#pragma unroll
    for (int i = 0; i < 4; ++i)
#pragma unroll
      for (int j = 0; j < 4; ++j) {
        acc[i][j] = (f32x4){0.f, 0.f, 0.f, 0.f};
        rm[i][j] = 1e30f;
      }
#pragma unroll 1
    for (int s = 0; s < NK; ++s) {
      STAGE(nk, cur ^ 1);
      if (npt < 7) {
        nk += 128;
        if (nk == D) { nk = 0; ++npt; if (npt < 7) mkA(npt); else nk = 0; }
      }
      asm volatile("s_waitcnt vmcnt(8)" ::: "memory");
      __builtin_amdgcn_s_barrier();
      __builtin_amdgcn_sched_barrier(0);
      const unsigned char* ab = &As[cur][0];
      const unsigned char* bb2 = &Bs[cur][0];
      i32x8 af[4], bfv[4];
#pragma unroll
      for (int i = 0; i < 4; ++i) {
        i32x4 lo = *(const i32x4*)(ab + aoff0[i]);
        i32x4 hi = *(const i32x4*)(ab + aoff1[i]);
        af[i] = __builtin_shufflevector(lo, hi, 0, 1, 2, 3, 4, 5, 6, 7);
        i32x4 lo2 = *(const i32x4*)(bb2 + boff0[i]);
        i32x4 hi2 = *(const i32x4*)(bb2 + boff1[i]);
        bfv[i] = __builtin_shufflevector(lo2, hi2, 0, 1, 2, 3, 4, 5, 6, 7);
      }
#pragma unroll
      for (int i = 0; i < 4; ++i)
#pragma unroll
        for (int j = 0; j < 4; ++j)
          acc[i][j] = __builtin_amdgcn_mfma_scale_f32_16x16x128_f8f6f4(
              af[i], bfv[j], acc[i][j], 0, 0, 0, SONE, 0, SONE);
      asm volatile("s_waitcnt lgkmcnt(0)" ::: "memory");
      __builtin_amdgcn_sched_barrier(0);
      __builtin_amdgcn_s_barrier();
      cur ^= 1;
    }
#pragma unroll
    for (int j = 0; j < 4; ++j) {
      float bnv = bnC[mbase + wcq * 64 + j * 16 + lrow];
#pragma unroll
      for (int i = 0; i < 4; ++i)
#pragma unroll
        for (int e = 0; e < 4; ++e)
          rm[i][e] = fminf(rm[i][e], bnv - 2.0f * acc[i][j][e]);
    }
#pragma unroll
    for (int s2 = 1; s2 < 16; s2 <<= 1)
#pragma unroll
      for (int i = 0; i < 4; ++i)
#pragma unroll
        for (int e = 0; e < 4; ++e)
          rm[i][e] = fminf(rm[i][e], __shfl_xor(rm[i][e], s2, 64));
    if (lrow == 0) {
#pragma unroll
      for (int i = 0; i < 4; ++i)
#pragma unroll
        for (int e = 0; e < 4; ++e) {
          int p = pt * 128 + wr * 64 + i * 16 + lk * 4 + e;
          if (p < NP) atomicMin(&mc[b * NP + p], enc_f(rm[i][e]));
        }
    }
  }
}

// ---------------------------------------------------------------------------
// gdistB: per-b patch reduction + combine. grid NB, block 256.
// ---------------------------------------------------------------------------
__global__ __launch_bounds__(256) void gdistB_kernel(
    const int* __restrict__ valid_mask,
    const float* __restrict__ xx_pt, const float* __restrict__ xx_rgb,
    const unsigned* __restrict__ mc_pt, const unsigned* __restrict__ mc_rgb,
    const float* __restrict__ nv_part, const unsigned* __restrict__ gmin,
    float* __restrict__ partial) {
  const int b = blockIdx.x;
  const int tid = threadIdx.x;
  __shared__ float s1[256], s2[256];
  float spt = 0.f, srgb = 0.f;
  for (int p = tid; p < NP; p += 256) {
    float m = (float)valid_mask[b * NP + p];
    float dpt = xx_pt[b * NP + p] + dec_f(mc_pt[b * NP + p]);
    dpt = sqrtf(fminf(fmaxf(dpt, 1e-12f), 50.f));
    float drg = xx_rgb[b * NP + p] + dec_f(mc_rgb[b * NP + p]);
    drg = sqrtf(fminf(fmaxf(drg, 1e-12f), 50.f));
    spt += m * dpt;
    srgb += drg;
  }
  s1[tid] = spt; s2[tid] = srgb;
  __syncthreads();
  for (int s = 128; s > 0; s >>= 1) {
    if (tid < s) { s1[tid] += s1[tid + s]; s2[tid] += s2[tid + s]; }
    __syncthreads();
  }
  if (tid == 0) {
    float nv = 0.f;
    for (int k = 0; k < 49; ++k) nv += nv_part[b * 49 + k];
    float ming_pt = sqrtf(fminf(fmaxf(dec_f(gmin[b]), 1e-12f), 50.f));
    float ming_rgb = sqrtf(fminf(fmaxf(dec_f(gmin[NB + b]), 1e-12f), 50.f));
    partial[b] = s2[0] / (float)NP + s1[0] / nv + 0.4f * (ming_pt + ming_rgb);
  }
}

// ---------------------------------------------------------------------------
// final tiny reduction. 1 block of 64.
// ---------------------------------------------------------------------------
__global__ void final_kernel(const float* __restrict__ partial, float* __restrict__ out) {
  const int lane = threadIdx.x & 63;
  float v = (lane < NB) ? partial[lane] : 0.f;
  for (int sft = 1; sft < 64; sft <<= 1) v += __shfl_xor(v, sft, 64);
  if (lane == 0) out[0] = 0.9f * v / (float)NB;
}

// ---------------------------------------------------------------------------
// FALLBACK path kernels (ws too small): fp32->bf16 pipeline
// ---------------------------------------------------------------------------
__global__ __launch_bounds__(256) void bank_norms_kernel(
    const float* __restrict__ bank_pt, const float* __restrict__ bank_rgb,
    float* __restrict__ bn_pt, float* __restrict__ bn_rgb) {
  const int branch = blockIdx.y;
  const float* bank = branch ? bank_rgb : bank_pt;
  float* bn = branch ? bn_rgb : bn_pt;
  const int D = branch ? DRG : DPT;
  const int w = threadIdx.x >> 6, lane = threadIdx.x & 63;
  const int row = blockIdx.x * 4 + w;
  const float2* rp = (const float2*)(bank + (size_t)row * D);
  const int cnt = D >> 7;
  float s = 0.f;
  for (int i = 0; i < cnt; ++i) {
    float2 v = rp[lane + 64 * i];
    s += v.x * v.x + v.y * v.y;
  }
  for (int sft = 1; sft < 64; sft <<= 1) s += __shfl_xor(s, sft, 64);
  if (lane == 0) bn[row] = s;
}

__global__ __launch_bounds__(256) void prep_fb_kernel(
    const float* __restrict__ feat_pt, const float* __restrict__ feat_rgb,
    const int* __restrict__ valid_mask,
    float* __restrict__ xx_pt, float* __restrict__ xx_rgb,
    float* __restrict__ gs_pt, float* __restrict__ gs_rgb) {
  const int b = blockIdx.y;
  const int w = threadIdx.x >> 6, lane = threadIdx.x & 63;
  float2 gp[9], gr[6];
#pragma unroll
  for (int i = 0; i < 9; ++i) gp[i] = make_float2(0.f, 0.f);
#pragma unroll
  for (int i = 0; i < 6; ++i) gr[i] = make_float2(0.f, 0.f);
  const int pbase = blockIdx.x * 16 + w * 4;
#pragma unroll
  for (int pi = 0; pi < 4; ++pi) {
    const int p = pbase + pi;
    const float msk = (float)valid_mask[b * NP + p];
    const float2* xr = (const float2*)(feat_pt + ((size_t)b * NP + p) * DPT);
    float s = 0.f;
#pragma unroll
    for (int i = 0; i < 9; ++i) {
      float2 v = xr[lane + 64 * i];
      s += v.x * v.x + v.y * v.y;
      gp[i].x += msk * v.x; gp[i].y += msk * v.y;
    }
    const float2* rr = (const float2*)(feat_rgb + ((size_t)b * NP + p) * DRG);
    float s2 = 0.f;
#pragma unroll
    for (int i = 0; i < 6; ++i) {
      float2 v = rr[lane + 64 * i];
      s2 += v.x * v.x + v.y * v.y;
      gr[i].x += msk * v.x; gr[i].y += msk * v.y;
    }
    for (int sft = 1; sft < 64; sft <<= 1) {
      s += __shfl_xor(s, sft, 64);
      s2 += __shfl_xor(s2, sft, 64);
    }
    if (lane == 0) {
      xx_pt[b * NP + p] = s;
      xx_rgb[b * NP + p] = s2;
    }
  }
#pragma unroll
  for (int i = 0; i < 9; ++i) {
    int d = 2 * (lane + 64 * i);
    atomicAdd(&gs_pt[b * DPT + d], gp[i].x);
    atomicAdd(&gs_pt[b * DPT + d + 1], gp[i].y);
  }
#pragma unroll
  for (int i = 0; i < 6; ++i) {
    int d = 2 * (lane + 64 * i);
    atomicAdd(&gs_rgb[b * DRG + d], gr[i].x);
    atomicAdd(&gs_rgb[b * DRG + d + 1], gr[i].y);
  }
}

__global__ __launch_bounds__(256) void gemm_min_kernel(
    const float* __restrict__ feat_pt, const float* __restrict__ feat_rgb,
    const float* __restrict__ bank_pt, const float* __restrict__ bank_rgb,
    const float* __restrict__ bn_pt, const float* __restrict__ bn_rgb,
    const int* __restrict__ classlabels,
    unsigned* __restrict__ mc_pt, unsigned* __restrict__ mc_rgb) {
  const int branch = blockIdx.z;
  const int b = blockIdx.y;
  const int ptile = blockIdx.x % 7;
  const int mchunk = blockIdx.x / 7;
  const int D = branch ? DRG : DPT;
  const float* feat = branch ? feat_rgb : feat_pt;
  const float* bank = branch ? bank_rgb : bank_pt;
  const float* bn = branch ? bn_rgb : bn_pt;
  unsigned* mc = branch ? mc_rgb : mc_pt;
  const int cls = classlabels[b];

  __shared__ __align__(16) unsigned short As[128 * 32];
  __shared__ __align__(16) unsigned short Bs2[128 * 32];

  const int tid = threadIdx.x;
  const int r = tid >> 1;
  const int h = tid & 1;
  const int p0 = ptile * 128;
  const int prow = (p0 + r < NP) ? (p0 + r) : (NP - 1);
  const float* Arow = feat + ((size_t)b * NP + prow) * D + h * 16;
  const float* BankC = bank + (size_t)cls * NM * D;
  const float* bnC = bn + cls * NM;
  const int swz = (r >> 1) & 3;
  const int wo0 = r * 32 + ((2 * h) ^ swz) * 8;
  const int wo1 = r * 32 + ((2 * h + 1) ^ swz) * 8;

  const int lane = tid & 63;
  const int w = tid >> 6;
  const int wr = w >> 1, wcq = w & 1;
  const int lrow = lane & 15, lk = lane >> 4;
  int aoff[4], boff[4];
#pragma unroll
  for (int i = 0; i < 4; ++i) {
    int row = wr * 64 + i * 16 + lrow;
    aoff[i] = row * 32 + (lk ^ ((row >> 1) & 3)) * 8;
    row = wcq * 64 + i * 16 + lrow;
    boff[i] = row * 32 + (lk ^ ((row >> 1) & 3)) * 8;
  }

  float rm[4][4];
#pragma unroll
  for (int i = 0; i < 4; ++i)
#pragma unroll
    for (int e = 0; e < 4; ++e) rm[i][e] = 1e30f;

  union V16 { unsigned short s[8]; float4 v; };

#pragma unroll 1
  for (int mt = 0; mt < 8; ++mt) {
    const int mbase = mchunk * 1024 + mt * 128;
    const float* Brow = BankC + (size_t)(mbase + r) * D + h * 16;
    f32x4 acc[4][4];
#pragma unroll
    for (int i = 0; i < 4; ++i)
#pragma unroll
      for (int j = 0; j < 4; ++j) acc[i][j] = (f32x4){0.f, 0.f, 0.f, 0.f};

#pragma unroll 1
    for (int k0 = 0; k0 < D; k0 += 32) {
      __syncthreads();
      {
        const float4* ga = (const float4*)(Arow + k0);
        float4 f0 = ga[0], f1 = ga[1], f2 = ga[2], f3 = ga[3];
        V16 u0, u1;
        u0.s[0] = f2bf(f0.x); u0.s[1] = f2bf(f0.y); u0.s[2] = f2bf(f0.z); u0.s[3] = f2bf(f0.w);
        u0.s[4] = f2bf(f1.x); u0.s[5] = f2bf(f1.y); u0.s[6] = f2bf(f1.z); u0.s[7] = f2bf(f1.w);
        u1.s[0] = f2bf(f2.x); u1.s[1] = f2bf(f2.y); u1.s[2] = f2bf(f2.z); u1.s[3] = f2bf(f2.w);
        u1.s[4] = f2bf(f3.x); u1.s[5] = f2bf(f3.y); u1.s[6] = f2bf(f3.z); u1.s[7] = f2bf(f3.w);
        *(float4*)&As[wo0] = u0.v;
        *(float4*)&As[wo1] = u1.v;
      }
      {
        const float4* gb = (const float4*)(Brow + k0);
        float4 f0 = gb[0], f1 = gb[1], f2 = gb[2], f3 = gb[3];
        V16 u0, u1;
        u0.s[0] = f2bf(f0.x); u0.s[1] = f2bf(f0.y); u0.s[2] = f2bf(f0.z); u0.s[3] = f2bf(f0.w);
        u0.s[4] = f2bf(f1.x); u0.s[5] = f2bf(f1.y); u0.s[6] = f2bf(f1.z); u0.s[7] = f2bf(f1.w);
        u1.s[0] = f2bf(f2.x); u1.s[1] = f2bf(f2.y); u1.s[2] = f2bf(f2.z); u1.s[3] = f2bf(f2.w);
        u1.s[4] = f2bf(f3.x); u1.s[5] = f2bf(f3.y); u1.s[6] = f2bf(f3.z); u1.s[7] = f2bf(f3.w);
        *(float4*)&Bs2[wo0] = u0.v;
        *(float4*)&Bs2[wo1] = u1.v;
      }
      __syncthreads();
      bf16x8 af[4], bfv[4];
#pragma unroll
      for (int i = 0; i < 4; ++i) {
        af[i] = *(const bf16x8*)&As[aoff[i]];
        bfv[i] = *(const bf16x8*)&Bs2[boff[i]];
      }
#pragma unroll
      for (int i = 0; i < 4; ++i)
#pragma unroll
        for (int j = 0; j < 4; ++j)
          acc[i][j] = __builtin_amdgcn_mfma_f32_16x16x32_bf16(af[i], bfv[j], acc[i][j], 0, 0, 0);
    }
#pragma unroll
    for (int j = 0; j < 4; ++j) {
      float bnv = bnC[mbase + wcq * 64 + j * 16 + lrow];
#pragma unroll
      for (int i = 0; i < 4; ++i)
#pragma unroll
        for (int e = 0; e < 4; ++e)
          rm[i][e] = fminf(rm[i][e], bnv - 2.0f * acc[i][j][e]);
    }
  }
#pragma unroll
  for (int s = 1; s < 16; s <<= 1)
#pragma unroll
    for (int i = 0; i < 4; ++i)
#pragma unroll
      for (int e = 0; e < 4; ++e)
        rm[i][e] = fminf(rm[i][e], __shfl_xor(rm[i][e], s, 64));
  if (lrow == 0) {
#pragma unroll
    for (int i = 0; i < 4; ++i)
#pragma unroll
      for (int e = 0; e < 4; ++e) {
        int p = p0 + wr * 64 + i * 16 + lk * 4 + e;
        if (p < NP) atomicMin(&mc[b * NP + p], enc_f(rm[i][e]));
      }
  }
}

__global__ __launch_bounds__(256) void gdist_fb_kernel(
    const float* __restrict__ bgp, const float* __restrict__ bgr,
    const float* __restrict__ gs_pt, const float* __restrict__ gs_rgb,
    const int* __restrict__ classlabels, const int* __restrict__ valid_mask,
    const float* __restrict__ xx_pt, const float* __restrict__ xx_rgb,
    const unsigned* __restrict__ mc_pt, const unsigned* __restrict__ mc_rgb,
    float* __restrict__ partial) {
  const int b = blockIdx.x;
  const int tid = threadIdx.x;
  const int w = tid >> 6, lane = tid & 63;
  __shared__ float sred[256], sred2[256], sred3[256];
  __shared__ float gsh[DPT];
  __shared__ float wmin[4];
  float nvi = 0.f, spt = 0.f, srgb = 0.f;
  for (int p = tid; p < NP; p += 256) {
    float m = (float)valid_mask[b * NP + p];
    nvi += m;
    float dpt = xx_pt[b * NP + p] + dec_f(mc_pt[b * NP + p]);
    dpt = sqrtf(fminf(fmaxf(dpt, 1e-12f), 50.f));
    float drg = xx_rgb[b * NP + p] + dec_f(mc_rgb[b * NP + p]);
    drg = sqrtf(fminf(fmaxf(drg, 1e-12f), 50.f));
    spt += m * dpt;
    srgb += drg;
  }
  sred[tid] = nvi; sred2[tid] = spt; sred3[tid] = srgb;
  __syncthreads();
  for (int s = 128; s > 0; s >>= 1) {
    if (tid < s) {
      sred[tid] += sred[tid + s];
      sred2[tid] += sred2[tid + s];
      sred3[tid] += sred3[tid + s];
    }
    __syncthreads();
  }
  const float nv = sred[0];
  const float mean_pt = sred2[0] / nv;
  const float mean_rgb = sred3[0] / (float)NP;
  const int cls = classlabels[b];
  float ming_pt, ming_rgb;
  for (int d = tid; d < DPT; d += 256) gsh[d] = gs_pt[b * DPT + d] / nv;
  __syncthreads();
  {
    float mn = 1e30f;
    for (int row = w; row < NMG; row += 4) {
      const float2* yr = (const float2*)(bgp + ((size_t)cls * NMG + row) * DPT);
      float s = 0.f;
#pragma unroll
      for (int i = 0; i < 9; ++i) {
        float2 y = yr[lane + 64 * i];
        int d = 2 * (lane + 64 * i);
        float dx = gsh[d] - y.x, dy = gsh[d + 1] - y.y;
        s += dx * dx + dy * dy;
      }
      for (int sft = 1; sft < 64; sft <<= 1) s += __shfl_xor(s, sft, 64);
      mn = fminf(mn, s);
    }
    if (lane == 0) wmin[w] = mn;
    __syncthreads();
    float m2 = fminf(fminf(wmin[0], wmin[1]), fminf(wmin[2], wmin[3]));
    ming_pt = sqrtf(fminf(fmaxf(m2, 1e-12f), 50.f));
    __syncthreads();
  }
  for (int d = tid; d < DRG; d += 256) gsh[d] = gs_rgb[b * DRG + d] / nv;
  __syncthreads();
  {
    float mn = 1e30f;
    for (int row = w; row < NMG; row += 4) {
      const float2* yr = (const float2*)(bgr + ((size_t)cls * NMG + row) * DRG);
      float s = 0.f;
#pragma unroll
      for (int i = 0; i < 6; ++i) {
        float2 y = yr[lane + 64 * i];
        int d = 2 * (lane + 64 * i);
        float dx = gsh[d] - y.x, dy = gsh[d + 1] - y.y;
        s += dx * dx + dy * dy;
      }
      for (int sft = 1; sft < 64; sft <<= 1) s += __shfl_xor(s, sft, 64);
      mn = fminf(mn, s);
    }
    if (lane == 0) wmin[w] = mn;
    __syncthreads();
    float m2 = fminf(fminf(wmin[0], wmin[1]), fminf(wmin[2], wmin[3]));
    ming_rgb = sqrtf(fminf(fmaxf(m2, 1e-12f), 50.f));
  }
  if (tid == 0)
    partial[b] = mean_rgb + mean_pt + 0.4f * (ming_pt + ming_rgb);
}

// ---------------------------------------------------------------------------
extern "C" void kernel_launch(void* const* d_in, const int* in_sizes, int n_in,
                              void* d_out, int out_size, void* d_ws, size_t ws_size,
                              hipStream_t stream) {
  const float* feat_pt = (const float*)d_in[0];
  const float* feat_rgb = (const float*)d_in[1];
  const float* bank_pt = (const float*)d_in[2];
  const float* bank_rgb = (const float*)d_in[3];
  const float* bgp = (const float*)d_in[4];
  const float* bgr = (const float*)d_in[5];
  const int* classlabels = (const int*)d_in[6];
  const int* valid_mask = (const int*)d_in[7];
  float* out = (float*)d_out;

  const size_t BBP = (size_t)NC * NM * DPT;   // bank fp8 bytes
  const size_t BBR = (size_t)NC * NM * DRG;
  const size_t FBP = (size_t)NB * NP * DPT;   // feature fp8 bytes
  const size_t FBR = (size_t)NB * NP * DRG;
  const size_t GSPART = (size_t)NB * 49 * DTOT;  // 1.5M floats
  const size_t SMALL_WORDS = 4 * (size_t)NC * NM + 8 * (size_t)NB * NP +
                             GSPART + (size_t)NB * 49 + 8 * NB + 2 * NC + 256;
  const size_t NEED = (BBP + BBR + FBP + FBR) + 4 * SMALL_WORDS;
  const bool fast = (ws_size >= NEED);

  if (fast) {
    unsigned char* b8_pt = (unsigned char*)d_ws;
    unsigned char* b8_rgb = b8_pt + BBP;
    unsigned char* f8_pt = b8_rgb + BBR;
    unsigned char* f8_rgb = f8_pt + FBP;
    float* fl = (float*)(f8_rgb + FBR);
    float* bn_pt = fl;                          // NC*NM
    float* bn_rgb = bn_pt + NC * NM;
    float* bnS_pt = bn_rgb + NC * NM;           // NC*NM
    float* bnS_rgb = bnS_pt + NC * NM;
    float* xx_pt = bnS_rgb + NC * NM;           // NB*NP
    float* xx_rgb = xx_pt + NB * NP;
    float* xxS_pt = xx_rgb + NB * NP;
    float* xxS_rgb = xxS_pt + NB * NP;
    float* gs_part = xxS_rgb + NB * NP;         // NB*49*DTOT
    float* nv_part = gs_part + GSPART;          // NB*49
    unsigned* mc_pt = (unsigned*)(nv_part + NB * 49);
    unsigned* mc_rgb = mc_pt + NB * NP;
    unsigned* pmc_pt = mc_rgb + NB * NP;
    unsigned* pmc_rgb = pmc_pt + NB * NP;
    float* partial = (float*)(pmc_rgb + NB * NP);   // NB
    unsigned* gmin = (unsigned*)(partial + NB);     // 2*NB
    unsigned* flagF = gmin + 2 * NB;                // 2*NB
    unsigned* classFlag = flagF + 2 * NB;           // NC

    fused_cp_kernel<<<2080, 256, 0, stream>>>(
        feat_pt, feat_rgb, bank_pt, bank_rgb, classlabels, valid_mask,
        xx_pt, xx_rgb, xxS_pt, xxS_rgb, gs_part, nv_part,
        f8_pt, f8_rgb, b8_pt, b8_rgb, bnS_pt, bnS_rgb,
        mc_pt, gmin, flagF, classFlag);
    fused_g1_kernel<<<768, 256, 0, stream>>>(
        f8_pt, f8_rgb, b8_pt, b8_rgb, bnS_pt, bnS_rgb, classlabels,
        pmc_pt, pmc_rgb, bgp, bgr, gs_part, nv_part, gmin);
    flag_kernel<<<32, 256, 0, stream>>>(
        xxS_pt, xxS_rgb, pmc_pt, pmc_rgb, classlabels, flagF, classFlag);
    fullconv_kernel<<<2064, 256, 0, stream>>>(
        bank_pt, bank_rgb, feat_pt, feat_rgb, b8_pt, b8_rgb, f8_pt, f8_rgb,
        bn_pt, bn_rgb, classFlag, flagF);
    gemm2_kernel<<<dim3(64, NB), 256, 0, stream>>>(
        f8_pt, f8_rgb, b8_pt, b8_rgb, bn_pt, bn_rgb, classlabels, flagF, mc_pt, mc_rgb);
    gdistB_kernel<<<NB, 256, 0, stream>>>(
        valid_mask, xx_pt, xx_rgb, mc_pt, mc_rgb, nv_part, gmin, partial);
    final_kernel<<<1, 64, 0, stream>>>(partial, out);
  } else {
    float* ws = (float*)d_ws;
    float* bn_pt = ws;
    float* bn_rgb = bn_pt + NC * NM;
    float* xx_pt = bn_rgb + NC * NM;
    float* xx_rgb = xx_pt + NB * NP;
    float* gs_pt = xx_rgb + NB * NP;
    float* gs_rgb = gs_pt + NB * DPT;
    unsigned* mc_pt = (unsigned*)(gs_rgb + NB * DRG);
    unsigned* mc_rgb = mc_pt + NB * NP;
    float* partial = (float*)(mc_rgb + NB * NP);

    hipMemsetAsync(gs_pt, 0, (size_t)(NB * DPT + NB * DRG) * 4, stream);
    hipMemsetAsync(mc_pt, 0xF7, (size_t)(2 * NB * NP) * 4, stream);

    bank_norms_kernel<<<dim3(NC * NM / 4, 2), 256, 0, stream>>>(bank_pt, bank_rgb, bn_pt, bn_rgb);
    prep_fb_kernel<<<dim3(49, NB), 256, 0, stream>>>(
        feat_pt, feat_rgb, valid_mask, xx_pt, xx_rgb, gs_pt, gs_rgb);
    gemm_min_kernel<<<dim3(28, NB, 2), 256, 0, stream>>>(
        feat_pt, feat_rgb, bank_pt, bank_rgb, bn_pt, bn_rgb, classlabels, mc_pt, mc_rgb);
    gdist_fb_kernel<<<NB, 256, 0, stream>>>(bgp, bgr, gs_pt, gs_rgb, classlabels, valid_mask,
                                            xx_pt, xx_rgb, mc_pt, mc_rgb, partial);
    final_kernel<<<1, 64, 0, stream>>>(partial, out);
  }
}

// Round 19
// 100.949 us; speedup vs baseline: 2.0064x; 1.0286x over previous
//
#include <hip/hip_runtime.h>
#include <hip/hip_bf16.h>

// Problem constants (match reference)
#define NB 16
#define NP 784
#define NC 10
#define NM 4096
#define NMG 128
#define DPT 1152
#define DRG 768
#define DTOT (DPT + DRG)   // 1920

typedef __attribute__((ext_vector_type(8))) short bf16x8;    // 8 bf16 (4 VGPR)
typedef __attribute__((ext_vector_type(4))) float f32x4;     // 16x16 MFMA acc
typedef __attribute__((ext_vector_type(4))) int i32x4;
typedef __attribute__((ext_vector_type(8))) int i32x8;

#define SONE 0x7F7F7F7F   // e8m0 scale = 1.0 in every byte
#define SKIP_THR 70.0f    // clamp(50) + fp8-quantization guard band

__device__ __forceinline__ unsigned short f2bf(float f) {
  unsigned u = __float_as_uint(f);
  return (unsigned short)((u + 0x7fffu + ((u >> 16) & 1u)) >> 16); // RNE
}
// order-preserving float->uint encoding (for atomicMin on float values)
__device__ __forceinline__ unsigned enc_f(float f) {
  unsigned u = __float_as_uint(f);
  return (u & 0x80000000u) ? ~u : (u | 0x80000000u);
}
__device__ __forceinline__ float dec_f(unsigned u) {
  return __uint_as_float((u & 0x80000000u) ? (u & 0x7fffffffu) : ~u);
}
// async global->LDS, 16B per lane. LDS dest must be wave-uniform (HW adds lane*16).
__device__ __forceinline__ void gl_lds16(const void* g, void* s) {
  __builtin_amdgcn_global_load_lds(
      (const __attribute__((address_space(1))) unsigned int*)g,
      (__attribute__((address_space(3))) unsigned int*)s, 16, 0, 0);
}

// ---------------------------------------------------------------------------
// FUSED init + convert128 + prep (one launch, independent block roles):
//  blk [0,784):     prep — patch norms (full + first-128), gs PARTIALS,
//                   nv partial (plain store), fp8 convert of first 128 dims.
//  blk [784,2064):  bank fp32 -> fp8 first 128 dims + partial norms, 64 rows
//                   per block (present gate computed inline from classlabels).
//  blk [2064,2080): init — mc sentinels, gmin sentinels, flag zeros.
// ---------------------------------------------------------------------------
__global__ __launch_bounds__(256) void fused_cp_kernel(
    const float* __restrict__ feat_pt, const float* __restrict__ feat_rgb,
    const float* __restrict__ bank_pt, const float* __restrict__ bank_rgb,
    const int* __restrict__ classlabels, const int* __restrict__ valid_mask,
    float* __restrict__ xx_pt, float* __restrict__ xx_rgb,
    float* __restrict__ xxS_pt, float* __restrict__ xxS_rgb,
    float* __restrict__ gs_part,   // [NB][49][DTOT]
    float* __restrict__ nv_part,   // [NB][49]
    unsigned char* __restrict__ f8_pt, unsigned char* __restrict__ f8_rgb,
    unsigned char* __restrict__ b8_pt, unsigned char* __restrict__ b8_rgb,
    float* __restrict__ bnS_pt, float* __restrict__ bnS_rgb,
    unsigned* __restrict__ mc, unsigned* __restrict__ gmin,
    unsigned* __restrict__ flagF, unsigned* __restrict__ classFlag) {
  __shared__ float accL[4][DTOT];   // 30 KB (prep blocks only)
  __shared__ float wnv[4];
  const int blk = blockIdx.x;
  const int w = threadIdx.x >> 6, lane = threadIdx.x & 63;
  if (blk < 784) {
    const int b = blk / 49, xb = blk % 49;
    float2 gp[9], gr[6];
#pragma unroll
    for (int i = 0; i < 9; ++i) gp[i] = make_float2(0.f, 0.f);
#pragma unroll
    for (int i = 0; i < 6; ++i) gr[i] = make_float2(0.f, 0.f);
    const int pbase = xb * 16 + w * 4;
    float mcount = 0.f;
#pragma unroll
    for (int pi = 0; pi < 4; ++pi) {
      const int p = pbase + pi;
      const float msk = (float)valid_mask[b * NP + p];
      mcount += msk;
      const float2* xr = (const float2*)(feat_pt + ((size_t)b * NP + p) * DPT);
      unsigned short* xw = (unsigned short*)(f8_pt + ((size_t)b * NP + p) * DPT);
      float s = 0.f, sp = 0.f;
#pragma unroll
      for (int i = 0; i < 9; ++i) {
        float2 v = xr[lane + 64 * i];
        float c2 = v.x * v.x + v.y * v.y;
        s += c2;
        if (i == 0) {
          sp = c2;   // dims 0..127
          int pk = __builtin_amdgcn_cvt_pk_fp8_f32(v.x, v.y, 0, false);
          xw[lane] = (unsigned short)(pk & 0xFFFF);
        }
        gp[i].x += msk * v.x; gp[i].y += msk * v.y;
      }
      const float2* rr = (const float2*)(feat_rgb + ((size_t)b * NP + p) * DRG);
      unsigned short* rw = (unsigned short*)(f8_rgb + ((size_t)b * NP + p) * DRG);
      float s2 = 0.f, sp2 = 0.f;
#pragma unroll
      for (int i = 0; i < 6; ++i) {
        float2 v = rr[lane + 64 * i];
        float c2 = v.x * v.x + v.y * v.y;
        s2 += c2;
        if (i == 0) {
          sp2 = c2;  // dims 0..127
          int pk = __builtin_amdgcn_cvt_pk_fp8_f32(v.x, v.y, 0, false);
          rw[lane] = (unsigned short)(pk & 0xFFFF);
        }
        gr[i].x += msk * v.x; gr[i].y += msk * v.y;
      }
      for (int sft = 1; sft < 64; sft <<= 1) {
        s += __shfl_xor(s, sft, 64);
        s2 += __shfl_xor(s2, sft, 64);
        sp += __shfl_xor(sp, sft, 64);
        sp2 += __shfl_xor(sp2, sft, 64);
      }
      if (lane == 0) {
        xx_pt[b * NP + p] = s;
        xx_rgb[b * NP + p] = s2;
        xxS_pt[b * NP + p] = sp;
        xxS_rgb[b * NP + p] = sp2;
      }
    }
    // per-wave rows into LDS (conflict-free float2 stores), then 4->1 reduce
#pragma unroll
    for (int i = 0; i < 9; ++i)
      *(float2*)&accL[w][2 * (lane + 64 * i)] = gp[i];
#pragma unroll
    for (int i = 0; i < 6; ++i)
      *(float2*)&accL[w][DPT + 2 * (lane + 64 * i)] = gr[i];
    if (lane == 0) wnv[w] = mcount;
    __syncthreads();
    float* dst = gs_part + ((size_t)b * 49 + xb) * DTOT;
    for (int e = threadIdx.x; e < DTOT; e += 256)
      dst[e] = accL[0][e] + accL[1][e] + accL[2][e] + accL[3][e];
    if (threadIdx.x == 0)
      nv_part[b * 49 + xb] = wnv[0] + wnv[1] + wnv[2] + wnv[3];
  } else if (blk < 2064) {
    const int cb = blk - 784;          // 0..1279
    const int branch = cb & 1;
    const int grp = cb >> 1;           // 0..639
    const int c = grp >> 6;
    bool pres = false;
#pragma unroll
    for (int i = 0; i < NB; ++i) pres |= (classlabels[i] == c);
    if (!pres) return;
    const int rch = grp & 63;
    const float* bank = branch ? bank_rgb : bank_pt;
    unsigned char* b8 = branch ? b8_rgb : b8_pt;
    float* bnS = branch ? bnS_rgb : bnS_pt;
    const int D = branch ? DRG : DPT;
#pragma unroll 1
    for (int rl = 0; rl < 16; ++rl) {
      const int row = (c << 12) + rch * 64 + w * 16 + rl;
      const float2* rp = (const float2*)(bank + (size_t)row * D);
      unsigned short* dp = (unsigned short*)(b8 + (size_t)row * D);
      float2 v = rp[lane];
      float s = v.x * v.x + v.y * v.y;
      int pk = __builtin_amdgcn_cvt_pk_fp8_f32(v.x, v.y, 0, false);
      dp[lane] = (unsigned short)(pk & 0xFFFF);
      for (int sft = 1; sft < 64; sft <<= 1) s += __shfl_xor(s, sft, 64);
      if (lane == 0) bnS[row] = s;
    }
  } else {
    // init blocks: sentinels + flag zeros (consumed by LATER kernels only)
    const int tid = (blk - 2064) * 256 + threadIdx.x;
    const int stride = 16 * 256;
    const int total_mc = 2 * NB * NP;  // mc only (pmc eliminated)
    for (int i = tid; i < total_mc; i += stride) mc[i] = 0xF7F7F7F7u;
    if (tid < 2 * NB) gmin[tid] = 0xF7F7F7F7u;
    if (tid < 2 * NB) flagF[tid] = 0u;
    if (tid < NC) classFlag[tid] = 0u;
  }
}

// ---------------------------------------------------------------------------
// FUSED gemm1 + gdistA:
//  blk [0,512):   certificate GEMM, 2 m-chunks (256 bank rows) per block.
//                 Sets flagF/classFlag DIRECTLY (sound: chunk-min trip =>
//                 true-min trip; no chunk trips => true bound >= THR since
//                 the overall min equals one chunk's min). pmc eliminated.
//  blk [512,768): gdistA — global-bank min; gsh from 49 gs partials with
//                 ILP-parallel accumulators; nv summed inline.
// ---------------------------------------------------------------------------
__global__ __launch_bounds__(256) void fused_g1_kernel(
    const unsigned char* __restrict__ f8_pt, const unsigned char* __restrict__ f8_rgb,
    const unsigned char* __restrict__ b8_pt, const unsigned char* __restrict__ b8_rgb,
    const float* __restrict__ bnS_pt, const float* __restrict__ bnS_rgb,
    const float* __restrict__ xxS_pt, const float* __restrict__ xxS_rgb,
    const int* __restrict__ classlabels,
    unsigned* __restrict__ flagF, unsigned* __restrict__ classFlag,
    const float* __restrict__ bgp, const float* __restrict__ bgr,
    const float* __restrict__ gs_part, const float* __restrict__ nv_part,
    unsigned* __restrict__ gmin) {
  __shared__ __align__(16) unsigned char As[2][16384];
  __shared__ __align__(16) unsigned char Bs[16384];
  const int blk = blockIdx.x;
  const int t = threadIdx.x;
  const int w = t >> 6, lane = t & 63;

  if (blk >= 512) {
    // ---- gdistA ----
    const int g = blk - 512;           // 0..255
    const int slice = g & 7;
    const int b = (g >> 3) & 15;
    const int branch = g >> 7;
    const int D = branch ? DRG : DPT;
    const int base = branch ? DPT : 0;
    const float* bank = branch ? bgr : bgp;
    const int cls = classlabels[b];
    float* gsh = (float*)&As[0][0];    // reuse LDS
    float nv = 0.f;
    {
      const float* np_ = nv_part + b * 49;
      float n0 = 0.f, n1 = 0.f, n2 = 0.f, n3 = 0.f;
#pragma unroll
      for (int k = 0; k < 48; k += 4) {
        n0 += np_[k]; n1 += np_[k + 1]; n2 += np_[k + 2]; n3 += np_[k + 3];
      }
      nv = n0 + n1 + n2 + n3 + np_[48];
    }
    const float inv = 1.f / nv;
    const float* gp0 = gs_part + (size_t)b * 49 * DTOT + base;
    for (int d = t; d < D; d += 256) {
      const float* p = gp0 + d;
      float s0 = 0.f, s1 = 0.f, s2 = 0.f, s3 = 0.f;
#pragma unroll
      for (int k = 0; k < 48; k += 4) {
        s0 += p[(size_t)k * DTOT];
        s1 += p[(size_t)(k + 1) * DTOT];
        s2 += p[(size_t)(k + 2) * DTOT];
        s3 += p[(size_t)(k + 3) * DTOT];
      }
      s0 += p[(size_t)48 * DTOT];
      gsh[d] = (s0 + s1 + s2 + s3) * inv;
    }
    __syncthreads();
    const int cnt = D >> 7;
    float mn = 1e30f;
#pragma unroll 1
    for (int rl = 0; rl < 4; ++rl) {
      const int row = slice * 16 + w * 4 + rl;
      const float2* yr = (const float2*)(bank + ((size_t)cls * NMG + row) * D);
      float s = 0.f;
      for (int i = 0; i < cnt; ++i) {
        float2 y = yr[lane + 64 * i];
        int d = 2 * (lane + 64 * i);
        float dx = gsh[d] - y.x, dy = gsh[d + 1] - y.y;
        s += dx * dx + dy * dy;
      }
      for (int sft = 1; sft < 64; sft <<= 1) s += __shfl_xor(s, sft, 64);
      mn = fminf(mn, s);
    }
    if (lane == 0) atomicMin(&gmin[branch * NB + b], enc_f(mn));
    return;
  }

  // ---- gemm1: 2 m-chunks (256 rows) per block ----
  const int branch = blk & 1;
  const int mch = (blk >> 1) & 15;    // 16 chunks x 256 rows
  const int b = blk >> 5;
  const int D = branch ? DRG : DPT;
  const unsigned char* f8 = branch ? f8_rgb : f8_pt;
  const unsigned char* b8 = branch ? b8_rgb : b8_pt;
  const float* bnS = branch ? bnS_rgb : bnS_pt;
  const float* xxS = branch ? xxS_rgb : xxS_pt;
  const int cls = classlabels[b];

  const unsigned char* fB = f8 + (size_t)b * NP * D;
  const unsigned char* bB = b8 + (size_t)cls * NM * D;
  const int mbase = mch * 256;

  int rr[4], cx[4];
#pragma unroll
  for (int i = 0; i < 4; ++i) {
    int pos = w * 256 + i * 64 + lane;
    rr[i] = pos >> 3;
    cx[i] = ((pos & 7) ^ (rr[i] & 7)) << 4;
  }
  const int wr = w >> 1, wcq = w & 1;
  const int lrow = lane & 15, lk = lane >> 4;
  int aoff0[4], aoff1[4], boff0[4], boff1[4];
#pragma unroll
  for (int i = 0; i < 4; ++i) {
    int ra = wr * 64 + i * 16 + lrow;
    aoff0[i] = ra * 128 + ((lk * 32) ^ ((ra & 7) << 4));
    aoff1[i] = ra * 128 + ((lk * 32 + 16) ^ ((ra & 7) << 4));
    int rb = wcq * 64 + i * 16 + lrow;
    boff0[i] = rb * 128 + ((lk * 32) ^ ((rb & 7) << 4));
    boff1[i] = rb * 128 + ((lk * 32 + 16) ^ ((rb & 7) << 4));
  }
  float bnv[8];
#pragma unroll
  for (int j = 0; j < 4; ++j) {
    bnv[j] = bnS[cls * NM + mbase + wcq * 64 + j * 16 + lrow];
    bnv[4 + j] = bnS[cls * NM + mbase + 128 + wcq * 64 + j * 16 + lrow];
  }

  auto STAGE_A = [&](int pt, int buf) {
#pragma unroll
    for (int i = 0; i < 4; ++i) {
      int pr = pt * 128 + rr[i];
      if (pr > NP - 1) pr = NP - 1;
      gl_lds16(fB + (size_t)pr * D + cx[i], &As[buf][0] + (w * 4 + i) * 1024);
    }
  };
  auto STAGE_B = [&](int half) {
#pragma unroll
    for (int i = 0; i < 4; ++i)
      gl_lds16(bB + (size_t)(mbase + half * 128 + rr[i]) * D + cx[i],
               &Bs[0] + (w * 4 + i) * 1024);
  };

  // prologue: B half 0 -> regs, B half 1 -> regs (one LDS buffer), then A0,A1
  i32x8 bfv[8];
  STAGE_B(0);
  asm volatile("s_waitcnt vmcnt(0)" ::: "memory");
  __builtin_amdgcn_s_barrier();
  __builtin_amdgcn_sched_barrier(0);
#pragma unroll
  for (int i = 0; i < 4; ++i) {
    i32x4 lo = *(const i32x4*)(&Bs[0] + boff0[i]);
    i32x4 hi = *(const i32x4*)(&Bs[0] + boff1[i]);
    bfv[i] = __builtin_shufflevector(lo, hi, 0, 1, 2, 3, 4, 5, 6, 7);
  }
  asm volatile("s_waitcnt lgkmcnt(0)" ::: "memory");
  __builtin_amdgcn_sched_barrier(0);
  __builtin_amdgcn_s_barrier();
  STAGE_B(1);
  asm volatile("s_waitcnt vmcnt(0)" ::: "memory");
  __builtin_amdgcn_s_barrier();
  __builtin_amdgcn_sched_barrier(0);
#pragma unroll
  for (int i = 0; i < 4; ++i) {
    i32x4 lo = *(const i32x4*)(&Bs[0] + boff0[i]);
    i32x4 hi = *(const i32x4*)(&Bs[0] + boff1[i]);
    bfv[4 + i] = __builtin_shufflevector(lo, hi, 0, 1, 2, 3, 4, 5, 6, 7);
  }
  asm volatile("s_waitcnt lgkmcnt(0)" ::: "memory");
  __builtin_amdgcn_sched_barrier(0);
  __builtin_amdgcn_s_barrier();
  STAGE_A(0, 0);
  STAGE_A(1, 1);

#pragma unroll 1
  for (int pt = 0; pt < 7; ++pt) {
    const int cur = pt & 1;
    // entry: A(pt) done (A(pt+1) stays in flight)
    asm volatile("s_waitcnt vmcnt(4)" ::: "memory");
    __builtin_amdgcn_s_barrier();
    __builtin_amdgcn_sched_barrier(0);
    i32x8 af[4];
#pragma unroll
    for (int i = 0; i < 4; ++i) {
      i32x4 lo = *(const i32x4*)(&As[cur][0] + aoff0[i]);
      i32x4 hi = *(const i32x4*)(&As[cur][0] + aoff1[i]);
      af[i] = __builtin_shufflevector(lo, hi, 0, 1, 2, 3, 4, 5, 6, 7);
    }
    float rm[4][4];
#pragma unroll
    for (int i = 0; i < 4; ++i) {
      f32x4 q0 = (f32x4){0.f, 0.f, 0.f, 0.f};
      f32x4 q1 = q0, q2 = q0, q3 = q0, q4 = q0, q5 = q0, q6 = q0, q7 = q0;
      q0 = __builtin_amdgcn_mfma_scale_f32_16x16x128_f8f6f4(af[i], bfv[0], q0, 0, 0, 0, SONE, 0, SONE);
      q1 = __builtin_amdgcn_mfma_scale_f32_16x16x128_f8f6f4(af[i], bfv[1], q1, 0, 0, 0, SONE, 0, SONE);
      q2 = __builtin_amdgcn_mfma_scale_f32_16x16x128_f8f6f4(af[i], bfv[2], q2, 0, 0, 0, SONE, 0, SONE);
      q3 = __builtin_amdgcn_mfma_scale_f32_16x16x128_f8f6f4(af[i], bfv[3], q3, 0, 0, 0, SONE, 0, SONE);
      q4 = __builtin_amdgcn_mfma_scale_f32_16x16x128_f8f6f4(af[i], bfv[4], q4, 0, 0, 0, SONE, 0, SONE);
      q5 = __builtin_amdgcn_mfma_scale_f32_16x16x128_f8f6f4(af[i], bfv[5], q5, 0, 0, 0, SONE, 0, SONE);
      q6 = __builtin_amdgcn_mfma_scale_f32_16x16x128_f8f6f4(af[i], bfv[6], q6, 0, 0, 0, SONE, 0, SONE);
      q7 = __builtin_amdgcn_mfma_scale_f32_16x16x128_f8f6f4(af[i], bfv[7], q7, 0, 0, 0, SONE, 0, SONE);
#pragma unroll
      for (int e = 0; e < 4; ++e) {
        float v = bnv[0] - 2.0f * q0[e];
        v = fminf(v, bnv[1] - 2.0f * q1[e]);
        v = fminf(v, bnv[2] - 2.0f * q2[e]);
        v = fminf(v, bnv[3] - 2.0f * q3[e]);
        v = fminf(v, bnv[4] - 2.0f * q4[e]);
        v = fminf(v, bnv[5] - 2.0f * q5[e]);
        v = fminf(v, bnv[6] - 2.0f * q6[e]);
        v = fminf(v, bnv[7] - 2.0f * q7[e]);
        rm[i][e] = v;
      }
    }
#pragma unroll
    for (int s2 = 1; s2 < 16; s2 <<= 1)
#pragma unroll
      for (int i = 0; i < 4; ++i)
#pragma unroll
        for (int e = 0; e < 4; ++e)
          rm[i][e] = fminf(rm[i][e], __shfl_xor(rm[i][e], s2, 64));
    if (lrow == 0) {
      bool trip = false;
#pragma unroll
      for (int i = 0; i < 4; ++i)
#pragma unroll
        for (int e = 0; e < 4; ++e) {
          int p = pt * 128 + wr * 64 + i * 16 + lk * 4 + e;
          if (p < NP) {
            float bound = xxS[b * NP + p] + rm[i][e];
            trip |= (bound < SKIP_THR);
          }
        }
      if (trip) {
        atomicOr(&flagF[branch * NB + b], 1u);
        atomicOr(&classFlag[cls], 1u);
      }
    }
    // exit: all waves finished reading buf[cur] -> safe to overwrite
    asm volatile("s_waitcnt lgkmcnt(0)" ::: "memory");
    __builtin_amdgcn_sched_barrier(0);
    __builtin_amdgcn_s_barrier();
    if (pt + 2 < 7) STAGE_A(pt + 2, cur);
  }
}

// ---------------------------------------------------------------------------
// Full fp8 conversion (fallback only; gated). Flat grid:
//  blocks [0,1280): bank rows, gated classFlag; [1280,2064): features, flagF
// ---------------------------------------------------------------------------
__global__ __launch_bounds__(256) void fullconv_kernel(
    const float* __restrict__ bank_pt, const float* __restrict__ bank_rgb,
    const float* __restrict__ feat_pt, const float* __restrict__ feat_rgb,
    unsigned char* __restrict__ b8_pt, unsigned char* __restrict__ b8_rgb,
    unsigned char* __restrict__ f8_pt, unsigned char* __restrict__ f8_rgb,
    float* __restrict__ bn_pt, float* __restrict__ bn_rgb,
    const unsigned* __restrict__ classFlag, const unsigned* __restrict__ flagF) {
  const int id = blockIdx.x;
  const int w = threadIdx.x >> 6, lane = threadIdx.x & 63;
  if (id < 1280) {
    const int branch = id & 1;
    const int cb = id >> 1;
    const int c = cb >> 6;
    if (classFlag[c] == 0u) return;
    const int rch = cb & 63;
    const float* bank = branch ? bank_rgb : bank_pt;
    unsigned char* b8 = branch ? b8_rgb : b8_pt;
    float* bn = branch ? bn_rgb : bn_pt;
    const int D = branch ? DRG : DPT;
    const int D4 = D >> 2;
#pragma unroll 1
    for (int rl = 0; rl < 16; ++rl) {
      const int row = (c << 12) + rch * 64 + w * 16 + rl;
      const float4* rp = (const float4*)(bank + (size_t)row * D);
      unsigned* dp = (unsigned*)(b8 + (size_t)row * D);
      float s = 0.f;
      for (int i = lane; i < D4; i += 64) {
        float4 v = rp[i];
        s += v.x * v.x + v.y * v.y + v.z * v.z + v.w * v.w;
        int pk = __builtin_amdgcn_cvt_pk_fp8_f32(v.x, v.y, 0, false);
        pk = __builtin_amdgcn_cvt_pk_fp8_f32(v.z, v.w, pk, true);
        dp[i] = (unsigned)pk;
      }
      for (int sft = 1; sft < 64; sft <<= 1) s += __shfl_xor(s, sft, 64);
      if (lane == 0) bn[row] = s;
    }
  } else {
    const int fb = id - 1280;
    const int b = fb / 49, xb = fb % 49;
    if (flagF[b] == 0u && flagF[NB + b] == 0u) return;
    const int pbase = xb * 16 + w * 4;
#pragma unroll 1
    for (int pi = 0; pi < 4; ++pi) {
      const int p = pbase + pi;
      const float2* xr = (const float2*)(feat_pt + ((size_t)b * NP + p) * DPT);
      unsigned short* xw = (unsigned short*)(f8_pt + ((size_t)b * NP + p) * DPT);
#pragma unroll
      for (int i = 0; i < 9; ++i) {
        float2 v = xr[lane + 64 * i];
        int pk = __builtin_amdgcn_cvt_pk_fp8_f32(v.x, v.y, 0, false);
        xw[lane + 64 * i] = (unsigned short)(pk & 0xFFFF);
      }
      const float2* rr = (const float2*)(feat_rgb + ((size_t)b * NP + p) * DRG);
      unsigned short* rw = (unsigned short*)(f8_rgb + ((size_t)b * NP + p) * DRG);
#pragma unroll
      for (int i = 0; i < 6; ++i) {
        float2 v = rr[lane + 64 * i];
        int pk = __builtin_amdgcn_cvt_pk_fp8_f32(v.x, v.y, 0, false);
        rw[lane + 64 * i] = (unsigned short)(pk & 0xFFFF);
      }
    }
  }
}

// ---------------------------------------------------------------------------
// Stage-2 GEMM (fallback, R7 schedule): full-K MX-fp8, gated on flagF.
// grid: (64, NB), block 256.
// ---------------------------------------------------------------------------
__global__ __launch_bounds__(256) void gemm2_kernel(
    const unsigned char* __restrict__ f8_pt, const unsigned char* __restrict__ f8_rgb,
    const unsigned char* __restrict__ b8_pt, const unsigned char* __restrict__ b8_rgb,
    const float* __restrict__ bn_pt, const float* __restrict__ bn_rgb,
    const int* __restrict__ classlabels, const unsigned* __restrict__ flagF,
    unsigned* __restrict__ mc_pt, unsigned* __restrict__ mc_rgb) {
  const int branch = blockIdx.x & 1;
  const int mch = blockIdx.x >> 1;
  const int b = blockIdx.y;
  if (flagF[branch * NB + b] == 0u) return;   // certificate passed: all clamp
  const int D = branch ? DRG : DPT;
  const int NK = D >> 7;
  const unsigned char* f8 = branch ? f8_rgb : f8_pt;
  const unsigned char* b8 = branch ? b8_rgb : b8_pt;
  const float* bn = branch ? bn_rgb : bn_pt;
  unsigned* mc = branch ? mc_rgb : mc_pt;
  const int cls = classlabels[b];

  __shared__ __align__(16) unsigned char As[2][16384];
  __shared__ __align__(16) unsigned char Bs[2][16384];

  const int t = threadIdx.x;
  const int w = t >> 6, lane = t & 63;
  const unsigned char* fB = f8 + (size_t)b * NP * D;
  const unsigned char* bB = b8 + (size_t)cls * NM * D;
  const float* bnC = bn + cls * NM;
  const int mbase = mch * 128;

  int rr[4], cx[4];
  const unsigned char* pA[4];
  const unsigned char* pB[4];
#pragma unroll
  for (int i = 0; i < 4; ++i) {
    int pos = w * 256 + i * 64 + lane;
    rr[i] = pos >> 3;
    cx[i] = ((pos & 7) ^ (rr[i] & 7)) << 4;
    pB[i] = bB + (size_t)(mbase + rr[i]) * D + cx[i];
  }
  const int wr = w >> 1, wcq = w & 1;
  const int lrow = lane & 15, lk = lane >> 4;
  int aoff0[4], aoff1[4], boff0[4], boff1[4];
#pragma unroll
  for (int i = 0; i < 4; ++i) {
    int ra = wr * 64 + i * 16 + lrow;
    aoff0[i] = ra * 128 + ((lk * 32) ^ ((ra & 7) << 4));
    aoff1[i] = ra * 128 + ((lk * 32 + 16) ^ ((ra & 7) << 4));
    int rb = wcq * 64 + i * 16 + lrow;
    boff0[i] = rb * 128 + ((lk * 32) ^ ((rb & 7) << 4));
    boff1[i] = rb * 128 + ((lk * 32 + 16) ^ ((rb & 7) << 4));
  }
  auto mkA = [&](int pt) {
    const int p0 = pt * 128;
#pragma unroll
    for (int i = 0; i < 4; ++i) {
      int pr = p0 + rr[i];
      if (pr > NP - 1) pr = NP - 1;
      pA[i] = fB + (size_t)pr * D + cx[i];
    }
  };
  auto STAGE = [&](int k, int buf) {
    unsigned char* ab = &As[buf][0];
    unsigned char* bb2 = &Bs[buf][0];
#pragma unroll
    for (int i = 0; i < 4; ++i) gl_lds16(pA[i] + k, ab + (w * 4 + i) * 1024);
#pragma unroll
    for (int i = 0; i < 4; ++i) gl_lds16(pB[i] + k, bb2 + (w * 4 + i) * 1024);
  };

  mkA(0);
  STAGE(0, 0);
  int cur = 0;
  int npt = 0, nk = 128;

#pragma unroll 1
  for (int pt = 0; pt < 7; ++pt) {
    float rm[4][4];
    f32x4 acc[4][4];
#pragma unroll
    for (int i = 0; i < 4; ++i)
#pragma unroll
      for (int j = 0; j < 4; ++j) {
        acc[i][j] = (f32x4){0.f, 0.f, 0.f, 0.f};
        rm[i][j] = 1e30f;
      }
#pragma unroll 1
    for (int s = 0; s < NK; ++s) {
      STAGE(nk, cur ^ 1);
      if (npt < 7) {
        nk += 128;
        if (nk == D) { nk = 0; ++npt; if (npt < 7) mkA(npt); else nk = 0; }
      }
      asm volatile("s_waitcnt vmcnt(8)" ::: "memory");
      __builtin_amdgcn_s_barrier();
      __builtin_amdgcn_sched_barrier(0);
      const unsigned char* ab = &As[cur][0];
      const unsigned char* bb2 = &Bs[cur][0];
      i32x8 af[4], bfv[4];
#pragma unroll
      for (int i = 0; i < 4; ++i) {
        i32x4 lo = *(const i32x4*)(ab + aoff0[i]);
        i32x4 hi = *(const i32x4*)(ab + aoff1[i]);
        af[i] = __builtin_shufflevector(lo, hi, 0, 1, 2, 3, 4, 5, 6, 7);
        i32x4 lo2 = *(const i32x4*)(bb2 + boff0[i]);
        i32x4 hi2 = *(const i32x4*)(bb2 + boff1[i]);
        bfv[i] = __builtin_shufflevector(lo2, hi2, 0, 1, 2, 3, 4, 5, 6, 7);
      }
#pragma unroll
      for (int i = 0; i < 4; ++i)
#pragma unroll
        for (int j = 0; j < 4; ++j)
          acc[i][j] = __builtin_amdgcn_mfma_scale_f32_16x16x128_f8f6f4(
              af[i], bfv[j], acc[i][j], 0, 0, 0, SONE, 0, SONE);
      asm volatile("s_waitcnt lgkmcnt(0)" ::: "memory");
      __builtin_amdgcn_sched_barrier(0);
      __builtin_amdgcn_s_barrier();
      cur ^= 1;
    }
#pragma unroll
    for (int j = 0; j < 4; ++j) {
      float bnv = bnC[mbase + wcq * 64 + j * 16 + lrow];
#pragma unroll
      for (int i = 0; i < 4; ++i)
#pragma unroll
        for (int e = 0; e < 4; ++e)
          rm[i][e] = fminf(rm[i][e], bnv - 2.0f * acc[i][j][e]);
    }
#pragma unroll
    for (int s2 = 1; s2 < 16; s2 <<= 1)
#pragma unroll
      for (int i = 0; i < 4; ++i)
#pragma unroll
        for (int e = 0; e < 4; ++e)
          rm[i][e] = fminf(rm[i][e], __shfl_xor(rm[i][e], s2, 64));
    if (lrow == 0) {
#pragma unroll
      for (int i = 0; i < 4; ++i)
#pragma unroll
        for (int e = 0; e < 4; ++e) {
          int p = pt * 128 + wr * 64 + i * 16 + lk * 4 + e;
          if (p < NP) atomicMin(&mc[b * NP + p], enc_f(rm[i][e]));
        }
    }
  }
}

// ---------------------------------------------------------------------------
// gdistB: per-b patch reduction + combine. grid NB, block 256.
// ---------------------------------------------------------------------------
__global__ __launch_bounds__(256) void gdistB_kernel(
    const int* __restrict__ valid_mask,
    const float* __restrict__ xx_pt, const float* __restrict__ xx_rgb,
    const unsigned* __restrict__ mc_pt, const unsigned* __restrict__ mc_rgb,
    const float* __restrict__ nv_part, const unsigned* __restrict__ gmin,
    float* __restrict__ partial) {
  const int b = blockIdx.x;
  const int tid = threadIdx.x;
  __shared__ float s1[256], s2[256];
  float spt = 0.f, srgb = 0.f;
  for (int p = tid; p < NP; p += 256) {
    float m = (float)valid_mask[b * NP + p];
    float dpt = xx_pt[b * NP + p] + dec_f(mc_pt[b * NP + p]);
    dpt = sqrtf(fminf(fmaxf(dpt, 1e-12f), 50.f));
    float drg = xx_rgb[b * NP + p] + dec_f(mc_rgb[b * NP + p]);
    drg = sqrtf(fminf(fmaxf(drg, 1e-12f), 50.f));
    spt += m * dpt;
    srgb += drg;
  }
  s1[tid] = spt; s2[tid] = srgb;
  __syncthreads();
  for (int s = 128; s > 0; s >>= 1) {
    if (tid < s) { s1[tid] += s1[tid + s]; s2[tid] += s2[tid + s]; }
    __syncthreads();
  }
  if (tid == 0) {
    float nv = 0.f;
    for (int k = 0; k < 49; ++k) nv += nv_part[b * 49 + k];
    float ming_pt = sqrtf(fminf(fmaxf(dec_f(gmin[b]), 1e-12f), 50.f));
    float ming_rgb = sqrtf(fminf(fmaxf(dec_f(gmin[NB + b]), 1e-12f), 50.f));
    partial[b] = s2[0] / (float)NP + s1[0] / nv + 0.4f * (ming_pt + ming_rgb);
  }
}

// ---------------------------------------------------------------------------
// final tiny reduction. 1 block of 64.
// ---------------------------------------------------------------------------
__global__ void final_kernel(const float* __restrict__ partial, float* __restrict__ out) {
  const int lane = threadIdx.x & 63;
  float v = (lane < NB) ? partial[lane] : 0.f;
  for (int sft = 1; sft < 64; sft <<= 1) v += __shfl_xor(v, sft, 64);
  if (lane == 0) out[0] = 0.9f * v / (float)NB;
}

// ---------------------------------------------------------------------------
// FALLBACK path kernels (ws too small): fp32->bf16 pipeline
// ---------------------------------------------------------------------------
__global__ __launch_bounds__(256) void bank_norms_kernel(
    const float* __restrict__ bank_pt, const float* __restrict__ bank_rgb,
    float* __restrict__ bn_pt, float* __restrict__ bn_rgb) {
  const int branch = blockIdx.y;
  const float* bank = branch ? bank_rgb : bank_pt;
  float* bn = branch ? bn_rgb : bn_pt;
  const int D = branch ? DRG : DPT;
  const int w = threadIdx.x >> 6, lane = threadIdx.x & 63;
  const int row = blockIdx.x * 4 + w;
  const float2* rp = (const float2*)(bank + (size_t)row * D);
  const int cnt = D >> 7;
  float s = 0.f;
  for (int i = 0; i < cnt; ++i) {
    float2 v = rp[lane + 64 * i];
    s += v.x * v.x + v.y * v.y;
  }
  for (int sft = 1; sft < 64; sft <<= 1) s += __shfl_xor(s, sft, 64);
  if (lane == 0) bn[row] = s;
}

__global__ __launch_bounds__(256) void prep_fb_kernel(
    const float* __restrict__ feat_pt, const float* __restrict__ feat_rgb,
    const int* __restrict__ valid_mask,
    float* __restrict__ xx_pt, float* __restrict__ xx_rgb,
    float* __restrict__ gs_pt, float* __restrict__ gs_rgb) {
  const int b = blockIdx.y;
  const int w = threadIdx.x >> 6, lane = threadIdx.x & 63;
  float2 gp[9], gr[6];
#pragma unroll
  for (int i = 0; i < 9; ++i) gp[i] = make_float2(0.f, 0.f);
#pragma unroll
  for (int i = 0; i < 6; ++i) gr[i] = make_float2(0.f, 0.f);
  const int pbase = blockIdx.x * 16 + w * 4;
#pragma unroll
  for (int pi = 0; pi < 4; ++pi) {
    const int p = pbase + pi;
    const float msk = (float)valid_mask[b * NP + p];
    const float2* xr = (const float2*)(feat_pt + ((size_t)b * NP + p) * DPT);
    float s = 0.f;
#pragma unroll
    for (int i = 0; i < 9; ++i) {
      float2 v = xr[lane + 64 * i];
      s += v.x * v.x + v.y * v.y;
      gp[i].x += msk * v.x; gp[i].y += msk * v.y;
    }
    const float2* rr = (const float2*)(feat_rgb + ((size_t)b * NP + p) * DRG);
    float s2 = 0.f;
#pragma unroll
    for (int i = 0; i < 6; ++i) {
      float2 v = rr[lane + 64 * i];
      s2 += v.x * v.x + v.y * v.y;
      gr[i].x += msk * v.x; gr[i].y += msk * v.y;
    }
    for (int sft = 1; sft < 64; sft <<= 1) {
      s += __shfl_xor(s, sft, 64);
      s2 += __shfl_xor(s2, sft, 64);
    }
    if (lane == 0) {
      xx_pt[b * NP + p] = s;
      xx_rgb[b * NP + p] = s2;
    }
  }
#pragma unroll
  for (int i = 0; i < 9; ++i) {
    int d = 2 * (lane + 64 * i);
    atomicAdd(&gs_pt[b * DPT + d], gp[i].x);
    atomicAdd(&gs_pt[b * DPT + d + 1], gp[i].y);
  }
#pragma unroll
  for (int i = 0; i < 6; ++i) {
    int d = 2 * (lane + 64 * i);
    atomicAdd(&gs_rgb[b * DRG + d], gr[i].x);
    atomicAdd(&gs_rgb[b * DRG + d + 1], gr[i].y);
  }
}

__global__ __launch_bounds__(256) void gemm_min_kernel(
    const float* __restrict__ feat_pt, const float* __restrict__ feat_rgb,
    const float* __restrict__ bank_pt, const float* __restrict__ bank_rgb,
    const float* __restrict__ bn_pt, const float* __restrict__ bn_rgb,
    const int* __restrict__ classlabels,
    unsigned* __restrict__ mc_pt, unsigned* __restrict__ mc_rgb) {
  const int branch = blockIdx.z;
  const int b = blockIdx.y;
  const int ptile = blockIdx.x % 7;
  const int mchunk = blockIdx.x / 7;
  const int D = branch ? DRG : DPT;
  const float* feat = branch ? feat_rgb : feat_pt;
  const float* bank = branch ? bank_rgb : bank_pt;
  const float* bn = branch ? bn_rgb : bn_pt;
  unsigned* mc = branch ? mc_rgb : mc_pt;
  const int cls = classlabels[b];

  __shared__ __align__(16) unsigned short As[128 * 32];
  __shared__ __align__(16) unsigned short Bs2[128 * 32];

  const int tid = threadIdx.x;
  const int r = tid >> 1;
  const int h = tid & 1;
  const int p0 = ptile * 128;
  const int prow = (p0 + r < NP) ? (p0 + r) : (NP - 1);
  const float* Arow = feat + ((size_t)b * NP + prow) * D + h * 16;
  const float* BankC = bank + (size_t)cls * NM * D;
  const float* bnC = bn + cls * NM;
  const int swz = (r >> 1) & 3;
  const int wo0 = r * 32 + ((2 * h) ^ swz) * 8;
  const int wo1 = r * 32 + ((2 * h + 1) ^ swz) * 8;

  const int lane = tid & 63;
  const int w = tid >> 6;
  const int wr = w >> 1, wcq = w & 1;
  const int lrow = lane & 15, lk = lane >> 4;
  int aoff[4], boff[4];
#pragma unroll
  for (int i = 0; i < 4; ++i) {
    int row = wr * 64 + i * 16 + lrow;
    aoff[i] = row * 32 + (lk ^ ((row >> 1) & 3)) * 8;
    row = wcq * 64 + i * 16 + lrow;
    boff[i] = row * 32 + (lk ^ ((row >> 1) & 3)) * 8;
  }

  float rm[4][4];
#pragma unroll
  for (int i = 0; i < 4; ++i)
#pragma unroll
    for (int e = 0; e < 4; ++e) rm[i][e] = 1e30f;

  union V16 { unsigned short s[8]; float4 v; };

#pragma unroll 1
  for (int mt = 0; mt < 8; ++mt) {
    const int mbase = mchunk * 1024 + mt * 128;
    const float* Brow = BankC + (size_t)(mbase + r) * D + h * 16;
    f32x4 acc[4][4];
#pragma unroll
    for (int i = 0; i < 4; ++i)
#pragma unroll
      for (int j = 0; j < 4; ++j) acc[i][j] = (f32x4){0.f, 0.f, 0.f, 0.f};

#pragma unroll 1
    for (int k0 = 0; k0 < D; k0 += 32) {
      __syncthreads();
      {
        const float4* ga = (const float4*)(Arow + k0);
        float4 f0 = ga[0], f1 = ga[1], f2 = ga[2], f3 = ga[3];
        V16 u0, u1;
        u0.s[0] = f2bf(f0.x); u0.s[1] = f2bf(f0.y); u0.s[2] = f2bf(f0.z); u0.s[3] = f2bf(f0.w);
        u0.s[4] = f2bf(f1.x); u0.s[5] = f2bf(f1.y); u0.s[6] = f2bf(f1.z); u0.s[7] = f2bf(f1.w);
        u1.s[0] = f2bf(f2.x); u1.s[1] = f2bf(f2.y); u1.s[2] = f2bf(f2.z); u1.s[3] = f2bf(f2.w);
        u1.s[4] = f2bf(f3.x); u1.s[5] = f2bf(f3.y); u1.s[6] = f2bf(f3.z); u1.s[7] = f2bf(f3.w);
        *(float4*)&As[wo0] = u0.v;
        *(float4*)&As[wo1] = u1.v;
      }
      {
        const float4* gb = (const float4*)(Brow + k0);
        float4 f0 = gb[0], f1 = gb[1], f2 = gb[2], f3 = gb[3];
        V16 u0, u1;
        u0.s[0] = f2bf(f0.x); u0.s[1] = f2bf(f0.y); u0.s[2] = f2bf(f0.z); u0.s[3] = f2bf(f0.w);
        u0.s[4] = f2bf(f1.x); u0.s[5] = f2bf(f1.y); u0.s[6] = f2bf(f1.z); u0.s[7] = f2bf(f1.w);
        u1.s[0] = f2bf(f2.x); u1.s[1] = f2bf(f2.y); u1.s[2] = f2bf(f2.z); u1.s[3] = f2bf(f2.w);
        u1.s[4] = f2bf(f3.x); u1.s[5] = f2bf(f3.y); u1.s[6] = f2bf(f3.z); u1.s[7] = f2bf(f3.w);
        *(float4*)&Bs2[wo0] = u0.v;
        *(float4*)&Bs2[wo1] = u1.v;
      }
      __syncthreads();
      bf16x8 af[4], bfv[4];
#pragma unroll
      for (int i = 0; i < 4; ++i) {
        af[i] = *(const bf16x8*)&As[aoff[i]];
        bfv[i] = *(const bf16x8*)&Bs2[boff[i]];
      }
#pragma unroll
      for (int i = 0; i < 4; ++i)
#pragma unroll
        for (int j = 0; j < 4; ++j)
          acc[i][j] = __builtin_amdgcn_mfma_f32_16x16x32_bf16(af[i], bfv[j], acc[i][j], 0, 0, 0);
    }
#pragma unroll
    for (int j = 0; j < 4; ++j) {
      float bnv = bnC[mbase + wcq * 64 + j * 16 + lrow];
#pragma unroll
      for (int i = 0; i < 4; ++i)
#pragma unroll
        for (int e = 0; e < 4; ++e)
          rm[i][e] = fminf(rm[i][e], bnv - 2.0f * acc[i][j][e]);
    }
  }
#pragma unroll
  for (int s = 1; s < 16; s <<= 1)
#pragma unroll
    for (int i = 0; i < 4; ++i)
#pragma unroll
      for (int e = 0; e < 4; ++e)
        rm[i][e] = fminf(rm[i][e], __shfl_xor(rm[i][e], s, 64));
  if (lrow == 0) {
#pragma unroll
    for (int i = 0; i < 4; ++i)
#pragma unroll
      for (int e = 0; e < 4; ++e) {
        int p = p0 + wr * 64 + i * 16 + lk * 4 + e;
        if (p < NP) atomicMin(&mc[b * NP + p], enc_f(rm[i][e]));
      }
  }
}

__global__ __launch_bounds__(256) void gdist_fb_kernel(
    const float* __restrict__ bgp, const float* __restrict__ bgr,
    const float* __restrict__ gs_pt, const float* __restrict__ gs_rgb,
    const int* __restrict__ classlabels, const int* __restrict__ valid_mask,
    const float* __restrict__ xx_pt, const float* __restrict__ xx_rgb,
    const unsigned* __restrict__ mc_pt, const unsigned* __restrict__ mc_rgb,
    float* __restrict__ partial) {
  const int b = blockIdx.x;
  const int tid = threadIdx.x;
  const int w = tid >> 6, lane = tid & 63;
  __shared__ float sred[256], sred2[256], sred3[256];
  __shared__ float gsh[DPT];
  __shared__ float wmin[4];
  float nvi = 0.f, spt = 0.f, srgb = 0.f;
  for (int p = tid; p < NP; p += 256) {
    float m = (float)valid_mask[b * NP + p];
    nvi += m;
    float dpt = xx_pt[b * NP + p] + dec_f(mc_pt[b * NP + p]);
    dpt = sqrtf(fminf(fmaxf(dpt, 1e-12f), 50.f));
    float drg = xx_rgb[b * NP + p] + dec_f(mc_rgb[b * NP + p]);
    drg = sqrtf(fminf(fmaxf(drg, 1e-12f), 50.f));
    spt += m * dpt;
    srgb += drg;
  }
  sred[tid] = nvi; sred2[tid] = spt; sred3[tid] = srgb;
  __syncthreads();
  for (int s = 128; s > 0; s >>= 1) {
    if (tid < s) {
      sred[tid] += sred[tid + s];
      sred2[tid] += sred2[tid + s];
      sred3[tid] += sred3[tid + s];
    }
    __syncthreads();
  }
  const float nv = sred[0];
  const float mean_pt = sred2[0] / nv;
  const float mean_rgb = sred3[0] / (float)NP;
  const int cls = classlabels[b];
  float ming_pt, ming_rgb;
  for (int d = tid; d < DPT; d += 256) gsh[d] = gs_pt[b * DPT + d] / nv;
  __syncthreads();
  {
    float mn = 1e30f;
    for (int row = w; row < NMG; row += 4) {
      const float2* yr = (const float2*)(bgp + ((size_t)cls * NMG + row) * DPT);
      float s = 0.f;
#pragma unroll
      for (int i = 0; i < 9; ++i) {
        float2 y = yr[lane + 64 * i];
        int d = 2 * (lane + 64 * i);
        float dx = gsh[d] - y.x, dy = gsh[d + 1] - y.y;
        s += dx * dx + dy * dy;
      }
      for (int sft = 1; sft < 64; sft <<= 1) s += __shfl_xor(s, sft, 64);
      mn = fminf(mn, s);
    }
    if (lane == 0) wmin[w] = mn;
    __syncthreads();
    float m2 = fminf(fminf(wmin[0], wmin[1]), fminf(wmin[2], wmin[3]));
    ming_pt = sqrtf(fminf(fmaxf(m2, 1e-12f), 50.f));
    __syncthreads();
  }
  for (int d = tid; d < DRG; d += 256) gsh[d] = gs_rgb[b * DRG + d] / nv;
  __syncthreads();
  {
    float mn = 1e30f;
    for (int row = w; row < NMG; row += 4) {
      const float2* yr = (const float2*)(bgr + ((size_t)cls * NMG + row) * DRG);
      float s = 0.f;
#pragma unroll
      for (int i = 0; i < 6; ++i) {
        float2 y = yr[lane + 64 * i];
        int d = 2 * (lane + 64 * i);
        float dx = gsh[d] - y.x, dy = gsh[d + 1] - y.y;
        s += dx * dx + dy * dy;
      }
      for (int sft = 1; sft < 64; sft <<= 1) s += __shfl_xor(s, sft, 64);
      mn = fminf(mn, s);
    }
    if (lane == 0) wmin[w] = mn;
    __syncthreads();
    float m2 = fminf(fminf(wmin[0], wmin[1]), fminf(wmin[2], wmin[3]));
    ming_rgb = sqrtf(fminf(fmaxf(m2, 1e-12f), 50.f));
  }
  if (tid == 0)
    partial[b] = mean_rgb + mean_pt + 0.4f * (ming_pt + ming_rgb);
}

// ---------------------------------------------------------------------------
extern "C" void kernel_launch(void* const* d_in, const int* in_sizes, int n_in,
                              void* d_out, int out_size, void* d_ws, size_t ws_size,
                              hipStream_t stream) {
  const float* feat_pt = (const float*)d_in[0];
  const float* feat_rgb = (const float*)d_in[1];
  const float* bank_pt = (const float*)d_in[2];
  const float* bank_rgb = (const float*)d_in[3];
  const float* bgp = (const float*)d_in[4];
  const float* bgr = (const float*)d_in[5];
  const int* classlabels = (const int*)d_in[6];
  const int* valid_mask = (const int*)d_in[7];
  float* out = (float*)d_out;

  const size_t BBP = (size_t)NC * NM * DPT;   // bank fp8 bytes
  const size_t BBR = (size_t)NC * NM * DRG;
  const size_t FBP = (size_t)NB * NP * DPT;   // feature fp8 bytes
  const size_t FBR = (size_t)NB * NP * DRG;
  const size_t GSPART = (size_t)NB * 49 * DTOT;  // 1.5M floats
  const size_t SMALL_WORDS = 4 * (size_t)NC * NM + 8 * (size_t)NB * NP +
                             GSPART + (size_t)NB * 49 + 8 * NB + 2 * NC + 256;
  const size_t NEED = (BBP + BBR + FBP + FBR) + 4 * SMALL_WORDS;
  const bool fast = (ws_size >= NEED);

  if (fast) {
    unsigned char* b8_pt = (unsigned char*)d_ws;
    unsigned char* b8_rgb = b8_pt + BBP;
    unsigned char* f8_pt = b8_rgb + BBR;
    unsigned char* f8_rgb = f8_pt + FBP;
    float* fl = (float*)(f8_rgb + FBR);
    float* bn_pt = fl;                          // NC*NM
    float* bn_rgb = bn_pt + NC * NM;
    float* bnS_pt = bn_rgb + NC * NM;           // NC*NM
    float* bnS_rgb = bnS_pt + NC * NM;
    float* xx_pt = bnS_rgb + NC * NM;           // NB*NP
    float* xx_rgb = xx_pt + NB * NP;
    float* xxS_pt = xx_rgb + NB * NP;
    float* xxS_rgb = xxS_pt + NB * NP;
    float* gs_part = xxS_rgb + NB * NP;         // NB*49*DTOT
    float* nv_part = gs_part + GSPART;          // NB*49
    unsigned* mc_pt = (unsigned*)(nv_part + NB * 49);
    unsigned* mc_rgb = mc_pt + NB * NP;
    float* partial = (float*)(mc_rgb + NB * NP);    // NB
    unsigned* gmin = (unsigned*)(partial + NB);     // 2*NB
    unsigned* flagF = gmin + 2 * NB;                // 2*NB
    unsigned* classFlag = flagF + 2 * NB;           // NC

    fused_cp_kernel<<<2080, 256, 0, stream>>>(
        feat_pt, feat_rgb, bank_pt, bank_rgb, classlabels, valid_mask,
        xx_pt, xx_rgb, xxS_pt, xxS_rgb, gs_part, nv_part,
        f8_pt, f8_rgb, b8_pt, b8_rgb, bnS_pt, bnS_rgb,
        mc_pt, gmin, flagF, classFlag);
    fused_g1_kernel<<<768, 256, 0, stream>>>(
        f8_pt, f8_rgb, b8_pt, b8_rgb, bnS_pt, bnS_rgb, xxS_pt, xxS_rgb,
        classlabels, flagF, classFlag, bgp, bgr, gs_part, nv_part, gmin);
    fullconv_kernel<<<2064, 256, 0, stream>>>(
        bank_pt, bank_rgb, feat_pt, feat_rgb, b8_pt, b8_rgb, f8_pt, f8_rgb,
        bn_pt, bn_rgb, classFlag, flagF);
    gemm2_kernel<<<dim3(64, NB), 256, 0, stream>>>(
        f8_pt, f8_rgb, b8_pt, b8_rgb, bn_pt, bn_rgb, classlabels, flagF, mc_pt, mc_rgb);
    gdistB_kernel<<<NB, 256, 0, stream>>>(
        valid_mask, xx_pt, xx_rgb, mc_pt, mc_rgb, nv_part, gmin, partial);
    final_kernel<<<1, 64, 0, stream>>>(partial, out);
  } else {
    float* ws = (float*)d_ws;
    float* bn_pt = ws;
    float* bn_rgb = bn_pt + NC * NM;
    float* xx_pt = bn_rgb + NC * NM;
    float* xx_rgb = xx_pt + NB * NP;
    float* gs_pt = xx_rgb + NB * NP;
    float* gs_rgb = gs_pt + NB * DPT;
    unsigned* mc_pt = (unsigned*)(gs_rgb + NB * DRG);
    unsigned* mc_rgb = mc_pt + NB * NP;
    float* partial = (float*)(mc_rgb + NB * NP);

    hipMemsetAsync(gs_pt, 0, (size_t)(NB * DPT + NB * DRG) * 4, stream);
    hipMemsetAsync(mc_pt, 0xF7, (size_t)(2 * NB * NP) * 4, stream);

    bank_norms_kernel<<<dim3(NC * NM / 4, 2), 256, 0, stream>>>(bank_pt, bank_rgb, bn_pt, bn_rgb);
    prep_fb_kernel<<<dim3(49, NB), 256, 0, stream>>>(
        feat_pt, feat_rgb, valid_mask, xx_pt, xx_rgb, gs_pt, gs_rgb);
    gemm_min_kernel<<<dim3(28, NB, 2), 256, 0, stream>>>(
        feat_pt, feat_rgb, bank_pt, bank_rgb, bn_pt, bn_rgb, classlabels, mc_pt, mc_rgb);
    gdist_fb_kernel<<<NB, 256, 0, stream>>>(bgp, bgr, gs_pt, gs_rgb, classlabels, valid_mask,
                                            xx_pt, xx_rgb, mc_pt, mc_rgb, partial);
    final_kernel<<<1, 64, 0, stream>>>(partial, out);
  }
}